// Round 12
// baseline (259.492 us; speedup 1.0000x reference)
//
#include <hip/hip_runtime.h>
#include <hip/hip_bf16.h>
#include <math.h>

#define B_SZ 2
#define L_SEQ 512
#define DMODEL 768
#define DINNER 1536
#define DSTATE 128
#define HEADDIM 64
#define NHEADS 24
#define CONVDIM 1792
#define DINPROJ 3352
#define ROWS (B_SZ * L_SEQ)  // 1024

#define CHUNK 32
#define NCHUNK (L_SEQ / CHUNK)  // 16
#define BCDIM (2 * DSTATE)      // 256

#define NPAD_IN 3456   // 54 * 64
#define NPAD_CLS 1024  // 16 * 64

typedef __attribute__((ext_vector_type(8))) __bf16 bf16x8;
typedef __attribute__((ext_vector_type(4))) __bf16 bf16x4;
typedef __attribute__((ext_vector_type(4))) float f32x4;

typedef __attribute__((address_space(1))) const unsigned int as1_u32;
typedef __attribute__((address_space(3))) unsigned int as3_u32;

__device__ __forceinline__ void gload16(const void* g, void* s) {
  __builtin_amdgcn_global_load_lds((as1_u32*)(unsigned long)g, (as3_u32*)(unsigned long)s, 16, 0,
                                   0);
}

__device__ __forceinline__ float siluf(float x) { return x / (1.f + expf(-x)); }
__device__ __forceinline__ float softplusf(float x) {
  return x > 0.f ? x + log1pf(expf(-x)) : log1pf(expf(x));
}

__device__ __forceinline__ float block_reduce_sum(float v, float* sred) {
  int tid = threadIdx.x;
  for (int off = 32; off; off >>= 1) v += __shfl_down(v, off, 64);
  int wid = tid >> 6, lane = tid & 63;
  if (lane == 0) sred[wid] = v;
  __syncthreads();
  float total;
  if (tid == 0) {
    total = 0.f;
    int nw = blockDim.x >> 6;
    for (int i = 0; i < nw; ++i) total += sred[i];
    sred[0] = total;
  }
  __syncthreads();
  total = sred[0];
  __syncthreads();
  return total;
}

// ---------------- fused: embed gather + LN(blk0) + all 5 weight transpose/decompose ------------
__global__ __launch_bounds__(256) void decomp_all_kernel(
    const float* __restrict__ Win, const float* __restrict__ Wout,
    const float* __restrict__ Wcls, const int* __restrict__ tok, const float* __restrict__ emb,
    const float* __restrict__ lnw0, const float* __restrict__ lnb0, float* __restrict__ x,
    __bf16* __restrict__ nxh, __bf16* __restrict__ nxl, __bf16* __restrict__ wih0,
    __bf16* __restrict__ wil0, __bf16* __restrict__ wih1, __bf16* __restrict__ wil1,
    __bf16* __restrict__ woh0, __bf16* __restrict__ wol0, __bf16* __restrict__ woh1,
    __bf16* __restrict__ wol1, __bf16* __restrict__ wch, __bf16* __restrict__ wcl) {
  constexpr int TIN = (NPAD_IN / 32) * (DMODEL / 32);    // 2592
  constexpr int TOUT = (DMODEL / 32) * (DINNER / 32);    // 1152
  constexpr int TCLS = (NPAD_CLS / 32) * (DMODEL / 32);  // 768
  __shared__ float tile[32][33];
  int bid = blockIdx.x;
  int tid = threadIdx.x;

  if (bid >= 2 * TIN + 2 * TOUT + TCLS) {
    int row = bid - (2 * TIN + 2 * TOUT + TCLS);
    int t = tok[row];
    float v[3];
    float s = 0.f;
#pragma unroll
    for (int j = 0; j < 3; ++j) {
      v[j] = emb[(size_t)t * DMODEL + tid + j * 256];
      s += v[j];
      x[(size_t)row * DMODEL + tid + j * 256] = v[j];
    }
    float* sred = (float*)tile;
    float mean = block_reduce_sum(s, sred) * (1.f / DMODEL);
    float s2 = 0.f;
#pragma unroll
    for (int j = 0; j < 3; ++j) {
      float d = v[j] - mean;
      s2 += d * d;
    }
    float var = block_reduce_sum(s2, sred) * (1.f / DMODEL);
    float r = 1.f / sqrtf(var + 1e-5f);
#pragma unroll
    for (int j = 0; j < 3; ++j) {
      int d = tid + j * 256;
      float val = (v[j] - mean) * r * lnw0[d] + lnb0[d];
      __bf16 h = (__bf16)val;
      nxh[(size_t)row * DMODEL + d] = h;
      nxl[(size_t)row * DMODEL + d] = (__bf16)(val - (float)h);
    }
    return;
  }

  const float* W;
  __bf16 *Th, *Tl;
  int K, N, ntx, r;
  if (bid < TIN) {
    W = Win; Th = wih0; Tl = wil0; K = DMODEL; N = DINPROJ; ntx = NPAD_IN / 32; r = bid;
  } else if (bid < 2 * TIN) {
    W = Win + (size_t)DMODEL * DINPROJ; Th = wih1; Tl = wil1; K = DMODEL; N = DINPROJ;
    ntx = NPAD_IN / 32; r = bid - TIN;
  } else if (bid < 2 * TIN + TOUT) {
    W = Wout; Th = woh0; Tl = wol0; K = DINNER; N = DMODEL; ntx = DMODEL / 32; r = bid - 2 * TIN;
  } else if (bid < 2 * TIN + 2 * TOUT) {
    W = Wout + (size_t)DINNER * DMODEL; Th = woh1; Tl = wol1; K = DINNER; N = DMODEL;
    ntx = DMODEL / 32; r = bid - 2 * TIN - TOUT;
  } else {
    W = Wcls; Th = wch; Tl = wcl; K = DMODEL; N = 1000; ntx = NPAD_CLS / 32;
    r = bid - 2 * TIN - 2 * TOUT;
  }
  int bn = (r % ntx) * 32, bk = (r / ntx) * 32;

  int i = tid >> 3, j4 = (tid & 7) * 4;
  int kk = bk + i;
  int nn = bn + j4;
  float4 v;
  if (nn + 3 < N) {
    v = *(const float4*)(W + (size_t)kk * N + nn);
  } else {
    v.x = (nn + 0 < N) ? W[(size_t)kk * N + nn + 0] : 0.f;
    v.y = (nn + 1 < N) ? W[(size_t)kk * N + nn + 1] : 0.f;
    v.z = (nn + 2 < N) ? W[(size_t)kk * N + nn + 2] : 0.f;
    v.w = (nn + 3 < N) ? W[(size_t)kk * N + nn + 3] : 0.f;
  }
  tile[i][j4 + 0] = v.x;
  tile[i][j4 + 1] = v.y;
  tile[i][j4 + 2] = v.z;
  tile[i][j4 + 3] = v.w;
  __syncthreads();
  int n = bn + i;
  bf16x4 hv, lv;
#pragma unroll
  for (int q = 0; q < 4; ++q) {
    float f = tile[j4 + q][i];
    __bf16 h = (__bf16)f;
    hv[q] = h;
    lv[q] = (__bf16)(f - (float)h);
  }
  *(bf16x4*)(Th + (size_t)n * K + bk + j4) = hv;
  *(bf16x4*)(Tl + (size_t)n * K + bk + j4) = lv;
}

// ---------------- layernorm -> bf16 hi/lo ----------------
__global__ __launch_bounds__(256) void ln_kernel(const float* __restrict__ x,
                                                 const float* __restrict__ w,
                                                 const float* __restrict__ b,
                                                 __bf16* __restrict__ oh,
                                                 __bf16* __restrict__ ol) {
  __shared__ float sred[8];
  int row = blockIdx.x, tid = threadIdx.x;
  const float* xr = x + (size_t)row * DMODEL;
  float v[3];
  float s = 0.f;
#pragma unroll
  for (int j = 0; j < 3; ++j) {
    v[j] = xr[tid + j * 256];
    s += v[j];
  }
  float mean = block_reduce_sum(s, sred) * (1.f / DMODEL);
  float s2 = 0.f;
#pragma unroll
  for (int j = 0; j < 3; ++j) {
    float d = v[j] - mean;
    s2 += d * d;
  }
  float var = block_reduce_sum(s2, sred) * (1.f / DMODEL);
  float r = 1.f / sqrtf(var + 1e-5f);
#pragma unroll
  for (int j = 0; j < 3; ++j) {
    int d = tid + j * 256;
    float val = (v[j] - mean) * r * w[d] + b[d];
    __bf16 h = (__bf16)val;
    oh[(size_t)row * DMODEL + d] = h;
    ol[(size_t)row * DMODEL + d] = (__bf16)(val - (float)h);
  }
}

// ---------------- x -> bf16 hi/lo ----------------
__global__ __launch_bounds__(256) void act_decomp_kernel(const float* __restrict__ x,
                                                         __bf16* __restrict__ oh,
                                                         __bf16* __restrict__ ol) {
  int row = blockIdx.x, tid = threadIdx.x;
#pragma unroll
  for (int j = 0; j < 3; ++j) {
    int d = tid + j * 256;
    float v = x[(size_t)row * DMODEL + d];
    __bf16 h = (__bf16)v;
    oh[(size_t)row * DMODEL + d] = h;
    ol[(size_t)row * DMODEL + d] = (__bf16)(v - (float)h);
  }
}

// ---------------- bf16x3 MFMA GEMM, 2-phase double-buffered staging ----------------
// If nbx>0: 1-D grid, bijective XCD swizzle, bx-major (blocks sharing a B-panel contiguous;
// A footprint stays L2-resident per XCD).
template <int FM, int FN, bool ATOMIC>
__global__ __launch_bounds__(256) void mfma_gemm_kernel(
    const __bf16* __restrict__ Ahi, const __bf16* __restrict__ Alo,
    const __bf16* __restrict__ Bhi, const __bf16* __restrict__ Blo,
    const float* __restrict__ addsrc, const float* __restrict__ bias, float* __restrict__ C,
    int N, int K, int kslice, int nbx, int nwg) {
  constexpr int BM = FM * 32;
  constexpr int BN = FN * 32;
  constexpr int RGA = BM / 16;
  constexpr int RGB = BN / 16;
  constexpr int NITER = (2 * (RGA + RGB)) / 4;
  constexpr int ABYTES = BM * 64;
  constexpr int BBYTES = BN * 64;
  constexpr int BUFBYTES = 2 * ABYTES + 2 * BBYTES;
  __shared__ char lds[2 * BUFBYTES];

  int tid = threadIdx.x;
  int wave = tid >> 6, lane = tid & 63;
  int wm = wave >> 1, wn = wave & 1;
  int bx, by;
  if (nbx > 0) {
    int orig = (blockIdx.x % 8) * (nwg / 8) + blockIdx.x / 8;  // XCD-contiguous chunks
    int nby = nwg / nbx;
    bx = orig / nby;  // bx-major: B-panel shared within a chunk
    by = orig % nby;
  } else {
    bx = blockIdx.x;
    by = blockIdx.y;
  }
  int bm = by * BM;
  int bn = bx * BN;
  int kbeg = ATOMIC ? blockIdx.z * kslice : 0;
  int kend = ATOMIC ? (kbeg + kslice) : K;
  int l2 = lane >> 2;
  int gch = (lane & 3) ^ ((lane >> 3) & 3);
  int lr = lane & 15, lg = lane >> 4;

  f32x4 acc[FM][FN] = {};

  auto stage = [&](char* buf, int k0) {
#pragma unroll
    for (int it = 0; it < NITER; ++it) {
      int rg = wave + it * 4;
      const __bf16* src;
      int row0, boff;
      if (rg < RGA) {
        src = Ahi;
        row0 = bm + rg * 16;
        boff = rg * 1024;
      } else if (rg < 2 * RGA) {
        src = Alo;
        row0 = bm + (rg - RGA) * 16;
        boff = ABYTES + (rg - RGA) * 1024;
      } else if (rg < 2 * RGA + RGB) {
        src = Bhi;
        row0 = bn + (rg - 2 * RGA) * 16;
        boff = 2 * ABYTES + (rg - 2 * RGA) * 1024;
      } else {
        src = Blo;
        row0 = bn + (rg - 2 * RGA - RGB) * 16;
        boff = 2 * ABYTES + BBYTES + (rg - 2 * RGA - RGB) * 1024;
      }
      gload16(src + (size_t)(row0 + l2) * K + k0 + gch * 8, buf + boff);
    }
  };

  stage(lds, kbeg);
  __syncthreads();

  char* curb = lds;
  char* nxtb = lds + BUFBYTES;
  for (int k0 = kbeg; k0 < kend; k0 += 32) {
    if (k0 + 32 < kend) stage(nxtb, k0 + 32);

    bf16x8 ahi[FM], alo[FM], bhi[FN], blo[FN];
#pragma unroll
    for (int m = 0; m < FM; ++m) {
      int r = wm * FM * 16 + m * 16 + lr;
      int off = r * 64 + ((lg ^ ((r >> 1) & 3)) * 16);
      ahi[m] = *(const bf16x8*)(curb + off);
      alo[m] = *(const bf16x8*)(curb + ABYTES + off);
    }
#pragma unroll
    for (int n = 0; n < FN; ++n) {
      int r = wn * FN * 16 + n * 16 + lr;
      int off = r * 64 + ((lg ^ ((r >> 1) & 3)) * 16);
      bhi[n] = *(const bf16x8*)(curb + 2 * ABYTES + off);
      blo[n] = *(const bf16x8*)(curb + 2 * ABYTES + BBYTES + off);
    }
#pragma unroll
    for (int m = 0; m < FM; ++m)
#pragma unroll
      for (int n = 0; n < FN; ++n) {
        acc[m][n] = __builtin_amdgcn_mfma_f32_16x16x32_bf16(ahi[m], bhi[n], acc[m][n], 0, 0, 0);
        acc[m][n] = __builtin_amdgcn_mfma_f32_16x16x32_bf16(ahi[m], blo[n], acc[m][n], 0, 0, 0);
        acc[m][n] = __builtin_amdgcn_mfma_f32_16x16x32_bf16(alo[m], bhi[n], acc[m][n], 0, 0, 0);
      }
    __syncthreads();
    char* t = curb;
    curb = nxtb;
    nxtb = t;
  }

#pragma unroll
  for (int m = 0; m < FM; ++m) {
#pragma unroll
    for (int n = 0; n < FN; ++n) {
      int gcol = bn + wn * FN * 16 + n * 16 + lr;
      if (gcol < N) {
#pragma unroll
        for (int r = 0; r < 4; ++r) {
          int grow = bm + wm * FM * 16 + m * 16 + lg * 4 + r;
          if (ATOMIC) {
            unsafeAtomicAdd(&C[(size_t)grow * N + gcol], acc[m][n][r]);
          } else {
            float v = acc[m][n][r];
            if (addsrc) v += addsrc[(size_t)grow * N + gcol];
            if (bias) v += bias[gcol];
            C[(size_t)grow * N + gcol] = v;
          }
        }
      }
    }
  }
}

// ---------------- fused: conv+silu(B/C) + dt softplus + Sraw = C.B^T  ----------------
// grid (NCHUNK, B_SZ), 256 threads; thread owns one B/C conv column (sliding-window taps).
__global__ __launch_bounds__(256) void convBC_sraw_kernel(
    const float* __restrict__ zx, const float* __restrict__ cw, const float* __restrict__ cb,
    const float* __restrict__ dtb, float* __restrict__ xBC, float* __restrict__ dts,
    float* __restrict__ Sraw) {
  __shared__ float Bs[CHUNK][132];
  __shared__ float Cs[CHUNK][132];
  int ci = blockIdx.x, b = blockIdx.y;
  int tid = threadIdx.x;
  int row0 = b * L_SEQ + ci * CHUNK;
  int c = tid;               // 0..255: B/C channel
  int ch = DINNER + c;       // conv-channel index (B/C section starts at 1536)
  int zcol = DINNER + ch;    // zx column = 3072 + c
  float w0 = cw[ch * 4 + 0], w1 = cw[ch * 4 + 1], w2 = cw[ch * 4 + 2], w3 = cw[ch * 4 + 3];
  float bias = cb[ch];
  float x0 = 0.f, x1 = 0.f, x2 = 0.f;  // zx at l-3, l-2, l-1 (zero before sequence start)
  if (ci > 0) {
    x0 = zx[(size_t)(row0 - 3) * DINPROJ + zcol];
    x1 = zx[(size_t)(row0 - 2) * DINPROJ + zcol];
    x2 = zx[(size_t)(row0 - 1) * DINPROJ + zcol];
  }
  for (int t = 0; t < CHUNK; ++t) {
    float x3 = zx[(size_t)(row0 + t) * DINPROJ + zcol];
    float acc = fmaf(w3, x3, fmaf(w2, x2, fmaf(w1, x1, fmaf(w0, x0, bias))));
    float v = siluf(acc);
    if (c < DSTATE) Bs[t][c] = v;
    else Cs[t][c - DSTATE] = v;
    xBC[(size_t)(row0 + t) * BCDIM + c] = v;
    x0 = x1; x1 = x2; x2 = x3;
  }
  // dt softplus for the 32 rows x 24 heads
  for (int i = tid; i < CHUNK * NHEADS; i += 256) {
    int t = i / NHEADS, h = i % NHEADS;
    float raw = zx[(size_t)(row0 + t) * DINPROJ + DINNER + CONVDIM + h] + dtb[h];
    dts[(size_t)(row0 + t) * NHEADS + h] = softplusf(raw);
  }
  __syncthreads();

  int t0 = (tid >> 4) * 2;
  int s0 = (tid & 15) * 2;
  float sacc[2][2] = {};
#pragma unroll
  for (int n = 0; n < DSTATE; n += 4) {
    float cr[2][4], br[2][4];
#pragma unroll
    for (int i = 0; i < 2; ++i) *(float4*)&cr[i][0] = *(const float4*)&Cs[t0 + i][n];
#pragma unroll
    for (int j = 0; j < 2; ++j) *(float4*)&br[j][0] = *(const float4*)&Bs[s0 + j][n];
#pragma unroll
    for (int i = 0; i < 2; ++i)
#pragma unroll
      for (int j = 0; j < 2; ++j)
#pragma unroll
        for (int k = 0; k < 4; ++k) sacc[i][j] = fmaf(cr[i][k], br[j][k], sacc[i][j]);
  }
  float* Sp = Sraw + ((size_t)(b * NCHUNK + ci) * CHUNK) * CHUNK;
#pragma unroll
  for (int i = 0; i < 2; ++i)
#pragma unroll
    for (int j = 0; j < 2; ++j) Sp[(t0 + i) * CHUNK + s0 + j] = sacc[i][j];
}

// ---------------- chunked SSD: fused X-conv + intra-chunk + chunk state (G -> bf16) ----------
__global__ __launch_bounds__(256) void chunk_local_kernel(
    const float* __restrict__ zx, const float* __restrict__ xBC, const float* __restrict__ Sraw,
    const float* __restrict__ dts, const float* __restrict__ cw, const float* __restrict__ cb,
    const float* __restrict__ Alog, const float* __restrict__ Dp, float* __restrict__ y,
    __bf16* __restrict__ G, float* __restrict__ et, float* __restrict__ elast) {
  __shared__ float Bs[CHUNK][132];
  __shared__ float Xs[CHUNK][68];
  __shared__ float Ss[CHUNK][36];
  __shared__ float sP[CHUNK], sW[CHUNK], sDt[CHUNK];

  int ci = blockIdx.x, h = blockIdx.y, b = blockIdx.z;
  int bh = b * NHEADS + h;
  int tid = threadIdx.x;
  int row0 = b * L_SEQ + ci * CHUNK;

#pragma unroll
  for (int i = 0; i < 2; ++i) {
    int vi = tid + i * 256;
    int t = vi >> 4;
    int n8 = (vi & 15) * 8;
    const float* r = xBC + (size_t)(row0 + t) * BCDIM;
    *(float4*)&Bs[t][n8] = *(const float4*)(r + n8);
    *(float4*)&Bs[t][n8 + 4] = *(const float4*)(r + n8 + 4);
  }
#pragma unroll
  for (int i = 0; i < 2; ++i) {
    int vi = tid + i * 256;
    int t = vi >> 4;
    int p4 = (vi & 15) * 4;
    int cX = h * HEADDIM + p4;
    float oX[4];
#pragma unroll
    for (int q = 0; q < 4; ++q) oX[q] = cb[cX + q];
#pragma unroll
    for (int k = 0; k < 4; ++k) {
      if (ci > 0 || t + k >= 3) {
        float4 v = *(const float4*)(zx + (size_t)(row0 + t - 3 + k) * DINPROJ + DINNER + cX);
#pragma unroll
        for (int q = 0; q < 4; ++q) oX[q] = fmaf(cw[(cX + q) * 4 + k], ((const float*)&v)[q], oX[q]);
      }
    }
#pragma unroll
    for (int q = 0; q < 4; ++q) Xs[t][p4 + q] = siluf(oX[q]);
  }
  if (tid < 32) {
    int t = tid;
    float Ah = -expf(Alog[h]);
    float dtv = dts[(size_t)(row0 + t) * NHEADS + h];
    float P = dtv * Ah;
#pragma unroll
    for (int off = 1; off < 32; off <<= 1) {
      float u = __shfl_up(P, off, 32);
      if (t >= off) P += u;
    }
    float Plast = __shfl(P, 31, 32);
    float e = expf(P);
    sP[t] = P;
    sDt[t] = dtv;
    sW[t] = expf(Plast - P) * dtv;
    et[(size_t)(bh * NCHUNK + ci) * CHUNK + t] = e;
    if (t == 31) elast[bh * NCHUNK + ci] = e;
  }
  __syncthreads();

  int t0 = (tid >> 4) * 2;
  int s0 = (tid & 15) * 2;
  {
    const float* Sp = Sraw + ((size_t)(b * NCHUNK + ci) * CHUNK) * CHUNK;
#pragma unroll
    for (int i = 0; i < 2; ++i)
#pragma unroll
      for (int j = 0; j < 2; ++j) {
        int t = t0 + i, s = s0 + j;
        float sr = Sp[t * CHUNK + s];
        Ss[t][s] = (t >= s) ? sr * expf(sP[t] - sP[s]) * sDt[s] : 0.f;
      }
  }
  __syncthreads();

  {
    int p0 = (tid & 15) * 4;
    float acc[2][4] = {};
#pragma unroll
    for (int s = 0; s < CHUNK; s += 4) {
      float sr[2][4], xr[4][4];
#pragma unroll
      for (int i = 0; i < 2; ++i) *(float4*)&sr[i][0] = *(const float4*)&Ss[t0 + i][s];
#pragma unroll
      for (int u = 0; u < 4; ++u) *(float4*)&xr[u][0] = *(const float4*)&Xs[s + u][p0];
#pragma unroll
      for (int i = 0; i < 2; ++i)
#pragma unroll
        for (int j = 0; j < 4; ++j)
#pragma unroll
          for (int u = 0; u < 4; ++u) acc[i][j] = fmaf(sr[i][u], xr[u][j], acc[i][j]);
    }
    float Dh = Dp[h];
#pragma unroll
    for (int i = 0; i < 2; ++i) {
      int row = row0 + t0 + i;
      float4 o;
      o.x = acc[i][0] + Dh * Xs[t0 + i][p0 + 0];
      o.y = acc[i][1] + Dh * Xs[t0 + i][p0 + 1];
      o.z = acc[i][2] + Dh * Xs[t0 + i][p0 + 2];
      o.w = acc[i][3] + Dh * Xs[t0 + i][p0 + 3];
      *(float4*)(y + (size_t)row * DINNER + h * HEADDIM + p0) = o;
    }
  }

  {
    int n0 = (tid >> 4) * 8;
    int p0 = (tid & 15) * 4;
    float g[8][4] = {};
#pragma unroll 4
    for (int s = 0; s < CHUNK; ++s) {
      float w = sW[s];
      float bv[8], xv[4];
      *(float4*)&bv[0] = *(const float4*)&Bs[s][n0];
      *(float4*)&bv[4] = *(const float4*)&Bs[s][n0 + 4];
      *(float4*)&xv[0] = *(const float4*)&Xs[s][p0];
#pragma unroll
      for (int k = 0; k < 8; ++k) {
        float wb = w * bv[k];
#pragma unroll
        for (int j = 0; j < 4; ++j) g[k][j] = fmaf(wb, xv[j], g[k][j]);
      }
    }
    __bf16* Gp = G + ((size_t)bh * NCHUNK + ci) * (DSTATE * HEADDIM);
#pragma unroll
    for (int k = 0; k < 8; ++k) {
      bf16x4 o;
#pragma unroll
      for (int q = 0; q < 4; ++q) o[q] = (__bf16)g[k][q];
      *(bf16x4*)(Gp + (size_t)(n0 + k) * HEADDIM + p0) = o;
    }
  }
}

// ---------------- combine chunk states (bf16 storage, fp32 running state) ----------------
__global__ __launch_bounds__(256) void combine_kernel(__bf16* __restrict__ G,
                                                      const float* __restrict__ elast) {
  int part = blockIdx.x;
  int bh = blockIdx.y;
  int gi = part * 256 + threadIdx.x;
  __bf16* base = G + (size_t)bh * NCHUNK * (DSTATE * HEADDIM);
  const float* el = elast + bh * NCHUNK;
  float h0 = 0.f, h1 = 0.f, h2 = 0.f, h3 = 0.f;
#pragma unroll
  for (int c = 0; c < NCHUNK - 1; ++c) {
    bf16x4 g = *(bf16x4*)(base + (size_t)c * (DSTATE * HEADDIM) + gi * 4);
    float e = el[c];
    h0 = fmaf(e, h0, (float)g[0]);
    h1 = fmaf(e, h1, (float)g[1]);
    h2 = fmaf(e, h2, (float)g[2]);
    h3 = fmaf(e, h3, (float)g[3]);
    bf16x4 o;
    o[0] = (__bf16)h0;
    o[1] = (__bf16)h1;
    o[2] = (__bf16)h2;
    o[3] = (__bf16)h3;
    *(bf16x4*)(base + (size_t)c * (DSTATE * HEADDIM) + gi * 4) = o;
  }
}

// ---------------- inter-chunk contribution ----------------
__global__ __launch_bounds__(256) void apply_inter_kernel(const float* __restrict__ xBC,
                                                          const __bf16* __restrict__ G,
                                                          const float* __restrict__ et,
                                                          float* __restrict__ y) {
  __shared__ float Cs[CHUNK][132];
  __shared__ float Hs[DSTATE][68];
  __shared__ float sE[CHUNK];
  int ci = blockIdx.x + 1;
  int h = blockIdx.y, b = blockIdx.z;
  int bh = b * NHEADS + h;
  int tid = threadIdx.x;
  int row0 = b * L_SEQ + ci * CHUNK;

#pragma unroll
  for (int i = 0; i < 4; ++i) {
    int vi = tid + i * 256;
    int t = vi >> 5;
    int n4 = (vi & 31) * 4;
    *(float4*)&Cs[t][n4] = *(const float4*)(xBC + (size_t)(row0 + t) * BCDIM + DSTATE + n4);
  }
  const __bf16* Hsrc = G + ((size_t)bh * NCHUNK + (ci - 1)) * (DSTATE * HEADDIM);
#pragma unroll
  for (int i = 0; i < 8; ++i) {
    int vi = tid + i * 256;
    int n = vi >> 4;
    int p4 = (vi & 15) * 4;
    bf16x4 g = *(const bf16x4*)(Hsrc + (size_t)n * HEADDIM + p4);
#pragma unroll
    for (int q = 0; q < 4; ++q) Hs[n][p4 + q] = (float)g[q];
  }
  if (tid < CHUNK) sE[tid] = et[(size_t)(bh * NCHUNK + ci) * CHUNK + tid];
  __syncthreads();

  int t0 = (tid >> 4) * 2;
  int p0 = (tid & 15) * 4;
  float acc[2][4] = {};
#pragma unroll
  for (int n = 0; n < DSTATE; n += 4) {
    float cr[2][4], hr[4][4];
#pragma unroll
    for (int i = 0; i < 2; ++i) *(float4*)&cr[i][0] = *(const float4*)&Cs[t0 + i][n];
#pragma unroll
    for (int u = 0; u < 4; ++u) *(float4*)&hr[u][0] = *(const float4*)&Hs[n + u][p0];
#pragma unroll
    for (int i = 0; i < 2; ++i)
#pragma unroll
      for (int j = 0; j < 4; ++j)
#pragma unroll
        for (int u = 0; u < 4; ++u) acc[i][j] = fmaf(cr[i][u], hr[u][j], acc[i][j]);
  }
#pragma unroll
  for (int i = 0; i < 2; ++i) {
    int row = row0 + t0 + i;
    float e = sE[t0 + i];
    float* yp = y + (size_t)row * DINNER + h * HEADDIM + p0;
    float4 cur = *(float4*)yp;
    cur.x = fmaf(e, acc[i][0], cur.x);
    cur.y = fmaf(e, acc[i][1], cur.y);
    cur.z = fmaf(e, acc[i][2], cur.z);
    cur.w = fmaf(e, acc[i][3], cur.w);
    *(float4*)yp = cur;
  }
}

// ---------------- gate (silu(z)) + RMS norm -> bf16 hi/lo ----------------
__global__ __launch_bounds__(256) void gate_rms_kernel(const float* __restrict__ y,
                                                       const float* __restrict__ zx,
                                                       const float* __restrict__ rmsw,
                                                       __bf16* __restrict__ oh,
                                                       __bf16* __restrict__ ol) {
  __shared__ float sred[8];
  int row = blockIdx.x, tid = threadIdx.x;
  const float* z = zx + (size_t)row * DINPROJ;
  const float* yr = y + (size_t)row * DINNER;
  float v[6];
  float ss = 0.f;
#pragma unroll
  for (int j = 0; j < 6; ++j) {
    int d = tid + j * 256;
    float val = yr[d] * siluf(z[d]);
    v[j] = val;
    ss += val * val;
  }
  float total = block_reduce_sum(ss, sred);
  float r = 1.f / sqrtf(total * (1.f / DINNER) + 1e-5f);
#pragma unroll
  for (int j = 0; j < 6; ++j) {
    int d = tid + j * 256;
    float val = v[j] * r * rmsw[d];
    __bf16 h = (__bf16)val;
    oh[(size_t)row * DINNER + d] = h;
    ol[(size_t)row * DINNER + d] = (__bf16)(val - (float)h);
  }
}

extern "C" void kernel_launch(void* const* d_in, const int* in_sizes, int n_in,
                              void* d_out, int out_size, void* d_ws, size_t ws_size,
                              hipStream_t stream) {
  const int* tokens = (const int*)d_in[0];
  const float* emb = (const float*)d_in[1];
  const float* ln_w = (const float*)d_in[2];
  const float* ln_b = (const float*)d_in[3];
  const float* Win = (const float*)d_in[4];
  const float* conv_w = (const float*)d_in[5];
  const float* conv_b = (const float*)d_in[6];
  const float* dt_bias = (const float*)d_in[7];
  const float* A_log = (const float*)d_in[8];
  const float* Dp = (const float*)d_in[9];
  const float* rms_w = (const float*)d_in[10];
  const float* Wout = (const float*)d_in[11];
  const float* Wcls = (const float*)d_in[12];
  const float* bcls = (const float*)d_in[13];
  float* out = (float*)d_out;

  float* ws = (float*)d_ws;
  float* x = ws;                                // 1024*768
  float* zx = x + (size_t)ROWS * DMODEL;        // 1024*3352
  float* y = zx + (size_t)ROWS * DINPROJ;       // 1024*1536
  __bf16* G = (__bf16*)(y + (size_t)ROWS * DINNER);  // 48*16*8192 bf16 (12.6MB)
  float* et = (float*)(G + (size_t)B_SZ * NHEADS * NCHUNK * DSTATE * HEADDIM);
  float* elast = et + (size_t)B_SZ * NHEADS * NCHUNK * CHUNK;
  float* xBC = elast + B_SZ * NHEADS * NCHUNK;  // 1024*256
  float* Sraw = xBC + (size_t)ROWS * BCDIM;     // 2*16*32*32
  float* dts = Sraw + (size_t)B_SZ * NCHUNK * CHUNK * CHUNK;  // 1024*24
  __bf16* bp = (__bf16*)(dts + (size_t)ROWS * NHEADS);
  __bf16* nxh = bp;  bp += (size_t)ROWS * DMODEL;
  __bf16* nxl = bp;  bp += (size_t)ROWS * DMODEL;
  __bf16* yh = bp;   bp += (size_t)ROWS * DINNER;
  __bf16* yl = bp;   bp += (size_t)ROWS * DINNER;
  __bf16* xh = bp;   bp += (size_t)ROWS * DMODEL;
  __bf16* xl = bp;   bp += (size_t)ROWS * DMODEL;
  __bf16* wih0 = bp; bp += (size_t)NPAD_IN * DMODEL;
  __bf16* wil0 = bp; bp += (size_t)NPAD_IN * DMODEL;
  __bf16* wih1 = bp; bp += (size_t)NPAD_IN * DMODEL;
  __bf16* wil1 = bp; bp += (size_t)NPAD_IN * DMODEL;
  __bf16* woh0 = bp; bp += (size_t)DMODEL * DINNER;
  __bf16* wol0 = bp; bp += (size_t)DMODEL * DINNER;
  __bf16* woh1 = bp; bp += (size_t)DMODEL * DINNER;
  __bf16* wol1 = bp; bp += (size_t)DMODEL * DINNER;
  __bf16* wch = bp;  bp += (size_t)NPAD_CLS * DMODEL;
  __bf16* wcl = bp;

  constexpr int TIN = (NPAD_IN / 32) * (DMODEL / 32);
  constexpr int TOUT = (DMODEL / 32) * (DINNER / 32);
  constexpr int TCLS = (NPAD_CLS / 32) * (DMODEL / 32);
  decomp_all_kernel<<<2 * TIN + 2 * TOUT + TCLS + ROWS, 256, 0, stream>>>(
      Win, Wout, Wcls, tokens, emb, ln_w, ln_b, x, nxh, nxl, wih0, wil0, wih1, wil1, woh0, wol0,
      woh1, wol1, wch, wcl);

  for (int blk = 0; blk < 2; ++blk) {
    const float* cw_b = conv_w + (size_t)blk * CONVDIM * 4;
    const float* cb_b = conv_b + (size_t)blk * CONVDIM;
    const float* dtb_b = dt_bias + (size_t)blk * NHEADS;
    const float* Alog_b = A_log + (size_t)blk * NHEADS;
    const float* Dp_b = Dp + (size_t)blk * NHEADS;
    const float* rmsw_b = rms_w + (size_t)blk * DINNER;
    __bf16* wih = blk ? wih1 : wih0;
    __bf16* wil = blk ? wil1 : wil0;
    __bf16* woh = blk ? woh1 : woh0;
    __bf16* wol = blk ? wol1 : wol0;

    if (blk == 1) {
      ln_kernel<<<ROWS, 256, 0, stream>>>(x, ln_w + (size_t)blk * DMODEL,
                                          ln_b + (size_t)blk * DMODEL, nxh, nxl);
    }

    // 1-D grid with bx-major XCD swizzle: 54*16 = 864 blocks
    mfma_gemm_kernel<2, 2, false><<<(NPAD_IN / 64) * (ROWS / 64), 256, 0, stream>>>(
        nxh, nxl, wih, wil, nullptr, nullptr, zx, DINPROJ, DMODEL, 0, NPAD_IN / 64,
        (NPAD_IN / 64) * (ROWS / 64));

    convBC_sraw_kernel<<<dim3(NCHUNK, B_SZ), 256, 0, stream>>>(zx, cw_b, cb_b, dtb_b, xBC, dts,
                                                               Sraw);

    chunk_local_kernel<<<dim3(NCHUNK, NHEADS, B_SZ), 256, 0, stream>>>(
        zx, xBC, Sraw, dts, cw_b, cb_b, Alog_b, Dp_b, y, G, et, elast);

    combine_kernel<<<dim3(8, B_SZ * NHEADS), 256, 0, stream>>>(G, elast);

    apply_inter_kernel<<<dim3(NCHUNK - 1, NHEADS, B_SZ), 256, 0, stream>>>(xBC, G, et, y);

    gate_rms_kernel<<<ROWS, 256, 0, stream>>>(y, zx, rmsw_b, yh, yl);

    mfma_gemm_kernel<2, 2, true><<<dim3(DMODEL / 64, ROWS / 64, 4), 256, 0, stream>>>(
        yh, yl, woh, wol, nullptr, nullptr, x, DMODEL, DINNER, DINNER / 4, 0, 0);
  }

  act_decomp_kernel<<<ROWS, 256, 0, stream>>>(x, xh, xl);
  // 1-D grid with bx-major XCD swizzle: 16*16 = 256 blocks
  mfma_gemm_kernel<2, 2, false><<<(NPAD_CLS / 64) * (ROWS / 64), 256, 0, stream>>>(
      xh, xl, wch, wcl, nullptr, bcls, out, 1000, DMODEL, 0, NPAD_CLS / 64,
      (NPAD_CLS / 64) * (ROWS / 64));
}

// Round 13
// 248.207 us; speedup vs baseline: 1.0455x; 1.0455x over previous
//
#include <hip/hip_runtime.h>
#include <hip/hip_bf16.h>
#include <math.h>

#define B_SZ 2
#define L_SEQ 512
#define DMODEL 768
#define DINNER 1536
#define DSTATE 128
#define HEADDIM 64
#define NHEADS 24
#define CONVDIM 1792
#define DINPROJ 3352
#define ROWS (B_SZ * L_SEQ)  // 1024

#define CHUNK 32
#define NCHUNK (L_SEQ / CHUNK)  // 16
#define BCDIM (2 * DSTATE)      // 256

#define NPAD_IN 3456   // 54 * 64
#define NPAD_CLS 1024  // 16 * 64

typedef __attribute__((ext_vector_type(8))) __bf16 bf16x8;
typedef __attribute__((ext_vector_type(4))) __bf16 bf16x4;
typedef __attribute__((ext_vector_type(4))) float f32x4;

typedef __attribute__((address_space(1))) const unsigned int as1_u32;
typedef __attribute__((address_space(3))) unsigned int as3_u32;

__device__ __forceinline__ void gload16(const void* g, void* s) {
  __builtin_amdgcn_global_load_lds((as1_u32*)(unsigned long)g, (as3_u32*)(unsigned long)s, 16, 0,
                                   0);
}

__device__ __forceinline__ float siluf(float x) { return x / (1.f + expf(-x)); }
__device__ __forceinline__ float softplusf(float x) {
  return x > 0.f ? x + log1pf(expf(-x)) : log1pf(expf(x));
}

__device__ __forceinline__ float block_reduce_sum(float v, float* sred) {
  int tid = threadIdx.x;
  for (int off = 32; off; off >>= 1) v += __shfl_down(v, off, 64);
  int wid = tid >> 6, lane = tid & 63;
  if (lane == 0) sred[wid] = v;
  __syncthreads();
  float total;
  if (tid == 0) {
    total = 0.f;
    int nw = blockDim.x >> 6;
    for (int i = 0; i < nw; ++i) total += sred[i];
    sred[0] = total;
  }
  __syncthreads();
  total = sred[0];
  __syncthreads();
  return total;
}

// ---------------- fused: embed gather + LN(blk0) + all 5 weight transpose/decompose ------------
__global__ __launch_bounds__(256) void decomp_all_kernel(
    const float* __restrict__ Win, const float* __restrict__ Wout,
    const float* __restrict__ Wcls, const int* __restrict__ tok, const float* __restrict__ emb,
    const float* __restrict__ lnw0, const float* __restrict__ lnb0, float* __restrict__ x,
    __bf16* __restrict__ nxh, __bf16* __restrict__ nxl, __bf16* __restrict__ wih0,
    __bf16* __restrict__ wil0, __bf16* __restrict__ wih1, __bf16* __restrict__ wil1,
    __bf16* __restrict__ woh0, __bf16* __restrict__ wol0, __bf16* __restrict__ woh1,
    __bf16* __restrict__ wol1, __bf16* __restrict__ wch, __bf16* __restrict__ wcl) {
  constexpr int TIN = (NPAD_IN / 32) * (DMODEL / 32);    // 2592
  constexpr int TOUT = (DMODEL / 32) * (DINNER / 32);    // 1152
  constexpr int TCLS = (NPAD_CLS / 32) * (DMODEL / 32);  // 768
  __shared__ float tile[32][33];
  int bid = blockIdx.x;
  int tid = threadIdx.x;

  if (bid >= 2 * TIN + 2 * TOUT + TCLS) {
    int row = bid - (2 * TIN + 2 * TOUT + TCLS);
    int t = tok[row];
    float v[3];
    float s = 0.f;
#pragma unroll
    for (int j = 0; j < 3; ++j) {
      v[j] = emb[(size_t)t * DMODEL + tid + j * 256];
      s += v[j];
      x[(size_t)row * DMODEL + tid + j * 256] = v[j];
    }
    float* sred = (float*)tile;
    float mean = block_reduce_sum(s, sred) * (1.f / DMODEL);
    float s2 = 0.f;
#pragma unroll
    for (int j = 0; j < 3; ++j) {
      float d = v[j] - mean;
      s2 += d * d;
    }
    float var = block_reduce_sum(s2, sred) * (1.f / DMODEL);
    float r = 1.f / sqrtf(var + 1e-5f);
#pragma unroll
    for (int j = 0; j < 3; ++j) {
      int d = tid + j * 256;
      float val = (v[j] - mean) * r * lnw0[d] + lnb0[d];
      __bf16 h = (__bf16)val;
      nxh[(size_t)row * DMODEL + d] = h;
      nxl[(size_t)row * DMODEL + d] = (__bf16)(val - (float)h);
    }
    return;
  }

  const float* W;
  __bf16 *Th, *Tl;
  int K, N, ntx, r;
  if (bid < TIN) {
    W = Win; Th = wih0; Tl = wil0; K = DMODEL; N = DINPROJ; ntx = NPAD_IN / 32; r = bid;
  } else if (bid < 2 * TIN) {
    W = Win + (size_t)DMODEL * DINPROJ; Th = wih1; Tl = wil1; K = DMODEL; N = DINPROJ;
    ntx = NPAD_IN / 32; r = bid - TIN;
  } else if (bid < 2 * TIN + TOUT) {
    W = Wout; Th = woh0; Tl = wol0; K = DINNER; N = DMODEL; ntx = DMODEL / 32; r = bid - 2 * TIN;
  } else if (bid < 2 * TIN + 2 * TOUT) {
    W = Wout + (size_t)DINNER * DMODEL; Th = woh1; Tl = wol1; K = DINNER; N = DMODEL;
    ntx = DMODEL / 32; r = bid - 2 * TIN - TOUT;
  } else {
    W = Wcls; Th = wch; Tl = wcl; K = DMODEL; N = 1000; ntx = NPAD_CLS / 32;
    r = bid - 2 * TIN - 2 * TOUT;
  }
  int bn = (r % ntx) * 32, bk = (r / ntx) * 32;

  int i = tid >> 3, j4 = (tid & 7) * 4;
  int kk = bk + i;
  int nn = bn + j4;
  float4 v;
  if (nn + 3 < N) {
    v = *(const float4*)(W + (size_t)kk * N + nn);
  } else {
    v.x = (nn + 0 < N) ? W[(size_t)kk * N + nn + 0] : 0.f;
    v.y = (nn + 1 < N) ? W[(size_t)kk * N + nn + 1] : 0.f;
    v.z = (nn + 2 < N) ? W[(size_t)kk * N + nn + 2] : 0.f;
    v.w = (nn + 3 < N) ? W[(size_t)kk * N + nn + 3] : 0.f;
  }
  tile[i][j4 + 0] = v.x;
  tile[i][j4 + 1] = v.y;
  tile[i][j4 + 2] = v.z;
  tile[i][j4 + 3] = v.w;
  __syncthreads();
  int n = bn + i;
  bf16x4 hv, lv;
#pragma unroll
  for (int q = 0; q < 4; ++q) {
    float f = tile[j4 + q][i];
    __bf16 h = (__bf16)f;
    hv[q] = h;
    lv[q] = (__bf16)(f - (float)h);
  }
  *(bf16x4*)(Th + (size_t)n * K + bk + j4) = hv;
  *(bf16x4*)(Tl + (size_t)n * K + bk + j4) = lv;
}

// ---------------- layernorm -> bf16 hi/lo ----------------
__global__ __launch_bounds__(256) void ln_kernel(const float* __restrict__ x,
                                                 const float* __restrict__ w,
                                                 const float* __restrict__ b,
                                                 __bf16* __restrict__ oh,
                                                 __bf16* __restrict__ ol) {
  __shared__ float sred[8];
  int row = blockIdx.x, tid = threadIdx.x;
  const float* xr = x + (size_t)row * DMODEL;
  float v[3];
  float s = 0.f;
#pragma unroll
  for (int j = 0; j < 3; ++j) {
    v[j] = xr[tid + j * 256];
    s += v[j];
  }
  float mean = block_reduce_sum(s, sred) * (1.f / DMODEL);
  float s2 = 0.f;
#pragma unroll
  for (int j = 0; j < 3; ++j) {
    float d = v[j] - mean;
    s2 += d * d;
  }
  float var = block_reduce_sum(s2, sred) * (1.f / DMODEL);
  float r = 1.f / sqrtf(var + 1e-5f);
#pragma unroll
  for (int j = 0; j < 3; ++j) {
    int d = tid + j * 256;
    float val = (v[j] - mean) * r * w[d] + b[d];
    __bf16 h = (__bf16)val;
    oh[(size_t)row * DMODEL + d] = h;
    ol[(size_t)row * DMODEL + d] = (__bf16)(val - (float)h);
  }
}

// ---------------- x -> bf16 hi/lo ----------------
__global__ __launch_bounds__(256) void act_decomp_kernel(const float* __restrict__ x,
                                                         __bf16* __restrict__ oh,
                                                         __bf16* __restrict__ ol) {
  int row = blockIdx.x, tid = threadIdx.x;
#pragma unroll
  for (int j = 0; j < 3; ++j) {
    int d = tid + j * 256;
    float v = x[(size_t)row * DMODEL + d];
    __bf16 h = (__bf16)v;
    oh[(size_t)row * DMODEL + d] = h;
    ol[(size_t)row * DMODEL + d] = (__bf16)(v - (float)h);
  }
}

// ---------------- bf16x3 MFMA GEMM, 2-phase double-buffered staging ----------------
// If nbx>0: 1-D grid, bijective XCD swizzle, by-major within chunk (round-11 mapping).
// If additionally nby>0: 1-D grid covers (bx,by,kz) for ATOMIC split-K.
template <int FM, int FN, bool ATOMIC>
__global__ __launch_bounds__(256) void mfma_gemm_kernel(
    const __bf16* __restrict__ Ahi, const __bf16* __restrict__ Alo,
    const __bf16* __restrict__ Bhi, const __bf16* __restrict__ Blo,
    const float* __restrict__ addsrc, const float* __restrict__ bias, float* __restrict__ C,
    int N, int K, int kslice, int nbx, int nby, int nwg) {
  constexpr int BM = FM * 32;
  constexpr int BN = FN * 32;
  constexpr int RGA = BM / 16;
  constexpr int RGB = BN / 16;
  constexpr int NITER = (2 * (RGA + RGB)) / 4;
  constexpr int ABYTES = BM * 64;
  constexpr int BBYTES = BN * 64;
  constexpr int BUFBYTES = 2 * ABYTES + 2 * BBYTES;
  __shared__ char lds[2 * BUFBYTES];

  int tid = threadIdx.x;
  int wave = tid >> 6, lane = tid & 63;
  int wm = wave >> 1, wn = wave & 1;
  int bx, by, kz;
  if (nbx > 0) {
    int orig = (blockIdx.x % 8) * (nwg / 8) + blockIdx.x / 8;  // XCD-contiguous chunks
    bx = orig % nbx;
    int t = orig / nbx;
    if (nby > 0) {
      by = t % nby;
      kz = t / nby;
    } else {
      by = t;
      kz = 0;
    }
  } else {
    bx = blockIdx.x;
    by = blockIdx.y;
    kz = blockIdx.z;
  }
  int bm = by * BM;
  int bn = bx * BN;
  int kbeg = ATOMIC ? kz * kslice : 0;
  int kend = ATOMIC ? (kbeg + kslice) : K;
  int l2 = lane >> 2;
  int gch = (lane & 3) ^ ((lane >> 3) & 3);
  int lr = lane & 15, lg = lane >> 4;

  f32x4 acc[FM][FN] = {};

  auto stage = [&](char* buf, int k0) {
#pragma unroll
    for (int it = 0; it < NITER; ++it) {
      int rg = wave + it * 4;
      const __bf16* src;
      int row0, boff;
      if (rg < RGA) {
        src = Ahi;
        row0 = bm + rg * 16;
        boff = rg * 1024;
      } else if (rg < 2 * RGA) {
        src = Alo;
        row0 = bm + (rg - RGA) * 16;
        boff = ABYTES + (rg - RGA) * 1024;
      } else if (rg < 2 * RGA + RGB) {
        src = Bhi;
        row0 = bn + (rg - 2 * RGA) * 16;
        boff = 2 * ABYTES + (rg - 2 * RGA) * 1024;
      } else {
        src = Blo;
        row0 = bn + (rg - 2 * RGA - RGB) * 16;
        boff = 2 * ABYTES + BBYTES + (rg - 2 * RGA - RGB) * 1024;
      }
      gload16(src + (size_t)(row0 + l2) * K + k0 + gch * 8, buf + boff);
    }
  };

  stage(lds, kbeg);
  __syncthreads();

  char* curb = lds;
  char* nxtb = lds + BUFBYTES;
  for (int k0 = kbeg; k0 < kend; k0 += 32) {
    if (k0 + 32 < kend) stage(nxtb, k0 + 32);

    bf16x8 ahi[FM], alo[FM], bhi[FN], blo[FN];
#pragma unroll
    for (int m = 0; m < FM; ++m) {
      int r = wm * FM * 16 + m * 16 + lr;
      int off = r * 64 + ((lg ^ ((r >> 1) & 3)) * 16);
      ahi[m] = *(const bf16x8*)(curb + off);
      alo[m] = *(const bf16x8*)(curb + ABYTES + off);
    }
#pragma unroll
    for (int n = 0; n < FN; ++n) {
      int r = wn * FN * 16 + n * 16 + lr;
      int off = r * 64 + ((lg ^ ((r >> 1) & 3)) * 16);
      bhi[n] = *(const bf16x8*)(curb + 2 * ABYTES + off);
      blo[n] = *(const bf16x8*)(curb + 2 * ABYTES + BBYTES + off);
    }
#pragma unroll
    for (int m = 0; m < FM; ++m)
#pragma unroll
      for (int n = 0; n < FN; ++n) {
        acc[m][n] = __builtin_amdgcn_mfma_f32_16x16x32_bf16(ahi[m], bhi[n], acc[m][n], 0, 0, 0);
        acc[m][n] = __builtin_amdgcn_mfma_f32_16x16x32_bf16(ahi[m], blo[n], acc[m][n], 0, 0, 0);
        acc[m][n] = __builtin_amdgcn_mfma_f32_16x16x32_bf16(alo[m], bhi[n], acc[m][n], 0, 0, 0);
      }
    __syncthreads();
    char* t = curb;
    curb = nxtb;
    nxtb = t;
  }

#pragma unroll
  for (int m = 0; m < FM; ++m) {
#pragma unroll
    for (int n = 0; n < FN; ++n) {
      int gcol = bn + wn * FN * 16 + n * 16 + lr;
      if (gcol < N) {
#pragma unroll
        for (int r = 0; r < 4; ++r) {
          int grow = bm + wm * FM * 16 + m * 16 + lg * 4 + r;
          if (ATOMIC) {
            unsafeAtomicAdd(&C[(size_t)grow * N + gcol], acc[m][n][r]);
          } else {
            float v = acc[m][n][r];
            if (addsrc) v += addsrc[(size_t)grow * N + gcol];
            if (bias) v += bias[gcol];
            C[(size_t)grow * N + gcol] = v;
          }
        }
      }
    }
  }
}

// ---------------- conv+silu for shared B/C channels + dt softplus -> xBC, dts ----------------
__global__ __launch_bounds__(256) void convBC_kernel(const float* __restrict__ zx,
                                                     const float* __restrict__ cw,
                                                     const float* __restrict__ cb,
                                                     const float* __restrict__ dtb,
                                                     float* __restrict__ xBC,
                                                     float* __restrict__ dts) {
  int row = blockIdx.x;
  int c = threadIdx.x;  // 0..255
  int ch = DINNER + c;  // conv-channel index (B/C section)
  int l = row & (L_SEQ - 1);
  float acc = cb[ch];
#pragma unroll
  for (int k = 0; k < 4; ++k) {
    int ls = l - 3 + k;
    if (ls >= 0)
      acc = fmaf(cw[ch * 4 + k], zx[(size_t)(row - 3 + k) * DINPROJ + DINNER + ch], acc);
  }
  xBC[(size_t)row * BCDIM + c] = siluf(acc);
  if (c < NHEADS) {
    float raw = zx[(size_t)row * DINPROJ + DINNER + CONVDIM + c] + dtb[c];
    dts[(size_t)row * NHEADS + c] = softplusf(raw);
  }
}

// ---------------- Sraw = C . B^T per (batch, chunk) — head-independent, hoisted ----------------
__global__ __launch_bounds__(256) void sraw_kernel(const float* __restrict__ xBC,
                                                   float* __restrict__ Sraw) {
  __shared__ float Bs[CHUNK][132];
  __shared__ float Cs[CHUNK][132];
  int ci = blockIdx.x, b = blockIdx.y;
  int tid = threadIdx.x;
  int row0 = b * L_SEQ + ci * CHUNK;
#pragma unroll
  for (int i = 0; i < 4; ++i) {
    int vi = tid + i * 256;
    int t = vi >> 5;
    int n4 = (vi & 31) * 4;
    const float* r = xBC + (size_t)(row0 + t) * BCDIM;
    *(float4*)&Bs[t][n4] = *(const float4*)(r + n4);
    *(float4*)&Cs[t][n4] = *(const float4*)(r + DSTATE + n4);
  }
  __syncthreads();
  int t0 = (tid >> 4) * 2;
  int s0 = (tid & 15) * 2;
  float sacc[2][2] = {};
#pragma unroll
  for (int n = 0; n < DSTATE; n += 4) {
    float cr[2][4], br[2][4];
#pragma unroll
    for (int i = 0; i < 2; ++i) *(float4*)&cr[i][0] = *(const float4*)&Cs[t0 + i][n];
#pragma unroll
    for (int j = 0; j < 2; ++j) *(float4*)&br[j][0] = *(const float4*)&Bs[s0 + j][n];
#pragma unroll
    for (int i = 0; i < 2; ++i)
#pragma unroll
      for (int j = 0; j < 2; ++j)
#pragma unroll
        for (int k = 0; k < 4; ++k) sacc[i][j] = fmaf(cr[i][k], br[j][k], sacc[i][j]);
  }
  float* Sp = Sraw + ((size_t)(b * NCHUNK + ci) * CHUNK) * CHUNK;
#pragma unroll
  for (int i = 0; i < 2; ++i)
#pragma unroll
    for (int j = 0; j < 2; ++j) Sp[(t0 + i) * CHUNK + s0 + j] = sacc[i][j];
}

// ---------------- chunked SSD: fused X-conv + intra-chunk + chunk state (G -> bf16) ----------
__global__ __launch_bounds__(256) void chunk_local_kernel(
    const float* __restrict__ zx, const float* __restrict__ xBC, const float* __restrict__ Sraw,
    const float* __restrict__ dts, const float* __restrict__ cw, const float* __restrict__ cb,
    const float* __restrict__ Alog, const float* __restrict__ Dp, float* __restrict__ y,
    __bf16* __restrict__ G, float* __restrict__ et, float* __restrict__ elast) {
  __shared__ float Bs[CHUNK][132];
  __shared__ float Xs[CHUNK][68];
  __shared__ float Ss[CHUNK][36];
  __shared__ float sP[CHUNK], sW[CHUNK], sDt[CHUNK];

  int ci = blockIdx.x, h = blockIdx.y, b = blockIdx.z;
  int bh = b * NHEADS + h;
  int tid = threadIdx.x;
  int row0 = b * L_SEQ + ci * CHUNK;

#pragma unroll
  for (int i = 0; i < 2; ++i) {
    int vi = tid + i * 256;
    int t = vi >> 4;
    int n8 = (vi & 15) * 8;
    const float* r = xBC + (size_t)(row0 + t) * BCDIM;
    *(float4*)&Bs[t][n8] = *(const float4*)(r + n8);
    *(float4*)&Bs[t][n8 + 4] = *(const float4*)(r + n8 + 4);
  }
#pragma unroll
  for (int i = 0; i < 2; ++i) {
    int vi = tid + i * 256;
    int t = vi >> 4;
    int p4 = (vi & 15) * 4;
    int cX = h * HEADDIM + p4;
    float oX[4];
#pragma unroll
    for (int q = 0; q < 4; ++q) oX[q] = cb[cX + q];
#pragma unroll
    for (int k = 0; k < 4; ++k) {
      if (ci > 0 || t + k >= 3) {
        float4 v = *(const float4*)(zx + (size_t)(row0 + t - 3 + k) * DINPROJ + DINNER + cX);
#pragma unroll
        for (int q = 0; q < 4; ++q) oX[q] = fmaf(cw[(cX + q) * 4 + k], ((const float*)&v)[q], oX[q]);
      }
    }
#pragma unroll
    for (int q = 0; q < 4; ++q) Xs[t][p4 + q] = siluf(oX[q]);
  }
  if (tid < 32) {
    int t = tid;
    float Ah = -expf(Alog[h]);
    float dtv = dts[(size_t)(row0 + t) * NHEADS + h];
    float P = dtv * Ah;
#pragma unroll
    for (int off = 1; off < 32; off <<= 1) {
      float u = __shfl_up(P, off, 32);
      if (t >= off) P += u;
    }
    float Plast = __shfl(P, 31, 32);
    float e = expf(P);
    sP[t] = P;
    sDt[t] = dtv;
    sW[t] = expf(Plast - P) * dtv;
    et[(size_t)(bh * NCHUNK + ci) * CHUNK + t] = e;
    if (t == 31) elast[bh * NCHUNK + ci] = e;
  }
  __syncthreads();

  int t0 = (tid >> 4) * 2;
  int s0 = (tid & 15) * 2;
  {
    const float* Sp = Sraw + ((size_t)(b * NCHUNK + ci) * CHUNK) * CHUNK;
#pragma unroll
    for (int i = 0; i < 2; ++i)
#pragma unroll
      for (int j = 0; j < 2; ++j) {
        int t = t0 + i, s = s0 + j;
        float sr = Sp[t * CHUNK + s];
        Ss[t][s] = (t >= s) ? sr * expf(sP[t] - sP[s]) * sDt[s] : 0.f;
      }
  }
  __syncthreads();

  {
    int p0 = (tid & 15) * 4;
    float acc[2][4] = {};
#pragma unroll
    for (int s = 0; s < CHUNK; s += 4) {
      float sr[2][4], xr[4][4];
#pragma unroll
      for (int i = 0; i < 2; ++i) *(float4*)&sr[i][0] = *(const float4*)&Ss[t0 + i][s];
#pragma unroll
      for (int u = 0; u < 4; ++u) *(float4*)&xr[u][0] = *(const float4*)&Xs[s + u][p0];
#pragma unroll
      for (int i = 0; i < 2; ++i)
#pragma unroll
        for (int j = 0; j < 4; ++j)
#pragma unroll
          for (int u = 0; u < 4; ++u) acc[i][j] = fmaf(sr[i][u], xr[u][j], acc[i][j]);
    }
    float Dh = Dp[h];
#pragma unroll
    for (int i = 0; i < 2; ++i) {
      int row = row0 + t0 + i;
      float4 o;
      o.x = acc[i][0] + Dh * Xs[t0 + i][p0 + 0];
      o.y = acc[i][1] + Dh * Xs[t0 + i][p0 + 1];
      o.z = acc[i][2] + Dh * Xs[t0 + i][p0 + 2];
      o.w = acc[i][3] + Dh * Xs[t0 + i][p0 + 3];
      *(float4*)(y + (size_t)row * DINNER + h * HEADDIM + p0) = o;
    }
  }

  {
    int n0 = (tid >> 4) * 8;
    int p0 = (tid & 15) * 4;
    float g[8][4] = {};
#pragma unroll 4
    for (int s = 0; s < CHUNK; ++s) {
      float w = sW[s];
      float bv[8], xv[4];
      *(float4*)&bv[0] = *(const float4*)&Bs[s][n0];
      *(float4*)&bv[4] = *(const float4*)&Bs[s][n0 + 4];
      *(float4*)&xv[0] = *(const float4*)&Xs[s][p0];
#pragma unroll
      for (int k = 0; k < 8; ++k) {
        float wb = w * bv[k];
#pragma unroll
        for (int j = 0; j < 4; ++j) g[k][j] = fmaf(wb, xv[j], g[k][j]);
      }
    }
    __bf16* Gp = G + ((size_t)bh * NCHUNK + ci) * (DSTATE * HEADDIM);
#pragma unroll
    for (int k = 0; k < 8; ++k) {
      bf16x4 o;
#pragma unroll
      for (int q = 0; q < 4; ++q) o[q] = (__bf16)g[k][q];
      *(bf16x4*)(Gp + (size_t)(n0 + k) * HEADDIM + p0) = o;
    }
  }
}

// ---------------- combine chunk states (bf16 storage, fp32 running state) ----------------
__global__ __launch_bounds__(256) void combine_kernel(__bf16* __restrict__ G,
                                                      const float* __restrict__ elast) {
  int part = blockIdx.x;
  int bh = blockIdx.y;
  int gi = part * 256 + threadIdx.x;
  __bf16* base = G + (size_t)bh * NCHUNK * (DSTATE * HEADDIM);
  const float* el = elast + bh * NCHUNK;
  float h0 = 0.f, h1 = 0.f, h2 = 0.f, h3 = 0.f;
#pragma unroll
  for (int c = 0; c < NCHUNK - 1; ++c) {
    bf16x4 g = *(bf16x4*)(base + (size_t)c * (DSTATE * HEADDIM) + gi * 4);
    float e = el[c];
    h0 = fmaf(e, h0, (float)g[0]);
    h1 = fmaf(e, h1, (float)g[1]);
    h2 = fmaf(e, h2, (float)g[2]);
    h3 = fmaf(e, h3, (float)g[3]);
    bf16x4 o;
    o[0] = (__bf16)h0;
    o[1] = (__bf16)h1;
    o[2] = (__bf16)h2;
    o[3] = (__bf16)h3;
    *(bf16x4*)(base + (size_t)c * (DSTATE * HEADDIM) + gi * 4) = o;
  }
}

// ---------------- inter-chunk contribution ----------------
__global__ __launch_bounds__(256) void apply_inter_kernel(const float* __restrict__ xBC,
                                                          const __bf16* __restrict__ G,
                                                          const float* __restrict__ et,
                                                          float* __restrict__ y) {
  __shared__ float Cs[CHUNK][132];
  __shared__ float Hs[DSTATE][68];
  __shared__ float sE[CHUNK];
  int ci = blockIdx.x + 1;
  int h = blockIdx.y, b = blockIdx.z;
  int bh = b * NHEADS + h;
  int tid = threadIdx.x;
  int row0 = b * L_SEQ + ci * CHUNK;

#pragma unroll
  for (int i = 0; i < 4; ++i) {
    int vi = tid + i * 256;
    int t = vi >> 5;
    int n4 = (vi & 31) * 4;
    *(float4*)&Cs[t][n4] = *(const float4*)(xBC + (size_t)(row0 + t) * BCDIM + DSTATE + n4);
  }
  const __bf16* Hsrc = G + ((size_t)bh * NCHUNK + (ci - 1)) * (DSTATE * HEADDIM);
#pragma unroll
  for (int i = 0; i < 8; ++i) {
    int vi = tid + i * 256;
    int n = vi >> 4;
    int p4 = (vi & 15) * 4;
    bf16x4 g = *(const bf16x4*)(Hsrc + (size_t)n * HEADDIM + p4);
#pragma unroll
    for (int q = 0; q < 4; ++q) Hs[n][p4 + q] = (float)g[q];
  }
  if (tid < CHUNK) sE[tid] = et[(size_t)(bh * NCHUNK + ci) * CHUNK + tid];
  __syncthreads();

  int t0 = (tid >> 4) * 2;
  int p0 = (tid & 15) * 4;
  float acc[2][4] = {};
#pragma unroll
  for (int n = 0; n < DSTATE; n += 4) {
    float cr[2][4], hr[4][4];
#pragma unroll
    for (int i = 0; i < 2; ++i) *(float4*)&cr[i][0] = *(const float4*)&Cs[t0 + i][n];
#pragma unroll
    for (int u = 0; u < 4; ++u) *(float4*)&hr[u][0] = *(const float4*)&Hs[n + u][p0];
#pragma unroll
    for (int i = 0; i < 2; ++i)
#pragma unroll
      for (int j = 0; j < 4; ++j)
#pragma unroll
        for (int u = 0; u < 4; ++u) acc[i][j] = fmaf(cr[i][u], hr[u][j], acc[i][j]);
  }
#pragma unroll
  for (int i = 0; i < 2; ++i) {
    int row = row0 + t0 + i;
    float e = sE[t0 + i];
    float* yp = y + (size_t)row * DINNER + h * HEADDIM + p0;
    float4 cur = *(float4*)yp;
    cur.x = fmaf(e, acc[i][0], cur.x);
    cur.y = fmaf(e, acc[i][1], cur.y);
    cur.z = fmaf(e, acc[i][2], cur.z);
    cur.w = fmaf(e, acc[i][3], cur.w);
    *(float4*)yp = cur;
  }
}

// ---------------- gate (silu(z)) + RMS norm -> bf16 hi/lo ----------------
__global__ __launch_bounds__(256) void gate_rms_kernel(const float* __restrict__ y,
                                                       const float* __restrict__ zx,
                                                       const float* __restrict__ rmsw,
                                                       __bf16* __restrict__ oh,
                                                       __bf16* __restrict__ ol) {
  __shared__ float sred[8];
  int row = blockIdx.x, tid = threadIdx.x;
  const float* z = zx + (size_t)row * DINPROJ;
  const float* yr = y + (size_t)row * DINNER;
  float v[6];
  float ss = 0.f;
#pragma unroll
  for (int j = 0; j < 6; ++j) {
    int d = tid + j * 256;
    float val = yr[d] * siluf(z[d]);
    v[j] = val;
    ss += val * val;
  }
  float total = block_reduce_sum(ss, sred);
  float r = 1.f / sqrtf(total * (1.f / DINNER) + 1e-5f);
#pragma unroll
  for (int j = 0; j < 6; ++j) {
    int d = tid + j * 256;
    float val = v[j] * r * rmsw[d];
    __bf16 h = (__bf16)val;
    oh[(size_t)row * DINNER + d] = h;
    ol[(size_t)row * DINNER + d] = (__bf16)(val - (float)h);
  }
}

extern "C" void kernel_launch(void* const* d_in, const int* in_sizes, int n_in,
                              void* d_out, int out_size, void* d_ws, size_t ws_size,
                              hipStream_t stream) {
  const int* tokens = (const int*)d_in[0];
  const float* emb = (const float*)d_in[1];
  const float* ln_w = (const float*)d_in[2];
  const float* ln_b = (const float*)d_in[3];
  const float* Win = (const float*)d_in[4];
  const float* conv_w = (const float*)d_in[5];
  const float* conv_b = (const float*)d_in[6];
  const float* dt_bias = (const float*)d_in[7];
  const float* A_log = (const float*)d_in[8];
  const float* Dp = (const float*)d_in[9];
  const float* rms_w = (const float*)d_in[10];
  const float* Wout = (const float*)d_in[11];
  const float* Wcls = (const float*)d_in[12];
  const float* bcls = (const float*)d_in[13];
  float* out = (float*)d_out;

  float* ws = (float*)d_ws;
  float* x = ws;                                // 1024*768
  float* zx = x + (size_t)ROWS * DMODEL;        // 1024*3352
  float* y = zx + (size_t)ROWS * DINPROJ;       // 1024*1536
  __bf16* G = (__bf16*)(y + (size_t)ROWS * DINNER);  // 48*16*8192 bf16 (12.6MB)
  float* et = (float*)(G + (size_t)B_SZ * NHEADS * NCHUNK * DSTATE * HEADDIM);
  float* elast = et + (size_t)B_SZ * NHEADS * NCHUNK * CHUNK;
  float* xBC = elast + B_SZ * NHEADS * NCHUNK;  // 1024*256
  float* Sraw = xBC + (size_t)ROWS * BCDIM;     // 2*16*32*32
  float* dts = Sraw + (size_t)B_SZ * NCHUNK * CHUNK * CHUNK;  // 1024*24
  __bf16* bp = (__bf16*)(dts + (size_t)ROWS * NHEADS);
  __bf16* nxh = bp;  bp += (size_t)ROWS * DMODEL;
  __bf16* nxl = bp;  bp += (size_t)ROWS * DMODEL;
  __bf16* yh = bp;   bp += (size_t)ROWS * DINNER;
  __bf16* yl = bp;   bp += (size_t)ROWS * DINNER;
  __bf16* xh = bp;   bp += (size_t)ROWS * DMODEL;
  __bf16* xl = bp;   bp += (size_t)ROWS * DMODEL;
  __bf16* wih0 = bp; bp += (size_t)NPAD_IN * DMODEL;
  __bf16* wil0 = bp; bp += (size_t)NPAD_IN * DMODEL;
  __bf16* wih1 = bp; bp += (size_t)NPAD_IN * DMODEL;
  __bf16* wil1 = bp; bp += (size_t)NPAD_IN * DMODEL;
  __bf16* woh0 = bp; bp += (size_t)DMODEL * DINNER;
  __bf16* wol0 = bp; bp += (size_t)DMODEL * DINNER;
  __bf16* woh1 = bp; bp += (size_t)DMODEL * DINNER;
  __bf16* wol1 = bp; bp += (size_t)DMODEL * DINNER;
  __bf16* wch = bp;  bp += (size_t)NPAD_CLS * DMODEL;
  __bf16* wcl = bp;

  constexpr int TIN = (NPAD_IN / 32) * (DMODEL / 32);
  constexpr int TOUT = (DMODEL / 32) * (DINNER / 32);
  constexpr int TCLS = (NPAD_CLS / 32) * (DMODEL / 32);
  decomp_all_kernel<<<2 * TIN + 2 * TOUT + TCLS + ROWS, 256, 0, stream>>>(
      Win, Wout, Wcls, tokens, emb, ln_w, ln_b, x, nxh, nxl, wih0, wil0, wih1, wil1, woh0, wol0,
      woh1, wol1, wch, wcl);

  for (int blk = 0; blk < 2; ++blk) {
    const float* cw_b = conv_w + (size_t)blk * CONVDIM * 4;
    const float* cb_b = conv_b + (size_t)blk * CONVDIM;
    const float* dtb_b = dt_bias + (size_t)blk * NHEADS;
    const float* Alog_b = A_log + (size_t)blk * NHEADS;
    const float* Dp_b = Dp + (size_t)blk * NHEADS;
    const float* rmsw_b = rms_w + (size_t)blk * DINNER;
    __bf16* wih = blk ? wih1 : wih0;
    __bf16* wil = blk ? wil1 : wil0;
    __bf16* woh = blk ? woh1 : woh0;
    __bf16* wol = blk ? wol1 : wol0;

    if (blk == 1) {
      ln_kernel<<<ROWS, 256, 0, stream>>>(x, ln_w + (size_t)blk * DMODEL,
                                          ln_b + (size_t)blk * DMODEL, nxh, nxl);
    }

    // 1-D grid, round-11 by-major XCD swizzle: 54*16 = 864 blocks
    mfma_gemm_kernel<2, 2, false><<<(NPAD_IN / 64) * (ROWS / 64), 256, 0, stream>>>(
        nxh, nxl, wih, wil, nullptr, nullptr, zx, DINPROJ, DMODEL, 0, NPAD_IN / 64, 0,
        (NPAD_IN / 64) * (ROWS / 64));

    convBC_kernel<<<ROWS, BCDIM, 0, stream>>>(zx, cw_b, cb_b, dtb_b, xBC, dts);

    sraw_kernel<<<dim3(NCHUNK, B_SZ), 256, 0, stream>>>(xBC, Sraw);

    chunk_local_kernel<<<dim3(NCHUNK, NHEADS, B_SZ), 256, 0, stream>>>(
        zx, xBC, Sraw, dts, cw_b, cb_b, Alog_b, Dp_b, y, G, et, elast);

    combine_kernel<<<dim3(8, B_SZ * NHEADS), 256, 0, stream>>>(G, elast);

    apply_inter_kernel<<<dim3(NCHUNK - 1, NHEADS, B_SZ), 256, 0, stream>>>(xBC, G, et, y);

    gate_rms_kernel<<<ROWS, 256, 0, stream>>>(y, zx, rmsw_b, yh, yl);

    // out-proj split-K as 1-D 12*16*4 = 768 blocks with XCD swizzle (768 % 8 == 0)
    mfma_gemm_kernel<2, 2, true><<<(DMODEL / 64) * (ROWS / 64) * 4, 256, 0, stream>>>(
        yh, yl, woh, wol, nullptr, nullptr, x, DMODEL, DINNER, DINNER / 4, DMODEL / 64,
        ROWS / 64, (DMODEL / 64) * (ROWS / 64) * 4);
  }

  act_decomp_kernel<<<ROWS, 256, 0, stream>>>(x, xh, xl);
  // 1-D grid with XCD swizzle: 16*16 = 256 blocks
  mfma_gemm_kernel<2, 2, false><<<(NPAD_CLS / 64) * (ROWS / 64), 256, 0, stream>>>(
      xh, xl, wch, wcl, nullptr, bcls, out, 1000, DMODEL, 0, NPAD_CLS / 64, 0,
      (NPAD_CLS / 64) * (ROWS / 64));
}

// Round 14
// 239.997 us; speedup vs baseline: 1.0812x; 1.0342x over previous
//
#include <hip/hip_runtime.h>
#include <hip/hip_bf16.h>
#include <math.h>

#define B_SZ 2
#define L_SEQ 512
#define DMODEL 768
#define DINNER 1536
#define DSTATE 128
#define HEADDIM 64
#define NHEADS 24
#define CONVDIM 1792
#define DINPROJ 3352
#define ROWS (B_SZ * L_SEQ)  // 1024

#define CHUNK 32
#define NCHUNK (L_SEQ / CHUNK)  // 16
#define BCDIM (2 * DSTATE)      // 256

#define NPAD_IN 3456   // 54 * 64
#define NPAD_CLS 1024  // 16 * 64

typedef __attribute__((ext_vector_type(8))) __bf16 bf16x8;
typedef __attribute__((ext_vector_type(4))) __bf16 bf16x4;
typedef __attribute__((ext_vector_type(4))) float f32x4;

typedef __attribute__((address_space(1))) const unsigned int as1_u32;
typedef __attribute__((address_space(3))) unsigned int as3_u32;

__device__ __forceinline__ void gload16(const void* g, void* s) {
  __builtin_amdgcn_global_load_lds((as1_u32*)(unsigned long)g, (as3_u32*)(unsigned long)s, 16, 0,
                                   0);
}

__device__ __forceinline__ float siluf(float x) { return x / (1.f + expf(-x)); }
__device__ __forceinline__ float softplusf(float x) {
  return x > 0.f ? x + log1pf(expf(-x)) : log1pf(expf(x));
}

__device__ __forceinline__ float block_reduce_sum(float v, float* sred) {
  int tid = threadIdx.x;
  for (int off = 32; off; off >>= 1) v += __shfl_down(v, off, 64);
  int wid = tid >> 6, lane = tid & 63;
  if (lane == 0) sred[wid] = v;
  __syncthreads();
  float total;
  if (tid == 0) {
    total = 0.f;
    int nw = blockDim.x >> 6;
    for (int i = 0; i < nw; ++i) total += sred[i];
    sred[0] = total;
  }
  __syncthreads();
  total = sred[0];
  __syncthreads();
  return total;
}

// ---------------- fused: embed gather + LN(blk0) + all 5 weight transpose/decompose ------------
__global__ __launch_bounds__(256) void decomp_all_kernel(
    const float* __restrict__ Win, const float* __restrict__ Wout,
    const float* __restrict__ Wcls, const int* __restrict__ tok, const float* __restrict__ emb,
    const float* __restrict__ lnw0, const float* __restrict__ lnb0, float* __restrict__ x,
    __bf16* __restrict__ nxh, __bf16* __restrict__ nxl, __bf16* __restrict__ wih0,
    __bf16* __restrict__ wil0, __bf16* __restrict__ wih1, __bf16* __restrict__ wil1,
    __bf16* __restrict__ woh0, __bf16* __restrict__ wol0, __bf16* __restrict__ woh1,
    __bf16* __restrict__ wol1, __bf16* __restrict__ wch, __bf16* __restrict__ wcl) {
  constexpr int TIN = (NPAD_IN / 32) * (DMODEL / 32);    // 2592
  constexpr int TOUT = (DMODEL / 32) * (DINNER / 32);    // 1152
  constexpr int TCLS = (NPAD_CLS / 32) * (DMODEL / 32);  // 768
  __shared__ float tile[32][33];
  int bid = blockIdx.x;
  int tid = threadIdx.x;

  if (bid >= 2 * TIN + 2 * TOUT + TCLS) {
    int row = bid - (2 * TIN + 2 * TOUT + TCLS);
    int t = tok[row];
    float v[3];
    float s = 0.f;
#pragma unroll
    for (int j = 0; j < 3; ++j) {
      v[j] = emb[(size_t)t * DMODEL + tid + j * 256];
      s += v[j];
      x[(size_t)row * DMODEL + tid + j * 256] = v[j];
    }
    float* sred = (float*)tile;
    float mean = block_reduce_sum(s, sred) * (1.f / DMODEL);
    float s2 = 0.f;
#pragma unroll
    for (int j = 0; j < 3; ++j) {
      float d = v[j] - mean;
      s2 += d * d;
    }
    float var = block_reduce_sum(s2, sred) * (1.f / DMODEL);
    float r = 1.f / sqrtf(var + 1e-5f);
#pragma unroll
    for (int j = 0; j < 3; ++j) {
      int d = tid + j * 256;
      float val = (v[j] - mean) * r * lnw0[d] + lnb0[d];
      __bf16 h = (__bf16)val;
      nxh[(size_t)row * DMODEL + d] = h;
      nxl[(size_t)row * DMODEL + d] = (__bf16)(val - (float)h);
    }
    return;
  }

  const float* W;
  __bf16 *Th, *Tl;
  int K, N, ntx, r;
  if (bid < TIN) {
    W = Win; Th = wih0; Tl = wil0; K = DMODEL; N = DINPROJ; ntx = NPAD_IN / 32; r = bid;
  } else if (bid < 2 * TIN) {
    W = Win + (size_t)DMODEL * DINPROJ; Th = wih1; Tl = wil1; K = DMODEL; N = DINPROJ;
    ntx = NPAD_IN / 32; r = bid - TIN;
  } else if (bid < 2 * TIN + TOUT) {
    W = Wout; Th = woh0; Tl = wol0; K = DINNER; N = DMODEL; ntx = DMODEL / 32; r = bid - 2 * TIN;
  } else if (bid < 2 * TIN + 2 * TOUT) {
    W = Wout + (size_t)DINNER * DMODEL; Th = woh1; Tl = wol1; K = DINNER; N = DMODEL;
    ntx = DMODEL / 32; r = bid - 2 * TIN - TOUT;
  } else {
    W = Wcls; Th = wch; Tl = wcl; K = DMODEL; N = 1000; ntx = NPAD_CLS / 32;
    r = bid - 2 * TIN - 2 * TOUT;
  }
  int bn = (r % ntx) * 32, bk = (r / ntx) * 32;

  int i = tid >> 3, j4 = (tid & 7) * 4;
  int kk = bk + i;
  int nn = bn + j4;
  float4 v;
  if (nn + 3 < N) {
    v = *(const float4*)(W + (size_t)kk * N + nn);
  } else {
    v.x = (nn + 0 < N) ? W[(size_t)kk * N + nn + 0] : 0.f;
    v.y = (nn + 1 < N) ? W[(size_t)kk * N + nn + 1] : 0.f;
    v.z = (nn + 2 < N) ? W[(size_t)kk * N + nn + 2] : 0.f;
    v.w = (nn + 3 < N) ? W[(size_t)kk * N + nn + 3] : 0.f;
  }
  tile[i][j4 + 0] = v.x;
  tile[i][j4 + 1] = v.y;
  tile[i][j4 + 2] = v.z;
  tile[i][j4 + 3] = v.w;
  __syncthreads();
  int n = bn + i;
  bf16x4 hv, lv;
#pragma unroll
  for (int q = 0; q < 4; ++q) {
    float f = tile[j4 + q][i];
    __bf16 h = (__bf16)f;
    hv[q] = h;
    lv[q] = (__bf16)(f - (float)h);
  }
  *(bf16x4*)(Th + (size_t)n * K + bk + j4) = hv;
  *(bf16x4*)(Tl + (size_t)n * K + bk + j4) = lv;
}

// ---------------- layernorm -> bf16 hi/lo ----------------
__global__ __launch_bounds__(256) void ln_kernel(const float* __restrict__ x,
                                                 const float* __restrict__ w,
                                                 const float* __restrict__ b,
                                                 __bf16* __restrict__ oh,
                                                 __bf16* __restrict__ ol) {
  __shared__ float sred[8];
  int row = blockIdx.x, tid = threadIdx.x;
  const float* xr = x + (size_t)row * DMODEL;
  float v[3];
  float s = 0.f;
#pragma unroll
  for (int j = 0; j < 3; ++j) {
    v[j] = xr[tid + j * 256];
    s += v[j];
  }
  float mean = block_reduce_sum(s, sred) * (1.f / DMODEL);
  float s2 = 0.f;
#pragma unroll
  for (int j = 0; j < 3; ++j) {
    float d = v[j] - mean;
    s2 += d * d;
  }
  float var = block_reduce_sum(s2, sred) * (1.f / DMODEL);
  float r = 1.f / sqrtf(var + 1e-5f);
#pragma unroll
  for (int j = 0; j < 3; ++j) {
    int d = tid + j * 256;
    float val = (v[j] - mean) * r * w[d] + b[d];
    __bf16 h = (__bf16)val;
    oh[(size_t)row * DMODEL + d] = h;
    ol[(size_t)row * DMODEL + d] = (__bf16)(val - (float)h);
  }
}

// ---------------- x -> bf16 hi/lo ----------------
__global__ __launch_bounds__(256) void act_decomp_kernel(const float* __restrict__ x,
                                                         __bf16* __restrict__ oh,
                                                         __bf16* __restrict__ ol) {
  int row = blockIdx.x, tid = threadIdx.x;
#pragma unroll
  for (int j = 0; j < 3; ++j) {
    int d = tid + j * 256;
    float v = x[(size_t)row * DMODEL + d];
    __bf16 h = (__bf16)v;
    oh[(size_t)row * DMODEL + d] = h;
    ol[(size_t)row * DMODEL + d] = (__bf16)(v - (float)h);
  }
}

// ---------------- bf16x3 MFMA GEMM, 2-phase double-buffered staging ----------------
template <int FM, int FN, bool ATOMIC>
__global__ __launch_bounds__(256) void mfma_gemm_kernel(
    const __bf16* __restrict__ Ahi, const __bf16* __restrict__ Alo,
    const __bf16* __restrict__ Bhi, const __bf16* __restrict__ Blo,
    const float* __restrict__ addsrc, const float* __restrict__ bias, float* __restrict__ C,
    int N, int K, int kslice, int nbx, int nby, int nwg) {
  constexpr int BM = FM * 32;
  constexpr int BN = FN * 32;
  constexpr int RGA = BM / 16;
  constexpr int RGB = BN / 16;
  constexpr int NITER = (2 * (RGA + RGB)) / 4;
  constexpr int ABYTES = BM * 64;
  constexpr int BBYTES = BN * 64;
  constexpr int BUFBYTES = 2 * ABYTES + 2 * BBYTES;
  __shared__ char lds[2 * BUFBYTES];

  int tid = threadIdx.x;
  int wave = tid >> 6, lane = tid & 63;
  int wm = wave >> 1, wn = wave & 1;
  int bx, by, kz;
  if (nbx > 0) {
    int orig = (blockIdx.x % 8) * (nwg / 8) + blockIdx.x / 8;
    bx = orig % nbx;
    int t = orig / nbx;
    if (nby > 0) {
      by = t % nby;
      kz = t / nby;
    } else {
      by = t;
      kz = 0;
    }
  } else {
    bx = blockIdx.x;
    by = blockIdx.y;
    kz = blockIdx.z;
  }
  int bm = by * BM;
  int bn = bx * BN;
  int kbeg = ATOMIC ? kz * kslice : 0;
  int kend = ATOMIC ? (kbeg + kslice) : K;
  int l2 = lane >> 2;
  int gch = (lane & 3) ^ ((lane >> 3) & 3);
  int lr = lane & 15, lg = lane >> 4;

  f32x4 acc[FM][FN] = {};

  auto stage = [&](char* buf, int k0) {
#pragma unroll
    for (int it = 0; it < NITER; ++it) {
      int rg = wave + it * 4;
      const __bf16* src;
      int row0, boff;
      if (rg < RGA) {
        src = Ahi;
        row0 = bm + rg * 16;
        boff = rg * 1024;
      } else if (rg < 2 * RGA) {
        src = Alo;
        row0 = bm + (rg - RGA) * 16;
        boff = ABYTES + (rg - RGA) * 1024;
      } else if (rg < 2 * RGA + RGB) {
        src = Bhi;
        row0 = bn + (rg - 2 * RGA) * 16;
        boff = 2 * ABYTES + (rg - 2 * RGA) * 1024;
      } else {
        src = Blo;
        row0 = bn + (rg - 2 * RGA - RGB) * 16;
        boff = 2 * ABYTES + BBYTES + (rg - 2 * RGA - RGB) * 1024;
      }
      gload16(src + (size_t)(row0 + l2) * K + k0 + gch * 8, buf + boff);
    }
  };

  stage(lds, kbeg);
  __syncthreads();

  char* curb = lds;
  char* nxtb = lds + BUFBYTES;
  for (int k0 = kbeg; k0 < kend; k0 += 32) {
    if (k0 + 32 < kend) stage(nxtb, k0 + 32);

    bf16x8 ahi[FM], alo[FM], bhi[FN], blo[FN];
#pragma unroll
    for (int m = 0; m < FM; ++m) {
      int r = wm * FM * 16 + m * 16 + lr;
      int off = r * 64 + ((lg ^ ((r >> 1) & 3)) * 16);
      ahi[m] = *(const bf16x8*)(curb + off);
      alo[m] = *(const bf16x8*)(curb + ABYTES + off);
    }
#pragma unroll
    for (int n = 0; n < FN; ++n) {
      int r = wn * FN * 16 + n * 16 + lr;
      int off = r * 64 + ((lg ^ ((r >> 1) & 3)) * 16);
      bhi[n] = *(const bf16x8*)(curb + 2 * ABYTES + off);
      blo[n] = *(const bf16x8*)(curb + 2 * ABYTES + BBYTES + off);
    }
#pragma unroll
    for (int m = 0; m < FM; ++m)
#pragma unroll
      for (int n = 0; n < FN; ++n) {
        acc[m][n] = __builtin_amdgcn_mfma_f32_16x16x32_bf16(ahi[m], bhi[n], acc[m][n], 0, 0, 0);
        acc[m][n] = __builtin_amdgcn_mfma_f32_16x16x32_bf16(ahi[m], blo[n], acc[m][n], 0, 0, 0);
        acc[m][n] = __builtin_amdgcn_mfma_f32_16x16x32_bf16(alo[m], bhi[n], acc[m][n], 0, 0, 0);
      }
    __syncthreads();
    char* t = curb;
    curb = nxtb;
    nxtb = t;
  }

#pragma unroll
  for (int m = 0; m < FM; ++m) {
#pragma unroll
    for (int n = 0; n < FN; ++n) {
      int gcol = bn + wn * FN * 16 + n * 16 + lr;
      if (gcol < N) {
#pragma unroll
        for (int r = 0; r < 4; ++r) {
          int grow = bm + wm * FM * 16 + m * 16 + lg * 4 + r;
          if (ATOMIC) {
            unsafeAtomicAdd(&C[(size_t)grow * N + gcol], acc[m][n][r]);
          } else {
            float v = acc[m][n][r];
            if (addsrc) v += addsrc[(size_t)grow * N + gcol];
            if (bias) v += bias[gcol];
            C[(size_t)grow * N + gcol] = v;
          }
        }
      }
    }
  }
}

// ---------------- conv+silu for shared B/C channels + dt softplus -> xBC, dts ----------------
__global__ __launch_bounds__(256) void convBC_kernel(const float* __restrict__ zx,
                                                     const float* __restrict__ cw,
                                                     const float* __restrict__ cb,
                                                     const float* __restrict__ dtb,
                                                     float* __restrict__ xBC,
                                                     float* __restrict__ dts) {
  int row = blockIdx.x;
  int c = threadIdx.x;  // 0..255
  int ch = DINNER + c;  // conv-channel index (B/C section)
  int l = row & (L_SEQ - 1);
  float acc = cb[ch];
#pragma unroll
  for (int k = 0; k < 4; ++k) {
    int ls = l - 3 + k;
    if (ls >= 0)
      acc = fmaf(cw[ch * 4 + k], zx[(size_t)(row - 3 + k) * DINPROJ + DINNER + ch], acc);
  }
  xBC[(size_t)row * BCDIM + c] = siluf(acc);
  if (c < NHEADS) {
    float raw = zx[(size_t)row * DINPROJ + DINNER + CONVDIM + c] + dtb[c];
    dts[(size_t)row * NHEADS + c] = softplusf(raw);
  }
}

// ---------------- Sraw = C . B^T per (batch, chunk) — head-independent, hoisted ----------------
__global__ __launch_bounds__(256) void sraw_kernel(const float* __restrict__ xBC,
                                                   float* __restrict__ Sraw) {
  __shared__ float Bs[CHUNK][132];
  __shared__ float Cs[CHUNK][132];
  int ci = blockIdx.x, b = blockIdx.y;
  int tid = threadIdx.x;
  int row0 = b * L_SEQ + ci * CHUNK;
#pragma unroll
  for (int i = 0; i < 4; ++i) {
    int vi = tid + i * 256;
    int t = vi >> 5;
    int n4 = (vi & 31) * 4;
    const float* r = xBC + (size_t)(row0 + t) * BCDIM;
    *(float4*)&Bs[t][n4] = *(const float4*)(r + n4);
    *(float4*)&Cs[t][n4] = *(const float4*)(r + DSTATE + n4);
  }
  __syncthreads();
  int t0 = (tid >> 4) * 2;
  int s0 = (tid & 15) * 2;
  float sacc[2][2] = {};
#pragma unroll
  for (int n = 0; n < DSTATE; n += 4) {
    float cr[2][4], br[2][4];
#pragma unroll
    for (int i = 0; i < 2; ++i) *(float4*)&cr[i][0] = *(const float4*)&Cs[t0 + i][n];
#pragma unroll
    for (int j = 0; j < 2; ++j) *(float4*)&br[j][0] = *(const float4*)&Bs[s0 + j][n];
#pragma unroll
    for (int i = 0; i < 2; ++i)
#pragma unroll
      for (int j = 0; j < 2; ++j)
#pragma unroll
        for (int k = 0; k < 4; ++k) sacc[i][j] = fmaf(cr[i][k], br[j][k], sacc[i][j]);
  }
  float* Sp = Sraw + ((size_t)(b * NCHUNK + ci) * CHUNK) * CHUNK;
#pragma unroll
  for (int i = 0; i < 2; ++i)
#pragma unroll
    for (int j = 0; j < 2; ++j) Sp[(t0 + i) * CHUNK + s0 + j] = sacc[i][j];
}

// ---------------- chunked SSD: fused X-conv + intra-chunk + chunk state ----------
// G is stored TRANSPOSED and chunk-swizzled: Gt[bh][ci][p][cs*8..], cs = (n/8) ^ (p&7).
__global__ __launch_bounds__(256) void chunk_local_kernel(
    const float* __restrict__ zx, const float* __restrict__ xBC, const float* __restrict__ Sraw,
    const float* __restrict__ dts, const float* __restrict__ cw, const float* __restrict__ cb,
    const float* __restrict__ Alog, const float* __restrict__ Dp, float* __restrict__ y,
    __bf16* __restrict__ Gt, float* __restrict__ et, float* __restrict__ elast) {
  __shared__ float Bs[CHUNK][132];
  __shared__ float Xs[CHUNK][68];
  __shared__ float Ss[CHUNK][36];
  __shared__ float sP[CHUNK], sW[CHUNK], sDt[CHUNK];

  int ci = blockIdx.x, h = blockIdx.y, b = blockIdx.z;
  int bh = b * NHEADS + h;
  int tid = threadIdx.x;
  int row0 = b * L_SEQ + ci * CHUNK;

#pragma unroll
  for (int i = 0; i < 2; ++i) {
    int vi = tid + i * 256;
    int t = vi >> 4;
    int n8 = (vi & 15) * 8;
    const float* r = xBC + (size_t)(row0 + t) * BCDIM;
    *(float4*)&Bs[t][n8] = *(const float4*)(r + n8);
    *(float4*)&Bs[t][n8 + 4] = *(const float4*)(r + n8 + 4);
  }
#pragma unroll
  for (int i = 0; i < 2; ++i) {
    int vi = tid + i * 256;
    int t = vi >> 4;
    int p4 = (vi & 15) * 4;
    int cX = h * HEADDIM + p4;
    float oX[4];
#pragma unroll
    for (int q = 0; q < 4; ++q) oX[q] = cb[cX + q];
#pragma unroll
    for (int k = 0; k < 4; ++k) {
      if (ci > 0 || t + k >= 3) {
        float4 v = *(const float4*)(zx + (size_t)(row0 + t - 3 + k) * DINPROJ + DINNER + cX);
#pragma unroll
        for (int q = 0; q < 4; ++q) oX[q] = fmaf(cw[(cX + q) * 4 + k], ((const float*)&v)[q], oX[q]);
      }
    }
#pragma unroll
    for (int q = 0; q < 4; ++q) Xs[t][p4 + q] = siluf(oX[q]);
  }
  if (tid < 32) {
    int t = tid;
    float Ah = -expf(Alog[h]);
    float dtv = dts[(size_t)(row0 + t) * NHEADS + h];
    float P = dtv * Ah;
#pragma unroll
    for (int off = 1; off < 32; off <<= 1) {
      float u = __shfl_up(P, off, 32);
      if (t >= off) P += u;
    }
    float Plast = __shfl(P, 31, 32);
    float e = expf(P);
    sP[t] = P;
    sDt[t] = dtv;
    sW[t] = expf(Plast - P) * dtv;
    et[(size_t)(bh * NCHUNK + ci) * CHUNK + t] = e;
    if (t == 31) elast[bh * NCHUNK + ci] = e;
  }
  __syncthreads();

  int t0 = (tid >> 4) * 2;
  int s0 = (tid & 15) * 2;
  {
    const float* Sp = Sraw + ((size_t)(b * NCHUNK + ci) * CHUNK) * CHUNK;
#pragma unroll
    for (int i = 0; i < 2; ++i)
#pragma unroll
      for (int j = 0; j < 2; ++j) {
        int t = t0 + i, s = s0 + j;
        float sr = Sp[t * CHUNK + s];
        Ss[t][s] = (t >= s) ? sr * expf(sP[t] - sP[s]) * sDt[s] : 0.f;
      }
  }
  __syncthreads();

  {
    int p0 = (tid & 15) * 4;
    float acc[2][4] = {};
#pragma unroll
    for (int s = 0; s < CHUNK; s += 4) {
      float sr[2][4], xr[4][4];
#pragma unroll
      for (int i = 0; i < 2; ++i) *(float4*)&sr[i][0] = *(const float4*)&Ss[t0 + i][s];
#pragma unroll
      for (int u = 0; u < 4; ++u) *(float4*)&xr[u][0] = *(const float4*)&Xs[s + u][p0];
#pragma unroll
      for (int i = 0; i < 2; ++i)
#pragma unroll
        for (int j = 0; j < 4; ++j)
#pragma unroll
          for (int u = 0; u < 4; ++u) acc[i][j] = fmaf(sr[i][u], xr[u][j], acc[i][j]);
    }
    float Dh = Dp[h];
#pragma unroll
    for (int i = 0; i < 2; ++i) {
      int row = row0 + t0 + i;
      float4 o;
      o.x = acc[i][0] + Dh * Xs[t0 + i][p0 + 0];
      o.y = acc[i][1] + Dh * Xs[t0 + i][p0 + 1];
      o.z = acc[i][2] + Dh * Xs[t0 + i][p0 + 2];
      o.w = acc[i][3] + Dh * Xs[t0 + i][p0 + 3];
      *(float4*)(y + (size_t)row * DINNER + h * HEADDIM + p0) = o;
    }
  }

  {
    int n0 = (tid >> 4) * 8;  // chunk index c = tid>>4 (0..15)
    int p0 = (tid & 15) * 4;
    float g[8][4] = {};
#pragma unroll 4
    for (int s = 0; s < CHUNK; ++s) {
      float w = sW[s];
      float bv[8], xv[4];
      *(float4*)&bv[0] = *(const float4*)&Bs[s][n0];
      *(float4*)&bv[4] = *(const float4*)&Bs[s][n0 + 4];
      *(float4*)&xv[0] = *(const float4*)&Xs[s][p0];
#pragma unroll
      for (int k = 0; k < 8; ++k) {
        float wb = w * bv[k];
#pragma unroll
        for (int j = 0; j < 4; ++j) g[k][j] = fmaf(wb, xv[j], g[k][j]);
      }
    }
    // transposed, chunk-swizzled store: Gt[p][cs] = g[.][j] column
    __bf16* Gp = Gt + ((size_t)bh * NCHUNK + ci) * (DSTATE * HEADDIM);
    int cchunk = tid >> 4;
#pragma unroll
    for (int j = 0; j < 4; ++j) {
      int p = p0 + j;
      int cs = cchunk ^ (p & 7);
      bf16x8 o;
#pragma unroll
      for (int k = 0; k < 8; ++k) o[k] = (__bf16)g[k][j];
      *(bf16x8*)(Gp + (size_t)p * DSTATE + cs * 8) = o;
    }
  }
}

// ---------------- combine chunk states (bf16 storage; elementwise, layout-agnostic) -----------
__global__ __launch_bounds__(256) void combine_kernel(__bf16* __restrict__ G,
                                                      const float* __restrict__ elast) {
  int part = blockIdx.x;
  int bh = blockIdx.y;
  int gi = part * 256 + threadIdx.x;
  __bf16* base = G + (size_t)bh * NCHUNK * (DSTATE * HEADDIM);
  const float* el = elast + bh * NCHUNK;
  float h0 = 0.f, h1 = 0.f, h2 = 0.f, h3 = 0.f;
#pragma unroll
  for (int c = 0; c < NCHUNK - 1; ++c) {
    bf16x4 g = *(bf16x4*)(base + (size_t)c * (DSTATE * HEADDIM) + gi * 4);
    float e = el[c];
    h0 = fmaf(e, h0, (float)g[0]);
    h1 = fmaf(e, h1, (float)g[1]);
    h2 = fmaf(e, h2, (float)g[2]);
    h3 = fmaf(e, h3, (float)g[3]);
    bf16x4 o;
    o[0] = (__bf16)h0;
    o[1] = (__bf16)h1;
    o[2] = (__bf16)h2;
    o[3] = (__bf16)h3;
    *(bf16x4*)(base + (size_t)c * (DSTATE * HEADDIM) + gi * 4) = o;
  }
}

// ---------------- inter-chunk contribution: MFMA bf16 (C 32x128 @ Ht^T 128x64) ---------------
__global__ __launch_bounds__(256) void apply_inter_kernel(const float* __restrict__ xBC,
                                                          const __bf16* __restrict__ Gt,
                                                          const float* __restrict__ et,
                                                          float* __restrict__ y) {
  __shared__ __bf16 CsB[CHUNK * DSTATE];   // [t][128] bf16, chunk-swizzled
  __shared__ __bf16 HsB[HEADDIM * DSTATE]; // [p][128] bf16, pre-swizzled global -> linear stage
  __shared__ float sE[CHUNK];
  int ci = blockIdx.x + 1;
  int h = blockIdx.y, b = blockIdx.z;
  int bh = b * NHEADS + h;
  int tid = threadIdx.x;
  int wave = tid >> 6, lane = tid & 63;
  int row0 = b * L_SEQ + ci * CHUNK;

  // stage Ht (16 KB) linearly via global_load_lds (global already transposed+swizzled)
  const __bf16* Hsrc = Gt + ((size_t)bh * NCHUNK + (ci - 1)) * (DSTATE * HEADDIM);
#pragma unroll
  for (int r = 0; r < 4; ++r) {
    gload16(Hsrc + (size_t)r * 2048 + wave * 512 + lane * 8,
            (char*)HsB + r * 4096 + wave * 1024);
  }
  // stage C tile: fp32 -> bf16, chunk-swizzled write
#pragma unroll
  for (int i = 0; i < 2; ++i) {
    int vi = tid + i * 256;  // 512 chunks of 8 elems
    int t = vi >> 4;
    int c = vi & 15;
    const float* src = xBC + (size_t)(row0 + t) * BCDIM + DSTATE + c * 8;
    float4 v0 = *(const float4*)src;
    float4 v1 = *(const float4*)(src + 4);
    bf16x8 o;
    o[0] = (__bf16)v0.x; o[1] = (__bf16)v0.y; o[2] = (__bf16)v0.z; o[3] = (__bf16)v0.w;
    o[4] = (__bf16)v1.x; o[5] = (__bf16)v1.y; o[6] = (__bf16)v1.z; o[7] = (__bf16)v1.w;
    int cs = c ^ (t & 7);
    *(bf16x8*)&CsB[t * DSTATE + cs * 8] = o;
  }
  if (tid < CHUNK) sE[tid] = et[(size_t)(bh * NCHUNK + ci) * CHUNK + tid];
  __syncthreads();

  int lr = lane & 15, lg = lane >> 4;
  int wm = wave >> 1;        // m block 0..1 (t half)
  int wnb = (wave & 1) * 2;  // n block base 0 or 2 (p quarters)
  f32x4 acc[2] = {};
#pragma unroll
  for (int ks = 0; ks < 4; ++ks) {
    int ar = wm * 16 + lr;
    bf16x8 af = *(const bf16x8*)&CsB[ar * DSTATE + (((ks * 4 + lg) ^ (ar & 7)) * 8)];
#pragma unroll
    for (int nn = 0; nn < 2; ++nn) {
      int br = (wnb + nn) * 16 + lr;
      bf16x8 bfr = *(const bf16x8*)&HsB[br * DSTATE + (((ks * 4 + lg) ^ (br & 7)) * 8)];
      acc[nn] = __builtin_amdgcn_mfma_f32_16x16x32_bf16(af, bfr, acc[nn], 0, 0, 0);
    }
  }
#pragma unroll
  for (int nn = 0; nn < 2; ++nn) {
    int p = (wnb + nn) * 16 + lr;
#pragma unroll
    for (int r = 0; r < 4; ++r) {
      int t = wm * 16 + lg * 4 + r;
      float e = sE[t];
      float* yp = &y[(size_t)(row0 + t) * DINNER + h * HEADDIM + p];
      *yp = fmaf(e, acc[nn][r], *yp);
    }
  }
}

// ---------------- gate (silu(z)) + RMS norm -> bf16 hi/lo ----------------
__global__ __launch_bounds__(256) void gate_rms_kernel(const float* __restrict__ y,
                                                       const float* __restrict__ zx,
                                                       const float* __restrict__ rmsw,
                                                       __bf16* __restrict__ oh,
                                                       __bf16* __restrict__ ol) {
  __shared__ float sred[8];
  int row = blockIdx.x, tid = threadIdx.x;
  const float* z = zx + (size_t)row * DINPROJ;
  const float* yr = y + (size_t)row * DINNER;
  float v[6];
  float ss = 0.f;
#pragma unroll
  for (int j = 0; j < 6; ++j) {
    int d = tid + j * 256;
    float val = yr[d] * siluf(z[d]);
    v[j] = val;
    ss += val * val;
  }
  float total = block_reduce_sum(ss, sred);
  float r = 1.f / sqrtf(total * (1.f / DINNER) + 1e-5f);
#pragma unroll
  for (int j = 0; j < 6; ++j) {
    int d = tid + j * 256;
    float val = v[j] * r * rmsw[d];
    __bf16 h = (__bf16)val;
    oh[(size_t)row * DINNER + d] = h;
    ol[(size_t)row * DINNER + d] = (__bf16)(val - (float)h);
  }
}

extern "C" void kernel_launch(void* const* d_in, const int* in_sizes, int n_in,
                              void* d_out, int out_size, void* d_ws, size_t ws_size,
                              hipStream_t stream) {
  const int* tokens = (const int*)d_in[0];
  const float* emb = (const float*)d_in[1];
  const float* ln_w = (const float*)d_in[2];
  const float* ln_b = (const float*)d_in[3];
  const float* Win = (const float*)d_in[4];
  const float* conv_w = (const float*)d_in[5];
  const float* conv_b = (const float*)d_in[6];
  const float* dt_bias = (const float*)d_in[7];
  const float* A_log = (const float*)d_in[8];
  const float* Dp = (const float*)d_in[9];
  const float* rms_w = (const float*)d_in[10];
  const float* Wout = (const float*)d_in[11];
  const float* Wcls = (const float*)d_in[12];
  const float* bcls = (const float*)d_in[13];
  float* out = (float*)d_out;

  float* ws = (float*)d_ws;
  float* x = ws;                                // 1024*768
  float* zx = x + (size_t)ROWS * DMODEL;        // 1024*3352
  float* y = zx + (size_t)ROWS * DINPROJ;       // 1024*1536
  __bf16* Gt = (__bf16*)(y + (size_t)ROWS * DINNER);  // 48*16*8192 bf16, transposed+swizzled
  float* et = (float*)(Gt + (size_t)B_SZ * NHEADS * NCHUNK * DSTATE * HEADDIM);
  float* elast = et + (size_t)B_SZ * NHEADS * NCHUNK * CHUNK;
  float* xBC = elast + B_SZ * NHEADS * NCHUNK;  // 1024*256
  float* Sraw = xBC + (size_t)ROWS * BCDIM;     // 2*16*32*32
  float* dts = Sraw + (size_t)B_SZ * NCHUNK * CHUNK * CHUNK;  // 1024*24
  __bf16* bp = (__bf16*)(dts + (size_t)ROWS * NHEADS);
  __bf16* nxh = bp;  bp += (size_t)ROWS * DMODEL;
  __bf16* nxl = bp;  bp += (size_t)ROWS * DMODEL;
  __bf16* yh = bp;   bp += (size_t)ROWS * DINNER;
  __bf16* yl = bp;   bp += (size_t)ROWS * DINNER;
  __bf16* xh = bp;   bp += (size_t)ROWS * DMODEL;
  __bf16* xl = bp;   bp += (size_t)ROWS * DMODEL;
  __bf16* wih0 = bp; bp += (size_t)NPAD_IN * DMODEL;
  __bf16* wil0 = bp; bp += (size_t)NPAD_IN * DMODEL;
  __bf16* wih1 = bp; bp += (size_t)NPAD_IN * DMODEL;
  __bf16* wil1 = bp; bp += (size_t)NPAD_IN * DMODEL;
  __bf16* woh0 = bp; bp += (size_t)DMODEL * DINNER;
  __bf16* wol0 = bp; bp += (size_t)DMODEL * DINNER;
  __bf16* woh1 = bp; bp += (size_t)DMODEL * DINNER;
  __bf16* wol1 = bp; bp += (size_t)DMODEL * DINNER;
  __bf16* wch = bp;  bp += (size_t)NPAD_CLS * DMODEL;
  __bf16* wcl = bp;

  constexpr int TIN = (NPAD_IN / 32) * (DMODEL / 32);
  constexpr int TOUT = (DMODEL / 32) * (DINNER / 32);
  constexpr int TCLS = (NPAD_CLS / 32) * (DMODEL / 32);
  decomp_all_kernel<<<2 * TIN + 2 * TOUT + TCLS + ROWS, 256, 0, stream>>>(
      Win, Wout, Wcls, tokens, emb, ln_w, ln_b, x, nxh, nxl, wih0, wil0, wih1, wil1, woh0, wol0,
      woh1, wol1, wch, wcl);

  for (int blk = 0; blk < 2; ++blk) {
    const float* cw_b = conv_w + (size_t)blk * CONVDIM * 4;
    const float* cb_b = conv_b + (size_t)blk * CONVDIM;
    const float* dtb_b = dt_bias + (size_t)blk * NHEADS;
    const float* Alog_b = A_log + (size_t)blk * NHEADS;
    const float* Dp_b = Dp + (size_t)blk * NHEADS;
    const float* rmsw_b = rms_w + (size_t)blk * DINNER;
    __bf16* wih = blk ? wih1 : wih0;
    __bf16* wil = blk ? wil1 : wil0;
    __bf16* woh = blk ? woh1 : woh0;
    __bf16* wol = blk ? wol1 : wol0;

    if (blk == 1) {
      ln_kernel<<<ROWS, 256, 0, stream>>>(x, ln_w + (size_t)blk * DMODEL,
                                          ln_b + (size_t)blk * DMODEL, nxh, nxl);
    }

    mfma_gemm_kernel<2, 2, false><<<(NPAD_IN / 64) * (ROWS / 64), 256, 0, stream>>>(
        nxh, nxl, wih, wil, nullptr, nullptr, zx, DINPROJ, DMODEL, 0, NPAD_IN / 64, 0,
        (NPAD_IN / 64) * (ROWS / 64));

    convBC_kernel<<<ROWS, BCDIM, 0, stream>>>(zx, cw_b, cb_b, dtb_b, xBC, dts);

    sraw_kernel<<<dim3(NCHUNK, B_SZ), 256, 0, stream>>>(xBC, Sraw);

    chunk_local_kernel<<<dim3(NCHUNK, NHEADS, B_SZ), 256, 0, stream>>>(
        zx, xBC, Sraw, dts, cw_b, cb_b, Alog_b, Dp_b, y, Gt, et, elast);

    combine_kernel<<<dim3(8, B_SZ * NHEADS), 256, 0, stream>>>(Gt, elast);

    apply_inter_kernel<<<dim3(NCHUNK - 1, NHEADS, B_SZ), 256, 0, stream>>>(xBC, Gt, et, y);

    gate_rms_kernel<<<ROWS, 256, 0, stream>>>(y, zx, rmsw_b, yh, yl);

    mfma_gemm_kernel<2, 2, true><<<(DMODEL / 64) * (ROWS / 64) * 4, 256, 0, stream>>>(
        yh, yl, woh, wol, nullptr, nullptr, x, DMODEL, DINNER, DINNER / 4, DMODEL / 64,
        ROWS / 64, (DMODEL / 64) * (ROWS / 64) * 4);
  }

  act_decomp_kernel<<<ROWS, 256, 0, stream>>>(x, xh, xl);
  mfma_gemm_kernel<2, 2, false><<<(NPAD_CLS / 64) * (ROWS / 64), 256, 0, stream>>>(
      xh, xl, wch, wcl, nullptr, bcls, out, 1000, DMODEL, 0, NPAD_CLS / 64, 0,
      (NPAD_CLS / 64) * (ROWS / 64));
}

// Round 15
// 232.261 us; speedup vs baseline: 1.1172x; 1.0333x over previous
//
#include <hip/hip_runtime.h>
#include <hip/hip_bf16.h>
#include <math.h>

#define B_SZ 2
#define L_SEQ 512
#define DMODEL 768
#define DINNER 1536
#define DSTATE 128
#define HEADDIM 64
#define NHEADS 24
#define CONVDIM 1792
#define DINPROJ 3352
#define ROWS (B_SZ * L_SEQ)  // 1024

#define CHUNK 32
#define NCHUNK (L_SEQ / CHUNK)  // 16
#define BCDIM (2 * DSTATE)      // 256

#define NPAD_IN 3456   // 54 * 64
#define NPAD_CLS 1024  // 16 * 64

typedef __attribute__((ext_vector_type(8))) __bf16 bf16x8;
typedef __attribute__((ext_vector_type(4))) __bf16 bf16x4;
typedef __attribute__((ext_vector_type(4))) float f32x4;

typedef __attribute__((address_space(1))) const unsigned int as1_u32;
typedef __attribute__((address_space(3))) unsigned int as3_u32;

__device__ __forceinline__ void gload16(const void* g, void* s) {
  __builtin_amdgcn_global_load_lds((as1_u32*)(unsigned long)g, (as3_u32*)(unsigned long)s, 16, 0,
                                   0);
}

__device__ __forceinline__ float siluf(float x) { return x / (1.f + expf(-x)); }
__device__ __forceinline__ float softplusf(float x) {
  return x > 0.f ? x + log1pf(expf(-x)) : log1pf(expf(x));
}

__device__ __forceinline__ float block_reduce_sum(float v, float* sred) {
  int tid = threadIdx.x;
  for (int off = 32; off; off >>= 1) v += __shfl_down(v, off, 64);
  int wid = tid >> 6, lane = tid & 63;
  if (lane == 0) sred[wid] = v;
  __syncthreads();
  float total;
  if (tid == 0) {
    total = 0.f;
    int nw = blockDim.x >> 6;
    for (int i = 0; i < nw; ++i) total += sred[i];
    sred[0] = total;
  }
  __syncthreads();
  total = sred[0];
  __syncthreads();
  return total;
}

// ---------------- fused: embed gather + LN(blk0) + all 5 weight transpose/decompose ------------
__global__ __launch_bounds__(256) void decomp_all_kernel(
    const float* __restrict__ Win, const float* __restrict__ Wout,
    const float* __restrict__ Wcls, const int* __restrict__ tok, const float* __restrict__ emb,
    const float* __restrict__ lnw0, const float* __restrict__ lnb0, float* __restrict__ x,
    __bf16* __restrict__ nxh, __bf16* __restrict__ nxl, __bf16* __restrict__ wih0,
    __bf16* __restrict__ wil0, __bf16* __restrict__ wih1, __bf16* __restrict__ wil1,
    __bf16* __restrict__ woh0, __bf16* __restrict__ wol0, __bf16* __restrict__ woh1,
    __bf16* __restrict__ wol1, __bf16* __restrict__ wch, __bf16* __restrict__ wcl) {
  constexpr int TIN = (NPAD_IN / 32) * (DMODEL / 32);    // 2592
  constexpr int TOUT = (DMODEL / 32) * (DINNER / 32);    // 1152
  constexpr int TCLS = (NPAD_CLS / 32) * (DMODEL / 32);  // 768
  __shared__ float tile[32][33];
  int bid = blockIdx.x;
  int tid = threadIdx.x;

  if (bid >= 2 * TIN + 2 * TOUT + TCLS) {
    int row = bid - (2 * TIN + 2 * TOUT + TCLS);
    int t = tok[row];
    float v[3];
    float s = 0.f;
#pragma unroll
    for (int j = 0; j < 3; ++j) {
      v[j] = emb[(size_t)t * DMODEL + tid + j * 256];
      s += v[j];
      x[(size_t)row * DMODEL + tid + j * 256] = v[j];
    }
    float* sred = (float*)tile;
    float mean = block_reduce_sum(s, sred) * (1.f / DMODEL);
    float s2 = 0.f;
#pragma unroll
    for (int j = 0; j < 3; ++j) {
      float d = v[j] - mean;
      s2 += d * d;
    }
    float var = block_reduce_sum(s2, sred) * (1.f / DMODEL);
    float r = 1.f / sqrtf(var + 1e-5f);
#pragma unroll
    for (int j = 0; j < 3; ++j) {
      int d = tid + j * 256;
      float val = (v[j] - mean) * r * lnw0[d] + lnb0[d];
      __bf16 h = (__bf16)val;
      nxh[(size_t)row * DMODEL + d] = h;
      nxl[(size_t)row * DMODEL + d] = (__bf16)(val - (float)h);
    }
    return;
  }

  const float* W;
  __bf16 *Th, *Tl;
  int K, N, ntx, r;
  if (bid < TIN) {
    W = Win; Th = wih0; Tl = wil0; K = DMODEL; N = DINPROJ; ntx = NPAD_IN / 32; r = bid;
  } else if (bid < 2 * TIN) {
    W = Win + (size_t)DMODEL * DINPROJ; Th = wih1; Tl = wil1; K = DMODEL; N = DINPROJ;
    ntx = NPAD_IN / 32; r = bid - TIN;
  } else if (bid < 2 * TIN + TOUT) {
    W = Wout; Th = woh0; Tl = wol0; K = DINNER; N = DMODEL; ntx = DMODEL / 32; r = bid - 2 * TIN;
  } else if (bid < 2 * TIN + 2 * TOUT) {
    W = Wout + (size_t)DINNER * DMODEL; Th = woh1; Tl = wol1; K = DINNER; N = DMODEL;
    ntx = DMODEL / 32; r = bid - 2 * TIN - TOUT;
  } else {
    W = Wcls; Th = wch; Tl = wcl; K = DMODEL; N = 1000; ntx = NPAD_CLS / 32;
    r = bid - 2 * TIN - 2 * TOUT;
  }
  int bn = (r % ntx) * 32, bk = (r / ntx) * 32;

  int i = tid >> 3, j4 = (tid & 7) * 4;
  int kk = bk + i;
  int nn = bn + j4;
  float4 v;
  if (nn + 3 < N) {
    v = *(const float4*)(W + (size_t)kk * N + nn);
  } else {
    v.x = (nn + 0 < N) ? W[(size_t)kk * N + nn + 0] : 0.f;
    v.y = (nn + 1 < N) ? W[(size_t)kk * N + nn + 1] : 0.f;
    v.z = (nn + 2 < N) ? W[(size_t)kk * N + nn + 2] : 0.f;
    v.w = (nn + 3 < N) ? W[(size_t)kk * N + nn + 3] : 0.f;
  }
  tile[i][j4 + 0] = v.x;
  tile[i][j4 + 1] = v.y;
  tile[i][j4 + 2] = v.z;
  tile[i][j4 + 3] = v.w;
  __syncthreads();
  int n = bn + i;
  bf16x4 hv, lv;
#pragma unroll
  for (int q = 0; q < 4; ++q) {
    float f = tile[j4 + q][i];
    __bf16 h = (__bf16)f;
    hv[q] = h;
    lv[q] = (__bf16)(f - (float)h);
  }
  *(bf16x4*)(Th + (size_t)n * K + bk + j4) = hv;
  *(bf16x4*)(Tl + (size_t)n * K + bk + j4) = lv;
}

// ---------------- layernorm -> bf16 hi/lo ----------------
__global__ __launch_bounds__(256) void ln_kernel(const float* __restrict__ x,
                                                 const float* __restrict__ w,
                                                 const float* __restrict__ b,
                                                 __bf16* __restrict__ oh,
                                                 __bf16* __restrict__ ol) {
  __shared__ float sred[8];
  int row = blockIdx.x, tid = threadIdx.x;
  const float* xr = x + (size_t)row * DMODEL;
  float v[3];
  float s = 0.f;
#pragma unroll
  for (int j = 0; j < 3; ++j) {
    v[j] = xr[tid + j * 256];
    s += v[j];
  }
  float mean = block_reduce_sum(s, sred) * (1.f / DMODEL);
  float s2 = 0.f;
#pragma unroll
  for (int j = 0; j < 3; ++j) {
    float d = v[j] - mean;
    s2 += d * d;
  }
  float var = block_reduce_sum(s2, sred) * (1.f / DMODEL);
  float r = 1.f / sqrtf(var + 1e-5f);
#pragma unroll
  for (int j = 0; j < 3; ++j) {
    int d = tid + j * 256;
    float val = (v[j] - mean) * r * w[d] + b[d];
    __bf16 h = (__bf16)val;
    oh[(size_t)row * DMODEL + d] = h;
    ol[(size_t)row * DMODEL + d] = (__bf16)(val - (float)h);
  }
}

// ---------------- x -> bf16 hi/lo ----------------
__global__ __launch_bounds__(256) void act_decomp_kernel(const float* __restrict__ x,
                                                         __bf16* __restrict__ oh,
                                                         __bf16* __restrict__ ol) {
  int row = blockIdx.x, tid = threadIdx.x;
#pragma unroll
  for (int j = 0; j < 3; ++j) {
    int d = tid + j * 256;
    float v = x[(size_t)row * DMODEL + d];
    __bf16 h = (__bf16)v;
    oh[(size_t)row * DMODEL + d] = h;
    ol[(size_t)row * DMODEL + d] = (__bf16)(v - (float)h);
  }
}

// ---------------- bf16x3 MFMA GEMM, 2-phase double-buffered staging ----------------
template <int FM, int FN, bool ATOMIC>
__global__ __launch_bounds__(256) void mfma_gemm_kernel(
    const __bf16* __restrict__ Ahi, const __bf16* __restrict__ Alo,
    const __bf16* __restrict__ Bhi, const __bf16* __restrict__ Blo,
    const float* __restrict__ addsrc, const float* __restrict__ bias, float* __restrict__ C,
    int N, int K, int kslice, int nbx, int nby, int nwg) {
  constexpr int BM = FM * 32;
  constexpr int BN = FN * 32;
  constexpr int RGA = BM / 16;
  constexpr int RGB = BN / 16;
  constexpr int NITER = (2 * (RGA + RGB)) / 4;
  constexpr int ABYTES = BM * 64;
  constexpr int BBYTES = BN * 64;
  constexpr int BUFBYTES = 2 * ABYTES + 2 * BBYTES;
  __shared__ char lds[2 * BUFBYTES];

  int tid = threadIdx.x;
  int wave = tid >> 6, lane = tid & 63;
  int wm = wave >> 1, wn = wave & 1;
  int bx, by, kz;
  if (nbx > 0) {
    int orig = (blockIdx.x % 8) * (nwg / 8) + blockIdx.x / 8;
    bx = orig % nbx;
    int t = orig / nbx;
    if (nby > 0) {
      by = t % nby;
      kz = t / nby;
    } else {
      by = t;
      kz = 0;
    }
  } else {
    bx = blockIdx.x;
    by = blockIdx.y;
    kz = blockIdx.z;
  }
  int bm = by * BM;
  int bn = bx * BN;
  int kbeg = ATOMIC ? kz * kslice : 0;
  int kend = ATOMIC ? (kbeg + kslice) : K;
  int l2 = lane >> 2;
  int gch = (lane & 3) ^ ((lane >> 3) & 3);
  int lr = lane & 15, lg = lane >> 4;

  f32x4 acc[FM][FN] = {};

  auto stage = [&](char* buf, int k0) {
#pragma unroll
    for (int it = 0; it < NITER; ++it) {
      int rg = wave + it * 4;
      const __bf16* src;
      int row0, boff;
      if (rg < RGA) {
        src = Ahi;
        row0 = bm + rg * 16;
        boff = rg * 1024;
      } else if (rg < 2 * RGA) {
        src = Alo;
        row0 = bm + (rg - RGA) * 16;
        boff = ABYTES + (rg - RGA) * 1024;
      } else if (rg < 2 * RGA + RGB) {
        src = Bhi;
        row0 = bn + (rg - 2 * RGA) * 16;
        boff = 2 * ABYTES + (rg - 2 * RGA) * 1024;
      } else {
        src = Blo;
        row0 = bn + (rg - 2 * RGA - RGB) * 16;
        boff = 2 * ABYTES + BBYTES + (rg - 2 * RGA - RGB) * 1024;
      }
      gload16(src + (size_t)(row0 + l2) * K + k0 + gch * 8, buf + boff);
    }
  };

  stage(lds, kbeg);
  __syncthreads();

  char* curb = lds;
  char* nxtb = lds + BUFBYTES;
  for (int k0 = kbeg; k0 < kend; k0 += 32) {
    if (k0 + 32 < kend) stage(nxtb, k0 + 32);

    bf16x8 ahi[FM], alo[FM], bhi[FN], blo[FN];
#pragma unroll
    for (int m = 0; m < FM; ++m) {
      int r = wm * FM * 16 + m * 16 + lr;
      int off = r * 64 + ((lg ^ ((r >> 1) & 3)) * 16);
      ahi[m] = *(const bf16x8*)(curb + off);
      alo[m] = *(const bf16x8*)(curb + ABYTES + off);
    }
#pragma unroll
    for (int n = 0; n < FN; ++n) {
      int r = wn * FN * 16 + n * 16 + lr;
      int off = r * 64 + ((lg ^ ((r >> 1) & 3)) * 16);
      bhi[n] = *(const bf16x8*)(curb + 2 * ABYTES + off);
      blo[n] = *(const bf16x8*)(curb + 2 * ABYTES + BBYTES + off);
    }
#pragma unroll
    for (int m = 0; m < FM; ++m)
#pragma unroll
      for (int n = 0; n < FN; ++n) {
        acc[m][n] = __builtin_amdgcn_mfma_f32_16x16x32_bf16(ahi[m], bhi[n], acc[m][n], 0, 0, 0);
        acc[m][n] = __builtin_amdgcn_mfma_f32_16x16x32_bf16(ahi[m], blo[n], acc[m][n], 0, 0, 0);
        acc[m][n] = __builtin_amdgcn_mfma_f32_16x16x32_bf16(alo[m], bhi[n], acc[m][n], 0, 0, 0);
      }
    __syncthreads();
    char* t = curb;
    curb = nxtb;
    nxtb = t;
  }

#pragma unroll
  for (int m = 0; m < FM; ++m) {
#pragma unroll
    for (int n = 0; n < FN; ++n) {
      int gcol = bn + wn * FN * 16 + n * 16 + lr;
      if (gcol < N) {
#pragma unroll
        for (int r = 0; r < 4; ++r) {
          int grow = bm + wm * FM * 16 + m * 16 + lg * 4 + r;
          if (ATOMIC) {
            unsafeAtomicAdd(&C[(size_t)grow * N + gcol], acc[m][n][r]);
          } else {
            float v = acc[m][n][r];
            if (addsrc) v += addsrc[(size_t)grow * N + gcol];
            if (bias) v += bias[gcol];
            C[(size_t)grow * N + gcol] = v;
          }
        }
      }
    }
  }
}

// ---------------- conv+silu for shared B/C channels + dt softplus -> xBC, dts ----------------
__global__ __launch_bounds__(256) void convBC_kernel(const float* __restrict__ zx,
                                                     const float* __restrict__ cw,
                                                     const float* __restrict__ cb,
                                                     const float* __restrict__ dtb,
                                                     float* __restrict__ xBC,
                                                     float* __restrict__ dts) {
  int row = blockIdx.x;
  int c = threadIdx.x;  // 0..255
  int ch = DINNER + c;  // conv-channel index (B/C section)
  int l = row & (L_SEQ - 1);
  float acc = cb[ch];
#pragma unroll
  for (int k = 0; k < 4; ++k) {
    int ls = l - 3 + k;
    if (ls >= 0)
      acc = fmaf(cw[ch * 4 + k], zx[(size_t)(row - 3 + k) * DINPROJ + DINNER + ch], acc);
  }
  xBC[(size_t)row * BCDIM + c] = siluf(acc);
  if (c < NHEADS) {
    float raw = zx[(size_t)row * DINPROJ + DINNER + CONVDIM + c] + dtb[c];
    dts[(size_t)row * NHEADS + c] = softplusf(raw);
  }
}

// ---------------- Sraw = C . B^T per (batch, chunk) — head-independent, hoisted ----------------
__global__ __launch_bounds__(256) void sraw_kernel(const float* __restrict__ xBC,
                                                   float* __restrict__ Sraw) {
  __shared__ float Bs[CHUNK][132];
  __shared__ float Cs[CHUNK][132];
  int ci = blockIdx.x, b = blockIdx.y;
  int tid = threadIdx.x;
  int row0 = b * L_SEQ + ci * CHUNK;
#pragma unroll
  for (int i = 0; i < 4; ++i) {
    int vi = tid + i * 256;
    int t = vi >> 5;
    int n4 = (vi & 31) * 4;
    const float* r = xBC + (size_t)(row0 + t) * BCDIM;
    *(float4*)&Bs[t][n4] = *(const float4*)(r + n4);
    *(float4*)&Cs[t][n4] = *(const float4*)(r + DSTATE + n4);
  }
  __syncthreads();
  int t0 = (tid >> 4) * 2;
  int s0 = (tid & 15) * 2;
  float sacc[2][2] = {};
#pragma unroll
  for (int n = 0; n < DSTATE; n += 4) {
    float cr[2][4], br[2][4];
#pragma unroll
    for (int i = 0; i < 2; ++i) *(float4*)&cr[i][0] = *(const float4*)&Cs[t0 + i][n];
#pragma unroll
    for (int j = 0; j < 2; ++j) *(float4*)&br[j][0] = *(const float4*)&Bs[s0 + j][n];
#pragma unroll
    for (int i = 0; i < 2; ++i)
#pragma unroll
      for (int j = 0; j < 2; ++j)
#pragma unroll
        for (int k = 0; k < 4; ++k) sacc[i][j] = fmaf(cr[i][k], br[j][k], sacc[i][j]);
  }
  float* Sp = Sraw + ((size_t)(b * NCHUNK + ci) * CHUNK) * CHUNK;
#pragma unroll
  for (int i = 0; i < 2; ++i)
#pragma unroll
    for (int j = 0; j < 2; ++j) Sp[(t0 + i) * CHUNK + s0 + j] = sacc[i][j];
}

// ---------------- chunked SSD: X-conv + intra-chunk (VALU) + chunk state (MFMA) ----------
// Gt layout: [bh][ci][p][cs*8..], cs = (n/8) ^ (p&7)  (transposed + chunk-swizzled)
__global__ __launch_bounds__(256) void chunk_local_kernel(
    const float* __restrict__ zx, const float* __restrict__ xBC, const float* __restrict__ Sraw,
    const float* __restrict__ dts, const float* __restrict__ cw, const float* __restrict__ cb,
    const float* __restrict__ Alog, const float* __restrict__ Dp, float* __restrict__ y,
    __bf16* __restrict__ Gt, float* __restrict__ et, float* __restrict__ elast) {
  __shared__ __bf16 Bt[DSTATE][40];   // B^T [n][s] bf16
  __shared__ float Xs[CHUNK][68];     // X [s][p] fp32
  __shared__ __bf16 Xt[HEADDIM][40];  // (sW*X)^T [p][s] bf16
  __shared__ float Ss[CHUNK][36];
  __shared__ __bf16 Gl[HEADDIM][136];  // G staging [p][n]
  __shared__ float sP[CHUNK], sW[CHUNK], sDt[CHUNK];

  int ci = blockIdx.x, h = blockIdx.y, b = blockIdx.z;
  int bh = b * NHEADS + h;
  int tid = threadIdx.x;
  int wave = tid >> 6, lane = tid & 63;
  int row0 = b * L_SEQ + ci * CHUNK;

  // stage B^T bf16 from xBC (coalesced float4 reads, scalar transposed LDS writes)
#pragma unroll
  for (int i = 0; i < 4; ++i) {
    int vi = tid + i * 256;  // 1024
    int s = vi >> 5;
    int n4 = (vi & 31) * 4;
    float4 v = *(const float4*)(xBC + (size_t)(row0 + s) * BCDIM + n4);
    Bt[n4 + 0][s] = (__bf16)v.x;
    Bt[n4 + 1][s] = (__bf16)v.y;
    Bt[n4 + 2][s] = (__bf16)v.z;
    Bt[n4 + 3][s] = (__bf16)v.w;
  }
  // fused conv+silu for X (this head's 64 channels)
#pragma unroll
  for (int i = 0; i < 2; ++i) {
    int vi = tid + i * 256;
    int t = vi >> 4;
    int p4 = (vi & 15) * 4;
    int cX = h * HEADDIM + p4;
    float oX[4];
#pragma unroll
    for (int q = 0; q < 4; ++q) oX[q] = cb[cX + q];
#pragma unroll
    for (int k = 0; k < 4; ++k) {
      if (ci > 0 || t + k >= 3) {
        float4 v = *(const float4*)(zx + (size_t)(row0 + t - 3 + k) * DINPROJ + DINNER + cX);
#pragma unroll
        for (int q = 0; q < 4; ++q) oX[q] = fmaf(cw[(cX + q) * 4 + k], ((const float*)&v)[q], oX[q]);
      }
    }
#pragma unroll
    for (int q = 0; q < 4; ++q) Xs[t][p4 + q] = siluf(oX[q]);
  }
  // decay prefix (first 32 lanes; dt precomputed)
  if (tid < 32) {
    int t = tid;
    float Ah = -expf(Alog[h]);
    float dtv = dts[(size_t)(row0 + t) * NHEADS + h];
    float P = dtv * Ah;
#pragma unroll
    for (int off = 1; off < 32; off <<= 1) {
      float u = __shfl_up(P, off, 32);
      if (t >= off) P += u;
    }
    float Plast = __shfl(P, 31, 32);
    float e = expf(P);
    sP[t] = P;
    sDt[t] = dtv;
    sW[t] = expf(Plast - P) * dtv;
    et[(size_t)(bh * NCHUNK + ci) * CHUNK + t] = e;
    if (t == 31) elast[bh * NCHUNK + ci] = e;
  }
  __syncthreads();

  int t0 = (tid >> 4) * 2;
  int s0 = (tid & 15) * 2;
  {
    const float* Sp = Sraw + ((size_t)(b * NCHUNK + ci) * CHUNK) * CHUNK;
#pragma unroll
    for (int i = 0; i < 2; ++i)
#pragma unroll
      for (int j = 0; j < 2; ++j) {
        int t = t0 + i, s = s0 + j;
        float sr = Sp[t * CHUNK + s];
        Ss[t][s] = (t >= s) ? sr * expf(sP[t] - sP[s]) * sDt[s] : 0.f;
      }
  }
  // Xt[p][s] = bf16(sW[s] * X[s][p])
#pragma unroll
  for (int i = 0; i < 8; ++i) {
    int vi = tid + i * 256;  // 2048
    int p = vi >> 5;
    int s = vi & 31;
    Xt[p][s] = (__bf16)(sW[s] * Xs[s][p]);
  }
  __syncthreads();

  // y_intra (fp32 VALU, unchanged)
  {
    int p0 = (tid & 15) * 4;
    float acc[2][4] = {};
#pragma unroll
    for (int s = 0; s < CHUNK; s += 4) {
      float sr[2][4], xr[4][4];
#pragma unroll
      for (int i = 0; i < 2; ++i) *(float4*)&sr[i][0] = *(const float4*)&Ss[t0 + i][s];
#pragma unroll
      for (int u = 0; u < 4; ++u) *(float4*)&xr[u][0] = *(const float4*)&Xs[s + u][p0];
#pragma unroll
      for (int i = 0; i < 2; ++i)
#pragma unroll
        for (int j = 0; j < 4; ++j)
#pragma unroll
          for (int u = 0; u < 4; ++u) acc[i][j] = fmaf(sr[i][u], xr[u][j], acc[i][j]);
    }
    float Dh = Dp[h];
#pragma unroll
    for (int i = 0; i < 2; ++i) {
      int row = row0 + t0 + i;
      float4 o;
      o.x = acc[i][0] + Dh * Xs[t0 + i][p0 + 0];
      o.y = acc[i][1] + Dh * Xs[t0 + i][p0 + 1];
      o.z = acc[i][2] + Dh * Xs[t0 + i][p0 + 2];
      o.w = acc[i][3] + Dh * Xs[t0 + i][p0 + 3];
      *(float4*)(y + (size_t)row * DINNER + h * HEADDIM + p0) = o;
    }
  }

  // chunk-state via MFMA: D[n][p] = sum_s Bt[n][s] * Xt[p][s]
  {
    int lr = lane & 15, lg = lane >> 4;
    f32x4 gacc[2][4] = {};
#pragma unroll
    for (int nt = 0; nt < 2; ++nt) {
      bf16x8 af = *(const bf16x8*)&Bt[(wave * 2 + nt) * 16 + lr][lg * 8];
#pragma unroll
      for (int pt = 0; pt < 4; ++pt) {
        bf16x8 bfr = *(const bf16x8*)&Xt[pt * 16 + lr][lg * 8];
        gacc[nt][pt] = __builtin_amdgcn_mfma_f32_16x16x32_bf16(af, bfr, gacc[nt][pt], 0, 0, 0);
      }
    }
#pragma unroll
    for (int nt = 0; nt < 2; ++nt)
#pragma unroll
      for (int pt = 0; pt < 4; ++pt) {
        int p = pt * 16 + lr;
        int n0 = (wave * 2 + nt) * 16 + lg * 4;
        bf16x4 o;
#pragma unroll
        for (int r = 0; r < 4; ++r) o[r] = (__bf16)gacc[nt][pt][r];
        *(bf16x4*)&Gl[p][n0] = o;
      }
  }
  __syncthreads();
  // coalesced swizzled store Gl -> Gt
  {
    __bf16* Gp = Gt + ((size_t)bh * NCHUNK + ci) * (DSTATE * HEADDIM);
#pragma unroll
    for (int i = 0; i < 4; ++i) {
      int vi = tid + i * 256;  // 1024
      int p = vi >> 4;
      int c = vi & 15;
      bf16x8 v = *(const bf16x8*)&Gl[p][c * 8];
      int cs = c ^ (p & 7);
      *(bf16x8*)(Gp + (size_t)p * DSTATE + cs * 8) = v;
    }
  }
}

// ---------------- combine chunk states (bf16 storage; elementwise, layout-agnostic) -----------
__global__ __launch_bounds__(256) void combine_kernel(__bf16* __restrict__ G,
                                                      const float* __restrict__ elast) {
  int part = blockIdx.x;
  int bh = blockIdx.y;
  int gi = part * 256 + threadIdx.x;
  __bf16* base = G + (size_t)bh * NCHUNK * (DSTATE * HEADDIM);
  const float* el = elast + bh * NCHUNK;
  float h0 = 0.f, h1 = 0.f, h2 = 0.f, h3 = 0.f;
#pragma unroll
  for (int c = 0; c < NCHUNK - 1; ++c) {
    bf16x4 g = *(bf16x4*)(base + (size_t)c * (DSTATE * HEADDIM) + gi * 4);
    float e = el[c];
    h0 = fmaf(e, h0, (float)g[0]);
    h1 = fmaf(e, h1, (float)g[1]);
    h2 = fmaf(e, h2, (float)g[2]);
    h3 = fmaf(e, h3, (float)g[3]);
    bf16x4 o;
    o[0] = (__bf16)h0;
    o[1] = (__bf16)h1;
    o[2] = (__bf16)h2;
    o[3] = (__bf16)h3;
    *(bf16x4*)(base + (size_t)c * (DSTATE * HEADDIM) + gi * 4) = o;
  }
}

// ---------------- inter-chunk contribution: MFMA bf16 (C 32x128 @ Ht^T 128x64) ---------------
__global__ __launch_bounds__(256) void apply_inter_kernel(const float* __restrict__ xBC,
                                                          const __bf16* __restrict__ Gt,
                                                          const float* __restrict__ et,
                                                          float* __restrict__ y) {
  __shared__ __bf16 CsB[CHUNK * DSTATE];   // [t][128] bf16, chunk-swizzled
  __shared__ __bf16 HsB[HEADDIM * DSTATE]; // [p][128] bf16, pre-swizzled global -> linear stage
  __shared__ float sE[CHUNK];
  int ci = blockIdx.x + 1;
  int h = blockIdx.y, b = blockIdx.z;
  int bh = b * NHEADS + h;
  int tid = threadIdx.x;
  int wave = tid >> 6, lane = tid & 63;
  int row0 = b * L_SEQ + ci * CHUNK;

  const __bf16* Hsrc = Gt + ((size_t)bh * NCHUNK + (ci - 1)) * (DSTATE * HEADDIM);
#pragma unroll
  for (int r = 0; r < 4; ++r) {
    gload16(Hsrc + (size_t)r * 2048 + wave * 512 + lane * 8,
            (char*)HsB + r * 4096 + wave * 1024);
  }
#pragma unroll
  for (int i = 0; i < 2; ++i) {
    int vi = tid + i * 256;
    int t = vi >> 4;
    int c = vi & 15;
    const float* src = xBC + (size_t)(row0 + t) * BCDIM + DSTATE + c * 8;
    float4 v0 = *(const float4*)src;
    float4 v1 = *(const float4*)(src + 4);
    bf16x8 o;
    o[0] = (__bf16)v0.x; o[1] = (__bf16)v0.y; o[2] = (__bf16)v0.z; o[3] = (__bf16)v0.w;
    o[4] = (__bf16)v1.x; o[5] = (__bf16)v1.y; o[6] = (__bf16)v1.z; o[7] = (__bf16)v1.w;
    int cs = c ^ (t & 7);
    *(bf16x8*)&CsB[t * DSTATE + cs * 8] = o;
  }
  if (tid < CHUNK) sE[tid] = et[(size_t)(bh * NCHUNK + ci) * CHUNK + tid];
  __syncthreads();

  int lr = lane & 15, lg = lane >> 4;
  int wm = wave >> 1;
  int wnb = (wave & 1) * 2;
  f32x4 acc[2] = {};
#pragma unroll
  for (int ks = 0; ks < 4; ++ks) {
    int ar = wm * 16 + lr;
    bf16x8 af = *(const bf16x8*)&CsB[ar * DSTATE + (((ks * 4 + lg) ^ (ar & 7)) * 8)];
#pragma unroll
    for (int nn = 0; nn < 2; ++nn) {
      int br = (wnb + nn) * 16 + lr;
      bf16x8 bfr = *(const bf16x8*)&HsB[br * DSTATE + (((ks * 4 + lg) ^ (br & 7)) * 8)];
      acc[nn] = __builtin_amdgcn_mfma_f32_16x16x32_bf16(af, bfr, acc[nn], 0, 0, 0);
    }
  }
#pragma unroll
  for (int nn = 0; nn < 2; ++nn) {
    int p = (wnb + nn) * 16 + lr;
#pragma unroll
    for (int r = 0; r < 4; ++r) {
      int t = wm * 16 + lg * 4 + r;
      float e = sE[t];
      float* yp = &y[(size_t)(row0 + t) * DINNER + h * HEADDIM + p];
      *yp = fmaf(e, acc[nn][r], *yp);
    }
  }
}

// ---------------- gate (silu(z)) + RMS norm -> bf16 hi/lo ----------------
__global__ __launch_bounds__(256) void gate_rms_kernel(const float* __restrict__ y,
                                                       const float* __restrict__ zx,
                                                       const float* __restrict__ rmsw,
                                                       __bf16* __restrict__ oh,
                                                       __bf16* __restrict__ ol) {
  __shared__ float sred[8];
  int row = blockIdx.x, tid = threadIdx.x;
  const float* z = zx + (size_t)row * DINPROJ;
  const float* yr = y + (size_t)row * DINNER;
  float v[6];
  float ss = 0.f;
#pragma unroll
  for (int j = 0; j < 6; ++j) {
    int d = tid + j * 256;
    float val = yr[d] * siluf(z[d]);
    v[j] = val;
    ss += val * val;
  }
  float total = block_reduce_sum(ss, sred);
  float r = 1.f / sqrtf(total * (1.f / DINNER) + 1e-5f);
#pragma unroll
  for (int j = 0; j < 6; ++j) {
    int d = tid + j * 256;
    float val = v[j] * r * rmsw[d];
    __bf16 h = (__bf16)val;
    oh[(size_t)row * DINNER + d] = h;
    ol[(size_t)row * DINNER + d] = (__bf16)(val - (float)h);
  }
}

extern "C" void kernel_launch(void* const* d_in, const int* in_sizes, int n_in,
                              void* d_out, int out_size, void* d_ws, size_t ws_size,
                              hipStream_t stream) {
  const int* tokens = (const int*)d_in[0];
  const float* emb = (const float*)d_in[1];
  const float* ln_w = (const float*)d_in[2];
  const float* ln_b = (const float*)d_in[3];
  const float* Win = (const float*)d_in[4];
  const float* conv_w = (const float*)d_in[5];
  const float* conv_b = (const float*)d_in[6];
  const float* dt_bias = (const float*)d_in[7];
  const float* A_log = (const float*)d_in[8];
  const float* Dp = (const float*)d_in[9];
  const float* rms_w = (const float*)d_in[10];
  const float* Wout = (const float*)d_in[11];
  const float* Wcls = (const float*)d_in[12];
  const float* bcls = (const float*)d_in[13];
  float* out = (float*)d_out;

  float* ws = (float*)d_ws;
  float* x = ws;                                // 1024*768
  float* zx = x + (size_t)ROWS * DMODEL;        // 1024*3352
  float* y = zx + (size_t)ROWS * DINPROJ;       // 1024*1536
  __bf16* Gt = (__bf16*)(y + (size_t)ROWS * DINNER);  // transposed+swizzled bf16
  float* et = (float*)(Gt + (size_t)B_SZ * NHEADS * NCHUNK * DSTATE * HEADDIM);
  float* elast = et + (size_t)B_SZ * NHEADS * NCHUNK * CHUNK;
  float* xBC = elast + B_SZ * NHEADS * NCHUNK;  // 1024*256
  float* Sraw = xBC + (size_t)ROWS * BCDIM;     // 2*16*32*32
  float* dts = Sraw + (size_t)B_SZ * NCHUNK * CHUNK * CHUNK;  // 1024*24
  __bf16* bp = (__bf16*)(dts + (size_t)ROWS * NHEADS);
  __bf16* nxh = bp;  bp += (size_t)ROWS * DMODEL;
  __bf16* nxl = bp;  bp += (size_t)ROWS * DMODEL;
  __bf16* yh = bp;   bp += (size_t)ROWS * DINNER;
  __bf16* yl = bp;   bp += (size_t)ROWS * DINNER;
  __bf16* xh = bp;   bp += (size_t)ROWS * DMODEL;
  __bf16* xl = bp;   bp += (size_t)ROWS * DMODEL;
  __bf16* wih0 = bp; bp += (size_t)NPAD_IN * DMODEL;
  __bf16* wil0 = bp; bp += (size_t)NPAD_IN * DMODEL;
  __bf16* wih1 = bp; bp += (size_t)NPAD_IN * DMODEL;
  __bf16* wil1 = bp; bp += (size_t)NPAD_IN * DMODEL;
  __bf16* woh0 = bp; bp += (size_t)DMODEL * DINNER;
  __bf16* wol0 = bp; bp += (size_t)DMODEL * DINNER;
  __bf16* woh1 = bp; bp += (size_t)DMODEL * DINNER;
  __bf16* wol1 = bp; bp += (size_t)DMODEL * DINNER;
  __bf16* wch = bp;  bp += (size_t)NPAD_CLS * DMODEL;
  __bf16* wcl = bp;

  constexpr int TIN = (NPAD_IN / 32) * (DMODEL / 32);
  constexpr int TOUT = (DMODEL / 32) * (DINNER / 32);
  constexpr int TCLS = (NPAD_CLS / 32) * (DMODEL / 32);
  decomp_all_kernel<<<2 * TIN + 2 * TOUT + TCLS + ROWS, 256, 0, stream>>>(
      Win, Wout, Wcls, tokens, emb, ln_w, ln_b, x, nxh, nxl, wih0, wil0, wih1, wil1, woh0, wol0,
      woh1, wol1, wch, wcl);

  for (int blk = 0; blk < 2; ++blk) {
    const float* cw_b = conv_w + (size_t)blk * CONVDIM * 4;
    const float* cb_b = conv_b + (size_t)blk * CONVDIM;
    const float* dtb_b = dt_bias + (size_t)blk * NHEADS;
    const float* Alog_b = A_log + (size_t)blk * NHEADS;
    const float* Dp_b = Dp + (size_t)blk * NHEADS;
    const float* rmsw_b = rms_w + (size_t)blk * DINNER;
    __bf16* wih = blk ? wih1 : wih0;
    __bf16* wil = blk ? wil1 : wil0;
    __bf16* woh = blk ? woh1 : woh0;
    __bf16* wol = blk ? wol1 : wol0;

    if (blk == 1) {
      ln_kernel<<<ROWS, 256, 0, stream>>>(x, ln_w + (size_t)blk * DMODEL,
                                          ln_b + (size_t)blk * DMODEL, nxh, nxl);
    }

    mfma_gemm_kernel<2, 2, false><<<(NPAD_IN / 64) * (ROWS / 64), 256, 0, stream>>>(
        nxh, nxl, wih, wil, nullptr, nullptr, zx, DINPROJ, DMODEL, 0, NPAD_IN / 64, 0,
        (NPAD_IN / 64) * (ROWS / 64));

    convBC_kernel<<<ROWS, BCDIM, 0, stream>>>(zx, cw_b, cb_b, dtb_b, xBC, dts);

    sraw_kernel<<<dim3(NCHUNK, B_SZ), 256, 0, stream>>>(xBC, Sraw);

    chunk_local_kernel<<<dim3(NCHUNK, NHEADS, B_SZ), 256, 0, stream>>>(
        zx, xBC, Sraw, dts, cw_b, cb_b, Alog_b, Dp_b, y, Gt, et, elast);

    combine_kernel<<<dim3(8, B_SZ * NHEADS), 256, 0, stream>>>(Gt, elast);

    apply_inter_kernel<<<dim3(NCHUNK - 1, NHEADS, B_SZ), 256, 0, stream>>>(xBC, Gt, et, y);

    gate_rms_kernel<<<ROWS, 256, 0, stream>>>(y, zx, rmsw_b, yh, yl);

    mfma_gemm_kernel<2, 2, true><<<(DMODEL / 64) * (ROWS / 64) * 4, 256, 0, stream>>>(
        yh, yl, woh, wol, nullptr, nullptr, x, DMODEL, DINNER, DINNER / 4, DMODEL / 64,
        ROWS / 64, (DMODEL / 64) * (ROWS / 64) * 4);
  }

  act_decomp_kernel<<<ROWS, 256, 0, stream>>>(x, xh, xl);
  mfma_gemm_kernel<2, 2, false><<<(NPAD_CLS / 64) * (ROWS / 64), 256, 0, stream>>>(
      xh, xl, wch, wcl, nullptr, bcls, out, 1000, DMODEL, 0, NPAD_CLS / 64, 0,
      (NPAD_CLS / 64) * (ROWS / 64));
}

// Round 16
// 220.380 us; speedup vs baseline: 1.1775x; 1.0539x over previous
//
#include <hip/hip_runtime.h>
#include <hip/hip_bf16.h>
#include <math.h>

#define B_SZ 2
#define L_SEQ 512
#define DMODEL 768
#define DINNER 1536
#define DSTATE 128
#define HEADDIM 64
#define NHEADS 24
#define CONVDIM 1792
#define DINPROJ 3352
#define ROWS (B_SZ * L_SEQ)  // 1024

#define CHUNK 32
#define NCHUNK (L_SEQ / CHUNK)  // 16
#define BCDIM (2 * DSTATE)      // 256

#define NPAD_IN 3456   // 54 * 64
#define NPAD_CLS 1024  // 16 * 64

typedef __attribute__((ext_vector_type(8))) __bf16 bf16x8;
typedef __attribute__((ext_vector_type(4))) __bf16 bf16x4;
typedef __attribute__((ext_vector_type(4))) float f32x4;

typedef __attribute__((address_space(1))) const unsigned int as1_u32;
typedef __attribute__((address_space(3))) unsigned int as3_u32;

__device__ __forceinline__ void gload16(const void* g, void* s) {
  __builtin_amdgcn_global_load_lds((as1_u32*)(unsigned long)g, (as3_u32*)(unsigned long)s, 16, 0,
                                   0);
}

__device__ __forceinline__ float siluf(float x) { return x / (1.f + expf(-x)); }
__device__ __forceinline__ float softplusf(float x) {
  return x > 0.f ? x + log1pf(expf(-x)) : log1pf(expf(x));
}

__device__ __forceinline__ float block_reduce_sum(float v, float* sred) {
  int tid = threadIdx.x;
  for (int off = 32; off; off >>= 1) v += __shfl_down(v, off, 64);
  int wid = tid >> 6, lane = tid & 63;
  if (lane == 0) sred[wid] = v;
  __syncthreads();
  float total;
  if (tid == 0) {
    total = 0.f;
    int nw = blockDim.x >> 6;
    for (int i = 0; i < nw; ++i) total += sred[i];
    sred[0] = total;
  }
  __syncthreads();
  total = sred[0];
  __syncthreads();
  return total;
}

// ---------------- fused: embed gather + LN(blk0) + all 5 weight transpose/decompose ------------
__global__ __launch_bounds__(256) void decomp_all_kernel(
    const float* __restrict__ Win, const float* __restrict__ Wout,
    const float* __restrict__ Wcls, const int* __restrict__ tok, const float* __restrict__ emb,
    const float* __restrict__ lnw0, const float* __restrict__ lnb0, float* __restrict__ x,
    __bf16* __restrict__ nxh, __bf16* __restrict__ nxl, __bf16* __restrict__ wih0,
    __bf16* __restrict__ wil0, __bf16* __restrict__ wih1, __bf16* __restrict__ wil1,
    __bf16* __restrict__ woh0, __bf16* __restrict__ wol0, __bf16* __restrict__ woh1,
    __bf16* __restrict__ wol1, __bf16* __restrict__ wch, __bf16* __restrict__ wcl) {
  constexpr int TIN = (NPAD_IN / 32) * (DMODEL / 32);    // 2592
  constexpr int TOUT = (DMODEL / 32) * (DINNER / 32);    // 1152
  constexpr int TCLS = (NPAD_CLS / 32) * (DMODEL / 32);  // 768
  __shared__ float tile[32][33];
  int bid = blockIdx.x;
  int tid = threadIdx.x;

  if (bid >= 2 * TIN + 2 * TOUT + TCLS) {
    int row = bid - (2 * TIN + 2 * TOUT + TCLS);
    int t = tok[row];
    float v[3];
    float s = 0.f;
#pragma unroll
    for (int j = 0; j < 3; ++j) {
      v[j] = emb[(size_t)t * DMODEL + tid + j * 256];
      s += v[j];
      x[(size_t)row * DMODEL + tid + j * 256] = v[j];
    }
    float* sred = (float*)tile;
    float mean = block_reduce_sum(s, sred) * (1.f / DMODEL);
    float s2 = 0.f;
#pragma unroll
    for (int j = 0; j < 3; ++j) {
      float d = v[j] - mean;
      s2 += d * d;
    }
    float var = block_reduce_sum(s2, sred) * (1.f / DMODEL);
    float r = 1.f / sqrtf(var + 1e-5f);
#pragma unroll
    for (int j = 0; j < 3; ++j) {
      int d = tid + j * 256;
      float val = (v[j] - mean) * r * lnw0[d] + lnb0[d];
      __bf16 h = (__bf16)val;
      nxh[(size_t)row * DMODEL + d] = h;
      nxl[(size_t)row * DMODEL + d] = (__bf16)(val - (float)h);
    }
    return;
  }

  const float* W;
  __bf16 *Th, *Tl;
  int K, N, ntx, r;
  if (bid < TIN) {
    W = Win; Th = wih0; Tl = wil0; K = DMODEL; N = DINPROJ; ntx = NPAD_IN / 32; r = bid;
  } else if (bid < 2 * TIN) {
    W = Win + (size_t)DMODEL * DINPROJ; Th = wih1; Tl = wil1; K = DMODEL; N = DINPROJ;
    ntx = NPAD_IN / 32; r = bid - TIN;
  } else if (bid < 2 * TIN + TOUT) {
    W = Wout; Th = woh0; Tl = wol0; K = DINNER; N = DMODEL; ntx = DMODEL / 32; r = bid - 2 * TIN;
  } else if (bid < 2 * TIN + 2 * TOUT) {
    W = Wout + (size_t)DINNER * DMODEL; Th = woh1; Tl = wol1; K = DINNER; N = DMODEL;
    ntx = DMODEL / 32; r = bid - 2 * TIN - TOUT;
  } else {
    W = Wcls; Th = wch; Tl = wcl; K = DMODEL; N = 1000; ntx = NPAD_CLS / 32;
    r = bid - 2 * TIN - 2 * TOUT;
  }
  int bn = (r % ntx) * 32, bk = (r / ntx) * 32;

  int i = tid >> 3, j4 = (tid & 7) * 4;
  int kk = bk + i;
  int nn = bn + j4;
  float4 v;
  if (nn + 3 < N) {
    v = *(const float4*)(W + (size_t)kk * N + nn);
  } else {
    v.x = (nn + 0 < N) ? W[(size_t)kk * N + nn + 0] : 0.f;
    v.y = (nn + 1 < N) ? W[(size_t)kk * N + nn + 1] : 0.f;
    v.z = (nn + 2 < N) ? W[(size_t)kk * N + nn + 2] : 0.f;
    v.w = (nn + 3 < N) ? W[(size_t)kk * N + nn + 3] : 0.f;
  }
  tile[i][j4 + 0] = v.x;
  tile[i][j4 + 1] = v.y;
  tile[i][j4 + 2] = v.z;
  tile[i][j4 + 3] = v.w;
  __syncthreads();
  int n = bn + i;
  bf16x4 hv, lv;
#pragma unroll
  for (int q = 0; q < 4; ++q) {
    float f = tile[j4 + q][i];
    __bf16 h = (__bf16)f;
    hv[q] = h;
    lv[q] = (__bf16)(f - (float)h);
  }
  *(bf16x4*)(Th + (size_t)n * K + bk + j4) = hv;
  *(bf16x4*)(Tl + (size_t)n * K + bk + j4) = lv;
}

// ---------------- layernorm -> bf16 hi/lo ----------------
__global__ __launch_bounds__(256) void ln_kernel(const float* __restrict__ x,
                                                 const float* __restrict__ w,
                                                 const float* __restrict__ b,
                                                 __bf16* __restrict__ oh,
                                                 __bf16* __restrict__ ol) {
  __shared__ float sred[8];
  int row = blockIdx.x, tid = threadIdx.x;
  const float* xr = x + (size_t)row * DMODEL;
  float v[3];
  float s = 0.f;
#pragma unroll
  for (int j = 0; j < 3; ++j) {
    v[j] = xr[tid + j * 256];
    s += v[j];
  }
  float mean = block_reduce_sum(s, sred) * (1.f / DMODEL);
  float s2 = 0.f;
#pragma unroll
  for (int j = 0; j < 3; ++j) {
    float d = v[j] - mean;
    s2 += d * d;
  }
  float var = block_reduce_sum(s2, sred) * (1.f / DMODEL);
  float r = 1.f / sqrtf(var + 1e-5f);
#pragma unroll
  for (int j = 0; j < 3; ++j) {
    int d = tid + j * 256;
    float val = (v[j] - mean) * r * w[d] + b[d];
    __bf16 h = (__bf16)val;
    oh[(size_t)row * DMODEL + d] = h;
    ol[(size_t)row * DMODEL + d] = (__bf16)(val - (float)h);
  }
}

// ---------------- x -> bf16 hi/lo ----------------
__global__ __launch_bounds__(256) void act_decomp_kernel(const float* __restrict__ x,
                                                         __bf16* __restrict__ oh,
                                                         __bf16* __restrict__ ol) {
  int row = blockIdx.x, tid = threadIdx.x;
#pragma unroll
  for (int j = 0; j < 3; ++j) {
    int d = tid + j * 256;
    float v = x[(size_t)row * DMODEL + d];
    __bf16 h = (__bf16)v;
    oh[(size_t)row * DMODEL + d] = h;
    ol[(size_t)row * DMODEL + d] = (__bf16)(v - (float)h);
  }
}

// ---------------- bf16x3 MFMA GEMM, 2-phase double-buffered staging ----------------
template <int FM, int FN, bool ATOMIC>
__global__ __launch_bounds__(256) void mfma_gemm_kernel(
    const __bf16* __restrict__ Ahi, const __bf16* __restrict__ Alo,
    const __bf16* __restrict__ Bhi, const __bf16* __restrict__ Blo,
    const float* __restrict__ addsrc, const float* __restrict__ bias, float* __restrict__ C,
    int N, int K, int kslice, int nbx, int nby, int nwg) {
  constexpr int BM = FM * 32;
  constexpr int BN = FN * 32;
  constexpr int RGA = BM / 16;
  constexpr int RGB = BN / 16;
  constexpr int NITER = (2 * (RGA + RGB)) / 4;
  constexpr int ABYTES = BM * 64;
  constexpr int BBYTES = BN * 64;
  constexpr int BUFBYTES = 2 * ABYTES + 2 * BBYTES;
  __shared__ char lds[2 * BUFBYTES];

  int tid = threadIdx.x;
  int wave = tid >> 6, lane = tid & 63;
  int wm = wave >> 1, wn = wave & 1;
  int bx, by, kz;
  if (nbx > 0) {
    int orig = (blockIdx.x % 8) * (nwg / 8) + blockIdx.x / 8;
    bx = orig % nbx;
    int t = orig / nbx;
    if (nby > 0) {
      by = t % nby;
      kz = t / nby;
    } else {
      by = t;
      kz = 0;
    }
  } else {
    bx = blockIdx.x;
    by = blockIdx.y;
    kz = blockIdx.z;
  }
  int bm = by * BM;
  int bn = bx * BN;
  int kbeg = ATOMIC ? kz * kslice : 0;
  int kend = ATOMIC ? (kbeg + kslice) : K;
  int l2 = lane >> 2;
  int gch = (lane & 3) ^ ((lane >> 3) & 3);
  int lr = lane & 15, lg = lane >> 4;

  f32x4 acc[FM][FN] = {};

  auto stage = [&](char* buf, int k0) {
#pragma unroll
    for (int it = 0; it < NITER; ++it) {
      int rg = wave + it * 4;
      const __bf16* src;
      int row0, boff;
      if (rg < RGA) {
        src = Ahi;
        row0 = bm + rg * 16;
        boff = rg * 1024;
      } else if (rg < 2 * RGA) {
        src = Alo;
        row0 = bm + (rg - RGA) * 16;
        boff = ABYTES + (rg - RGA) * 1024;
      } else if (rg < 2 * RGA + RGB) {
        src = Bhi;
        row0 = bn + (rg - 2 * RGA) * 16;
        boff = 2 * ABYTES + (rg - 2 * RGA) * 1024;
      } else {
        src = Blo;
        row0 = bn + (rg - 2 * RGA - RGB) * 16;
        boff = 2 * ABYTES + BBYTES + (rg - 2 * RGA - RGB) * 1024;
      }
      gload16(src + (size_t)(row0 + l2) * K + k0 + gch * 8, buf + boff);
    }
  };

  stage(lds, kbeg);
  __syncthreads();

  char* curb = lds;
  char* nxtb = lds + BUFBYTES;
  for (int k0 = kbeg; k0 < kend; k0 += 32) {
    if (k0 + 32 < kend) stage(nxtb, k0 + 32);

    bf16x8 ahi[FM], alo[FM], bhi[FN], blo[FN];
#pragma unroll
    for (int m = 0; m < FM; ++m) {
      int r = wm * FM * 16 + m * 16 + lr;
      int off = r * 64 + ((lg ^ ((r >> 1) & 3)) * 16);
      ahi[m] = *(const bf16x8*)(curb + off);
      alo[m] = *(const bf16x8*)(curb + ABYTES + off);
    }
#pragma unroll
    for (int n = 0; n < FN; ++n) {
      int r = wn * FN * 16 + n * 16 + lr;
      int off = r * 64 + ((lg ^ ((r >> 1) & 3)) * 16);
      bhi[n] = *(const bf16x8*)(curb + 2 * ABYTES + off);
      blo[n] = *(const bf16x8*)(curb + 2 * ABYTES + BBYTES + off);
    }
#pragma unroll
    for (int m = 0; m < FM; ++m)
#pragma unroll
      for (int n = 0; n < FN; ++n) {
        acc[m][n] = __builtin_amdgcn_mfma_f32_16x16x32_bf16(ahi[m], bhi[n], acc[m][n], 0, 0, 0);
        acc[m][n] = __builtin_amdgcn_mfma_f32_16x16x32_bf16(ahi[m], blo[n], acc[m][n], 0, 0, 0);
        acc[m][n] = __builtin_amdgcn_mfma_f32_16x16x32_bf16(alo[m], bhi[n], acc[m][n], 0, 0, 0);
      }
    __syncthreads();
    char* t = curb;
    curb = nxtb;
    nxtb = t;
  }

#pragma unroll
  for (int m = 0; m < FM; ++m) {
#pragma unroll
    for (int n = 0; n < FN; ++n) {
      int gcol = bn + wn * FN * 16 + n * 16 + lr;
      if (gcol < N) {
#pragma unroll
        for (int r = 0; r < 4; ++r) {
          int grow = bm + wm * FM * 16 + m * 16 + lg * 4 + r;
          if (ATOMIC) {
            unsafeAtomicAdd(&C[(size_t)grow * N + gcol], acc[m][n][r]);
          } else {
            float v = acc[m][n][r];
            if (addsrc) v += addsrc[(size_t)grow * N + gcol];
            if (bias) v += bias[gcol];
            C[(size_t)grow * N + gcol] = v;
          }
        }
      }
    }
  }
}

// ---------------- conv+silu for shared B/C channels + dt softplus -> xBC, dts ----------------
__global__ __launch_bounds__(256) void convBC_kernel(const float* __restrict__ zx,
                                                     const float* __restrict__ cw,
                                                     const float* __restrict__ cb,
                                                     const float* __restrict__ dtb,
                                                     float* __restrict__ xBC,
                                                     float* __restrict__ dts) {
  int row = blockIdx.x;
  int c = threadIdx.x;  // 0..255
  int ch = DINNER + c;  // conv-channel index (B/C section)
  int l = row & (L_SEQ - 1);
  float acc = cb[ch];
#pragma unroll
  for (int k = 0; k < 4; ++k) {
    int ls = l - 3 + k;
    if (ls >= 0)
      acc = fmaf(cw[ch * 4 + k], zx[(size_t)(row - 3 + k) * DINPROJ + DINNER + ch], acc);
  }
  xBC[(size_t)row * BCDIM + c] = siluf(acc);
  if (c < NHEADS) {
    float raw = zx[(size_t)row * DINPROJ + DINNER + CONVDIM + c] + dtb[c];
    dts[(size_t)row * NHEADS + c] = softplusf(raw);
  }
}

// ---------------- Sraw = C . B^T per (batch, chunk) — head-independent, hoisted ----------------
__global__ __launch_bounds__(256) void sraw_kernel(const float* __restrict__ xBC,
                                                   float* __restrict__ Sraw) {
  __shared__ float Bs[CHUNK][132];
  __shared__ float Cs[CHUNK][132];
  int ci = blockIdx.x, b = blockIdx.y;
  int tid = threadIdx.x;
  int row0 = b * L_SEQ + ci * CHUNK;
#pragma unroll
  for (int i = 0; i < 4; ++i) {
    int vi = tid + i * 256;
    int t = vi >> 5;
    int n4 = (vi & 31) * 4;
    const float* r = xBC + (size_t)(row0 + t) * BCDIM;
    *(float4*)&Bs[t][n4] = *(const float4*)(r + n4);
    *(float4*)&Cs[t][n4] = *(const float4*)(r + DSTATE + n4);
  }
  __syncthreads();
  int t0 = (tid >> 4) * 2;
  int s0 = (tid & 15) * 2;
  float sacc[2][2] = {};
#pragma unroll
  for (int n = 0; n < DSTATE; n += 4) {
    float cr[2][4], br[2][4];
#pragma unroll
    for (int i = 0; i < 2; ++i) *(float4*)&cr[i][0] = *(const float4*)&Cs[t0 + i][n];
#pragma unroll
    for (int j = 0; j < 2; ++j) *(float4*)&br[j][0] = *(const float4*)&Bs[s0 + j][n];
#pragma unroll
    for (int i = 0; i < 2; ++i)
#pragma unroll
      for (int j = 0; j < 2; ++j)
#pragma unroll
        for (int k = 0; k < 4; ++k) sacc[i][j] = fmaf(cr[i][k], br[j][k], sacc[i][j]);
  }
  float* Sp = Sraw + ((size_t)(b * NCHUNK + ci) * CHUNK) * CHUNK;
#pragma unroll
  for (int i = 0; i < 2; ++i)
#pragma unroll
    for (int j = 0; j < 2; ++j) Sp[(t0 + i) * CHUNK + s0 + j] = sacc[i][j];
}

// ---------------- chunked SSD: X-conv + intra-chunk (VALU) + chunk state (MFMA) ----------
// Gt layout: [bh][ci][p][cs*8..], cs = (n/8) ^ (p&7)  (transposed + chunk-swizzled)
__global__ __launch_bounds__(256) void chunk_local_kernel(
    const float* __restrict__ zx, const float* __restrict__ xBC, const float* __restrict__ Sraw,
    const float* __restrict__ dts, const float* __restrict__ cw, const float* __restrict__ cb,
    const float* __restrict__ Alog, const float* __restrict__ Dp, float* __restrict__ y,
    __bf16* __restrict__ Gt, float* __restrict__ et, float* __restrict__ elast) {
  __shared__ __bf16 Bt[DSTATE][40];   // B^T [n][s] bf16
  __shared__ float Xs[CHUNK][68];     // X [s][p] fp32
  __shared__ __bf16 Xt[HEADDIM][40];  // (sW*X)^T [p][s] bf16
  __shared__ float Ss[CHUNK][36];
  __shared__ __bf16 Gl[HEADDIM][136];  // G staging [p][n]
  __shared__ float sP[CHUNK], sW[CHUNK], sDt[CHUNK];

  int ci = blockIdx.x, h = blockIdx.y, b = blockIdx.z;
  int bh = b * NHEADS + h;
  int tid = threadIdx.x;
  int wave = tid >> 6, lane = tid & 63;
  int row0 = b * L_SEQ + ci * CHUNK;

#pragma unroll
  for (int i = 0; i < 4; ++i) {
    int vi = tid + i * 256;  // 1024
    int s = vi >> 5;
    int n4 = (vi & 31) * 4;
    float4 v = *(const float4*)(xBC + (size_t)(row0 + s) * BCDIM + n4);
    Bt[n4 + 0][s] = (__bf16)v.x;
    Bt[n4 + 1][s] = (__bf16)v.y;
    Bt[n4 + 2][s] = (__bf16)v.z;
    Bt[n4 + 3][s] = (__bf16)v.w;
  }
#pragma unroll
  for (int i = 0; i < 2; ++i) {
    int vi = tid + i * 256;
    int t = vi >> 4;
    int p4 = (vi & 15) * 4;
    int cX = h * HEADDIM + p4;
    float oX[4];
#pragma unroll
    for (int q = 0; q < 4; ++q) oX[q] = cb[cX + q];
#pragma unroll
    for (int k = 0; k < 4; ++k) {
      if (ci > 0 || t + k >= 3) {
        float4 v = *(const float4*)(zx + (size_t)(row0 + t - 3 + k) * DINPROJ + DINNER + cX);
#pragma unroll
        for (int q = 0; q < 4; ++q) oX[q] = fmaf(cw[(cX + q) * 4 + k], ((const float*)&v)[q], oX[q]);
      }
    }
#pragma unroll
    for (int q = 0; q < 4; ++q) Xs[t][p4 + q] = siluf(oX[q]);
  }
  if (tid < 32) {
    int t = tid;
    float Ah = -expf(Alog[h]);
    float dtv = dts[(size_t)(row0 + t) * NHEADS + h];
    float P = dtv * Ah;
#pragma unroll
    for (int off = 1; off < 32; off <<= 1) {
      float u = __shfl_up(P, off, 32);
      if (t >= off) P += u;
    }
    float Plast = __shfl(P, 31, 32);
    float e = expf(P);
    sP[t] = P;
    sDt[t] = dtv;
    sW[t] = expf(Plast - P) * dtv;
    et[(size_t)(bh * NCHUNK + ci) * CHUNK + t] = e;
    if (t == 31) elast[bh * NCHUNK + ci] = e;
  }
  __syncthreads();

  int t0 = (tid >> 4) * 2;
  int s0 = (tid & 15) * 2;
  {
    const float* Sp = Sraw + ((size_t)(b * NCHUNK + ci) * CHUNK) * CHUNK;
#pragma unroll
    for (int i = 0; i < 2; ++i)
#pragma unroll
      for (int j = 0; j < 2; ++j) {
        int t = t0 + i, s = s0 + j;
        float sr = Sp[t * CHUNK + s];
        Ss[t][s] = (t >= s) ? sr * expf(sP[t] - sP[s]) * sDt[s] : 0.f;
      }
  }
#pragma unroll
  for (int i = 0; i < 8; ++i) {
    int vi = tid + i * 256;  // 2048
    int p = vi >> 5;
    int s = vi & 31;
    Xt[p][s] = (__bf16)(sW[s] * Xs[s][p]);
  }
  __syncthreads();

  {
    int p0 = (tid & 15) * 4;
    float acc[2][4] = {};
#pragma unroll
    for (int s = 0; s < CHUNK; s += 4) {
      float sr[2][4], xr[4][4];
#pragma unroll
      for (int i = 0; i < 2; ++i) *(float4*)&sr[i][0] = *(const float4*)&Ss[t0 + i][s];
#pragma unroll
      for (int u = 0; u < 4; ++u) *(float4*)&xr[u][0] = *(const float4*)&Xs[s + u][p0];
#pragma unroll
      for (int i = 0; i < 2; ++i)
#pragma unroll
        for (int j = 0; j < 4; ++j)
#pragma unroll
          for (int u = 0; u < 4; ++u) acc[i][j] = fmaf(sr[i][u], xr[u][j], acc[i][j]);
    }
    float Dh = Dp[h];
#pragma unroll
    for (int i = 0; i < 2; ++i) {
      int row = row0 + t0 + i;
      float4 o;
      o.x = acc[i][0] + Dh * Xs[t0 + i][p0 + 0];
      o.y = acc[i][1] + Dh * Xs[t0 + i][p0 + 1];
      o.z = acc[i][2] + Dh * Xs[t0 + i][p0 + 2];
      o.w = acc[i][3] + Dh * Xs[t0 + i][p0 + 3];
      *(float4*)(y + (size_t)row * DINNER + h * HEADDIM + p0) = o;
    }
  }

  {
    int lr = lane & 15, lg = lane >> 4;
    f32x4 gacc[2][4] = {};
#pragma unroll
    for (int nt = 0; nt < 2; ++nt) {
      bf16x8 af = *(const bf16x8*)&Bt[(wave * 2 + nt) * 16 + lr][lg * 8];
#pragma unroll
      for (int pt = 0; pt < 4; ++pt) {
        bf16x8 bfr = *(const bf16x8*)&Xt[pt * 16 + lr][lg * 8];
        gacc[nt][pt] = __builtin_amdgcn_mfma_f32_16x16x32_bf16(af, bfr, gacc[nt][pt], 0, 0, 0);
      }
    }
#pragma unroll
    for (int nt = 0; nt < 2; ++nt)
#pragma unroll
      for (int pt = 0; pt < 4; ++pt) {
        int p = pt * 16 + lr;
        int n0 = (wave * 2 + nt) * 16 + lg * 4;
        bf16x4 o;
#pragma unroll
        for (int r = 0; r < 4; ++r) o[r] = (__bf16)gacc[nt][pt][r];
        *(bf16x4*)&Gl[p][n0] = o;
      }
  }
  __syncthreads();
  {
    __bf16* Gp = Gt + ((size_t)bh * NCHUNK + ci) * (DSTATE * HEADDIM);
#pragma unroll
    for (int i = 0; i < 4; ++i) {
      int vi = tid + i * 256;  // 1024
      int p = vi >> 4;
      int c = vi & 15;
      bf16x8 v = *(const bf16x8*)&Gl[p][c * 8];
      int cs = c ^ (p & 7);
      *(bf16x8*)(Gp + (size_t)p * DSTATE + cs * 8) = v;
    }
  }
}

// ---------------- combine chunk states (bf16x8-wide, fp32 running state) -----------
__global__ __launch_bounds__(256) void combine_kernel(__bf16* __restrict__ G,
                                                      const float* __restrict__ elast) {
  int part = blockIdx.x;  // 0..3
  int bh = blockIdx.y;
  int gi = part * 256 + threadIdx.x;  // bf16x8 group index within 1024
  __bf16* base = G + (size_t)bh * NCHUNK * (DSTATE * HEADDIM);
  const float* el = elast + bh * NCHUNK;
  float hs[8] = {};
#pragma unroll
  for (int c = 0; c < NCHUNK - 1; ++c) {
    bf16x8 g = *(bf16x8*)(base + (size_t)c * (DSTATE * HEADDIM) + gi * 8);
    float e = el[c];
    bf16x8 o;
#pragma unroll
    for (int q = 0; q < 8; ++q) {
      hs[q] = fmaf(e, hs[q], (float)g[q]);
      o[q] = (__bf16)hs[q];
    }
    *(bf16x8*)(base + (size_t)c * (DSTATE * HEADDIM) + gi * 8) = o;
  }
}

// ---------------- inter-chunk contribution: MFMA bf16 (C 32x128 @ Ht^T 128x64) ---------------
__global__ __launch_bounds__(256) void apply_inter_kernel(const float* __restrict__ xBC,
                                                          const __bf16* __restrict__ Gt,
                                                          const float* __restrict__ et,
                                                          float* __restrict__ y) {
  __shared__ __bf16 CsB[CHUNK * DSTATE];   // [t][128] bf16, chunk-swizzled
  __shared__ __bf16 HsB[HEADDIM * DSTATE]; // [p][128] bf16, pre-swizzled global -> linear stage
  __shared__ float sE[CHUNK];
  int ci = blockIdx.x + 1;
  int h = blockIdx.y, b = blockIdx.z;
  int bh = b * NHEADS + h;
  int tid = threadIdx.x;
  int wave = tid >> 6, lane = tid & 63;
  int row0 = b * L_SEQ + ci * CHUNK;

  const __bf16* Hsrc = Gt + ((size_t)bh * NCHUNK + (ci - 1)) * (DSTATE * HEADDIM);
#pragma unroll
  for (int r = 0; r < 4; ++r) {
    gload16(Hsrc + (size_t)r * 2048 + wave * 512 + lane * 8,
            (char*)HsB + r * 4096 + wave * 1024);
  }
#pragma unroll
  for (int i = 0; i < 2; ++i) {
    int vi = tid + i * 256;
    int t = vi >> 4;
    int c = vi & 15;
    const float* src = xBC + (size_t)(row0 + t) * BCDIM + DSTATE + c * 8;
    float4 v0 = *(const float4*)src;
    float4 v1 = *(const float4*)(src + 4);
    bf16x8 o;
    o[0] = (__bf16)v0.x; o[1] = (__bf16)v0.y; o[2] = (__bf16)v0.z; o[3] = (__bf16)v0.w;
    o[4] = (__bf16)v1.x; o[5] = (__bf16)v1.y; o[6] = (__bf16)v1.z; o[7] = (__bf16)v1.w;
    int cs = c ^ (t & 7);
    *(bf16x8*)&CsB[t * DSTATE + cs * 8] = o;
  }
  if (tid < CHUNK) sE[tid] = et[(size_t)(bh * NCHUNK + ci) * CHUNK + tid];
  __syncthreads();

  int lr = lane & 15, lg = lane >> 4;
  int wm = wave >> 1;
  int wnb = (wave & 1) * 2;
  f32x4 acc[2] = {};
#pragma unroll
  for (int ks = 0; ks < 4; ++ks) {
    int ar = wm * 16 + lr;
    bf16x8 af = *(const bf16x8*)&CsB[ar * DSTATE + (((ks * 4 + lg) ^ (ar & 7)) * 8)];
#pragma unroll
    for (int nn = 0; nn < 2; ++nn) {
      int br = (wnb + nn) * 16 + lr;
      bf16x8 bfr = *(const bf16x8*)&HsB[br * DSTATE + (((ks * 4 + lg) ^ (br & 7)) * 8)];
      acc[nn] = __builtin_amdgcn_mfma_f32_16x16x32_bf16(af, bfr, acc[nn], 0, 0, 0);
    }
  }
#pragma unroll
  for (int nn = 0; nn < 2; ++nn) {
    int p = (wnb + nn) * 16 + lr;
#pragma unroll
    for (int r = 0; r < 4; ++r) {
      int t = wm * 16 + lg * 4 + r;
      float e = sE[t];
      float* yp = &y[(size_t)(row0 + t) * DINNER + h * HEADDIM + p];
      *yp = fmaf(e, acc[nn][r], *yp);
    }
  }
}

// ---------------- gate (silu(z)) + RMS norm -> bf16 hi/lo ----------------
__global__ __launch_bounds__(256) void gate_rms_kernel(const float* __restrict__ y,
                                                       const float* __restrict__ zx,
                                                       const float* __restrict__ rmsw,
                                                       __bf16* __restrict__ oh,
                                                       __bf16* __restrict__ ol) {
  __shared__ float sred[8];
  int row = blockIdx.x, tid = threadIdx.x;
  const float* z = zx + (size_t)row * DINPROJ;
  const float* yr = y + (size_t)row * DINNER;
  float v[6];
  float ss = 0.f;
#pragma unroll
  for (int j = 0; j < 6; ++j) {
    int d = tid + j * 256;
    float val = yr[d] * siluf(z[d]);
    v[j] = val;
    ss += val * val;
  }
  float total = block_reduce_sum(ss, sred);
  float r = 1.f / sqrtf(total * (1.f / DINNER) + 1e-5f);
#pragma unroll
  for (int j = 0; j < 6; ++j) {
    int d = tid + j * 256;
    float val = v[j] * r * rmsw[d];
    __bf16 h = (__bf16)val;
    oh[(size_t)row * DINNER + d] = h;
    ol[(size_t)row * DINNER + d] = (__bf16)(val - (float)h);
  }
}

extern "C" void kernel_launch(void* const* d_in, const int* in_sizes, int n_in,
                              void* d_out, int out_size, void* d_ws, size_t ws_size,
                              hipStream_t stream) {
  const int* tokens = (const int*)d_in[0];
  const float* emb = (const float*)d_in[1];
  const float* ln_w = (const float*)d_in[2];
  const float* ln_b = (const float*)d_in[3];
  const float* Win = (const float*)d_in[4];
  const float* conv_w = (const float*)d_in[5];
  const float* conv_b = (const float*)d_in[6];
  const float* dt_bias = (const float*)d_in[7];
  const float* A_log = (const float*)d_in[8];
  const float* Dp = (const float*)d_in[9];
  const float* rms_w = (const float*)d_in[10];
  const float* Wout = (const float*)d_in[11];
  const float* Wcls = (const float*)d_in[12];
  const float* bcls = (const float*)d_in[13];
  float* out = (float*)d_out;

  float* ws = (float*)d_ws;
  float* x = ws;                                // 1024*768
  float* zx = x + (size_t)ROWS * DMODEL;        // 1024*3352
  float* y = zx + (size_t)ROWS * DINPROJ;       // 1024*1536
  __bf16* Gt = (__bf16*)(y + (size_t)ROWS * DINNER);  // transposed+swizzled bf16
  float* et = (float*)(Gt + (size_t)B_SZ * NHEADS * NCHUNK * DSTATE * HEADDIM);
  float* elast = et + (size_t)B_SZ * NHEADS * NCHUNK * CHUNK;
  float* xBC = elast + B_SZ * NHEADS * NCHUNK;  // 1024*256
  float* Sraw = xBC + (size_t)ROWS * BCDIM;     // 2*16*32*32
  float* dts = Sraw + (size_t)B_SZ * NCHUNK * CHUNK * CHUNK;  // 1024*24
  __bf16* bp = (__bf16*)(dts + (size_t)ROWS * NHEADS);
  __bf16* nxh = bp;  bp += (size_t)ROWS * DMODEL;
  __bf16* nxl = bp;  bp += (size_t)ROWS * DMODEL;
  __bf16* yh = bp;   bp += (size_t)ROWS * DINNER;
  __bf16* yl = bp;   bp += (size_t)ROWS * DINNER;
  __bf16* xh = bp;   bp += (size_t)ROWS * DMODEL;
  __bf16* xl = bp;   bp += (size_t)ROWS * DMODEL;
  __bf16* wih0 = bp; bp += (size_t)NPAD_IN * DMODEL;
  __bf16* wil0 = bp; bp += (size_t)NPAD_IN * DMODEL;
  __bf16* wih1 = bp; bp += (size_t)NPAD_IN * DMODEL;
  __bf16* wil1 = bp; bp += (size_t)NPAD_IN * DMODEL;
  __bf16* woh0 = bp; bp += (size_t)DMODEL * DINNER;
  __bf16* wol0 = bp; bp += (size_t)DMODEL * DINNER;
  __bf16* woh1 = bp; bp += (size_t)DMODEL * DINNER;
  __bf16* wol1 = bp; bp += (size_t)DMODEL * DINNER;
  __bf16* wch = bp;  bp += (size_t)NPAD_CLS * DMODEL;
  __bf16* wcl = bp;

  constexpr int TIN = (NPAD_IN / 32) * (DMODEL / 32);
  constexpr int TOUT = (DMODEL / 32) * (DINNER / 32);
  constexpr int TCLS = (NPAD_CLS / 32) * (DMODEL / 32);
  decomp_all_kernel<<<2 * TIN + 2 * TOUT + TCLS + ROWS, 256, 0, stream>>>(
      Win, Wout, Wcls, tokens, emb, ln_w, ln_b, x, nxh, nxl, wih0, wil0, wih1, wil1, woh0, wol0,
      woh1, wol1, wch, wcl);

  for (int blk = 0; blk < 2; ++blk) {
    const float* cw_b = conv_w + (size_t)blk * CONVDIM * 4;
    const float* cb_b = conv_b + (size_t)blk * CONVDIM;
    const float* dtb_b = dt_bias + (size_t)blk * NHEADS;
    const float* Alog_b = A_log + (size_t)blk * NHEADS;
    const float* Dp_b = Dp + (size_t)blk * NHEADS;
    const float* rmsw_b = rms_w + (size_t)blk * DINNER;
    __bf16* wih = blk ? wih1 : wih0;
    __bf16* wil = blk ? wil1 : wil0;
    __bf16* woh = blk ? woh1 : woh0;
    __bf16* wol = blk ? wol1 : wol0;

    if (blk == 1) {
      ln_kernel<<<ROWS, 256, 0, stream>>>(x, ln_w + (size_t)blk * DMODEL,
                                          ln_b + (size_t)blk * DMODEL, nxh, nxl);
    }

    // in-proj: 128x64 tiles, 54*8 = 432 blocks (432 % 8 == 0), by-major XCD swizzle
    mfma_gemm_kernel<4, 2, false><<<(NPAD_IN / 64) * (ROWS / 128), 256, 0, stream>>>(
        nxh, nxl, wih, wil, nullptr, nullptr, zx, DINPROJ, DMODEL, 0, NPAD_IN / 64, 0,
        (NPAD_IN / 64) * (ROWS / 128));

    convBC_kernel<<<ROWS, BCDIM, 0, stream>>>(zx, cw_b, cb_b, dtb_b, xBC, dts);

    sraw_kernel<<<dim3(NCHUNK, B_SZ), 256, 0, stream>>>(xBC, Sraw);

    chunk_local_kernel<<<dim3(NCHUNK, NHEADS, B_SZ), 256, 0, stream>>>(
        zx, xBC, Sraw, dts, cw_b, cb_b, Alog_b, Dp_b, y, Gt, et, elast);

    combine_kernel<<<dim3(4, B_SZ * NHEADS), 256, 0, stream>>>(Gt, elast);

    apply_inter_kernel<<<dim3(NCHUNK - 1, NHEADS, B_SZ), 256, 0, stream>>>(xBC, Gt, et, y);

    gate_rms_kernel<<<ROWS, 256, 0, stream>>>(y, zx, rmsw_b, yh, yl);

    mfma_gemm_kernel<2, 2, true><<<(DMODEL / 64) * (ROWS / 64) * 4, 256, 0, stream>>>(
        yh, yl, woh, wol, nullptr, nullptr, x, DMODEL, DINNER, DINNER / 4, DMODEL / 64,
        ROWS / 64, (DMODEL / 64) * (ROWS / 64) * 4);
  }

  act_decomp_kernel<<<ROWS, 256, 0, stream>>>(x, xh, xl);
  mfma_gemm_kernel<2, 2, false><<<(NPAD_CLS / 64) * (ROWS / 64), 256, 0, stream>>>(
      xh, xl, wch, wcl, nullptr, bcls, out, 1000, DMODEL, 0, NPAD_CLS / 64, 0,
      (NPAD_CLS / 64) * (ROWS / 64));
}

// Round 17
// 216.732 us; speedup vs baseline: 1.1973x; 1.0168x over previous
//
#include <hip/hip_runtime.h>
#include <hip/hip_bf16.h>
#include <math.h>

#define B_SZ 2
#define L_SEQ 512
#define DMODEL 768
#define DINNER 1536
#define DSTATE 128
#define HEADDIM 64
#define NHEADS 24
#define CONVDIM 1792
#define DINPROJ 3352
#define ROWS (B_SZ * L_SEQ)  // 1024

#define CHUNK 32
#define NCHUNK (L_SEQ / CHUNK)  // 16
#define BCDIM (2 * DSTATE)      // 256

#define NPAD_IN 3456   // 54 * 64
#define NPAD_CLS 1024  // 16 * 64

typedef __attribute__((ext_vector_type(8))) __bf16 bf16x8;
typedef __attribute__((ext_vector_type(4))) __bf16 bf16x4;
typedef __attribute__((ext_vector_type(4))) float f32x4;

typedef __attribute__((address_space(1))) const unsigned int as1_u32;
typedef __attribute__((address_space(3))) unsigned int as3_u32;

__device__ __forceinline__ void gload16(const void* g, void* s) {
  __builtin_amdgcn_global_load_lds((as1_u32*)(unsigned long)g, (as3_u32*)(unsigned long)s, 16, 0,
                                   0);
}

__device__ __forceinline__ float siluf(float x) { return x / (1.f + expf(-x)); }
__device__ __forceinline__ float softplusf(float x) {
  return x > 0.f ? x + log1pf(expf(-x)) : log1pf(expf(x));
}

__device__ __forceinline__ float block_reduce_sum(float v, float* sred) {
  int tid = threadIdx.x;
  for (int off = 32; off; off >>= 1) v += __shfl_down(v, off, 64);
  int wid = tid >> 6, lane = tid & 63;
  if (lane == 0) sred[wid] = v;
  __syncthreads();
  float total;
  if (tid == 0) {
    total = 0.f;
    int nw = blockDim.x >> 6;
    for (int i = 0; i < nw; ++i) total += sred[i];
    sred[0] = total;
  }
  __syncthreads();
  total = sred[0];
  __syncthreads();
  return total;
}

// ---------------- fused: embed gather + LN(blk0) + all 5 weight transpose/decompose ------------
__global__ __launch_bounds__(256) void decomp_all_kernel(
    const float* __restrict__ Win, const float* __restrict__ Wout,
    const float* __restrict__ Wcls, const int* __restrict__ tok, const float* __restrict__ emb,
    const float* __restrict__ lnw0, const float* __restrict__ lnb0, float* __restrict__ x,
    __bf16* __restrict__ nxh, __bf16* __restrict__ nxl, __bf16* __restrict__ wih0,
    __bf16* __restrict__ wil0, __bf16* __restrict__ wih1, __bf16* __restrict__ wil1,
    __bf16* __restrict__ woh0, __bf16* __restrict__ wol0, __bf16* __restrict__ woh1,
    __bf16* __restrict__ wol1, __bf16* __restrict__ wch, __bf16* __restrict__ wcl) {
  constexpr int TIN = (NPAD_IN / 32) * (DMODEL / 32);    // 2592
  constexpr int TOUT = (DMODEL / 32) * (DINNER / 32);    // 1152
  constexpr int TCLS = (NPAD_CLS / 32) * (DMODEL / 32);  // 768
  __shared__ float tile[32][33];
  int bid = blockIdx.x;
  int tid = threadIdx.x;

  if (bid >= 2 * TIN + 2 * TOUT + TCLS) {
    int row = bid - (2 * TIN + 2 * TOUT + TCLS);
    int t = tok[row];
    float v[3];
    float s = 0.f;
#pragma unroll
    for (int j = 0; j < 3; ++j) {
      v[j] = emb[(size_t)t * DMODEL + tid + j * 256];
      s += v[j];
      x[(size_t)row * DMODEL + tid + j * 256] = v[j];
    }
    float* sred = (float*)tile;
    float mean = block_reduce_sum(s, sred) * (1.f / DMODEL);
    float s2 = 0.f;
#pragma unroll
    for (int j = 0; j < 3; ++j) {
      float d = v[j] - mean;
      s2 += d * d;
    }
    float var = block_reduce_sum(s2, sred) * (1.f / DMODEL);
    float r = 1.f / sqrtf(var + 1e-5f);
#pragma unroll
    for (int j = 0; j < 3; ++j) {
      int d = tid + j * 256;
      float val = (v[j] - mean) * r * lnw0[d] + lnb0[d];
      __bf16 h = (__bf16)val;
      nxh[(size_t)row * DMODEL + d] = h;
      nxl[(size_t)row * DMODEL + d] = (__bf16)(val - (float)h);
    }
    return;
  }

  const float* W;
  __bf16 *Th, *Tl;
  int K, N, ntx, r;
  if (bid < TIN) {
    W = Win; Th = wih0; Tl = wil0; K = DMODEL; N = DINPROJ; ntx = NPAD_IN / 32; r = bid;
  } else if (bid < 2 * TIN) {
    W = Win + (size_t)DMODEL * DINPROJ; Th = wih1; Tl = wil1; K = DMODEL; N = DINPROJ;
    ntx = NPAD_IN / 32; r = bid - TIN;
  } else if (bid < 2 * TIN + TOUT) {
    W = Wout; Th = woh0; Tl = wol0; K = DINNER; N = DMODEL; ntx = DMODEL / 32; r = bid - 2 * TIN;
  } else if (bid < 2 * TIN + 2 * TOUT) {
    W = Wout + (size_t)DINNER * DMODEL; Th = woh1; Tl = wol1; K = DINNER; N = DMODEL;
    ntx = DMODEL / 32; r = bid - 2 * TIN - TOUT;
  } else {
    W = Wcls; Th = wch; Tl = wcl; K = DMODEL; N = 1000; ntx = NPAD_CLS / 32;
    r = bid - 2 * TIN - 2 * TOUT;
  }
  int bn = (r % ntx) * 32, bk = (r / ntx) * 32;

  int i = tid >> 3, j4 = (tid & 7) * 4;
  int kk = bk + i;
  int nn = bn + j4;
  float4 v;
  if (nn + 3 < N) {
    v = *(const float4*)(W + (size_t)kk * N + nn);
  } else {
    v.x = (nn + 0 < N) ? W[(size_t)kk * N + nn + 0] : 0.f;
    v.y = (nn + 1 < N) ? W[(size_t)kk * N + nn + 1] : 0.f;
    v.z = (nn + 2 < N) ? W[(size_t)kk * N + nn + 2] : 0.f;
    v.w = (nn + 3 < N) ? W[(size_t)kk * N + nn + 3] : 0.f;
  }
  tile[i][j4 + 0] = v.x;
  tile[i][j4 + 1] = v.y;
  tile[i][j4 + 2] = v.z;
  tile[i][j4 + 3] = v.w;
  __syncthreads();
  int n = bn + i;
  bf16x4 hv, lv;
#pragma unroll
  for (int q = 0; q < 4; ++q) {
    float f = tile[j4 + q][i];
    __bf16 h = (__bf16)f;
    hv[q] = h;
    lv[q] = (__bf16)(f - (float)h);
  }
  *(bf16x4*)(Th + (size_t)n * K + bk + j4) = hv;
  *(bf16x4*)(Tl + (size_t)n * K + bk + j4) = lv;
}

// ---------------- layernorm -> bf16 hi/lo ----------------
__global__ __launch_bounds__(256) void ln_kernel(const float* __restrict__ x,
                                                 const float* __restrict__ w,
                                                 const float* __restrict__ b,
                                                 __bf16* __restrict__ oh,
                                                 __bf16* __restrict__ ol) {
  __shared__ float sred[8];
  int row = blockIdx.x, tid = threadIdx.x;
  const float* xr = x + (size_t)row * DMODEL;
  float v[3];
  float s = 0.f;
#pragma unroll
  for (int j = 0; j < 3; ++j) {
    v[j] = xr[tid + j * 256];
    s += v[j];
  }
  float mean = block_reduce_sum(s, sred) * (1.f / DMODEL);
  float s2 = 0.f;
#pragma unroll
  for (int j = 0; j < 3; ++j) {
    float d = v[j] - mean;
    s2 += d * d;
  }
  float var = block_reduce_sum(s2, sred) * (1.f / DMODEL);
  float r = 1.f / sqrtf(var + 1e-5f);
#pragma unroll
  for (int j = 0; j < 3; ++j) {
    int d = tid + j * 256;
    float val = (v[j] - mean) * r * w[d] + b[d];
    __bf16 h = (__bf16)val;
    oh[(size_t)row * DMODEL + d] = h;
    ol[(size_t)row * DMODEL + d] = (__bf16)(val - (float)h);
  }
}

// ---------------- x -> bf16 hi/lo ----------------
__global__ __launch_bounds__(256) void act_decomp_kernel(const float* __restrict__ x,
                                                         __bf16* __restrict__ oh,
                                                         __bf16* __restrict__ ol) {
  int row = blockIdx.x, tid = threadIdx.x;
#pragma unroll
  for (int j = 0; j < 3; ++j) {
    int d = tid + j * 256;
    float v = x[(size_t)row * DMODEL + d];
    __bf16 h = (__bf16)v;
    oh[(size_t)row * DMODEL + d] = h;
    ol[(size_t)row * DMODEL + d] = (__bf16)(v - (float)h);
  }
}

// ---------------- bf16x3 MFMA GEMM, 2-phase double-buffered staging ----------------
template <int FM, int FN, bool ATOMIC>
__global__ __launch_bounds__(256) void mfma_gemm_kernel(
    const __bf16* __restrict__ Ahi, const __bf16* __restrict__ Alo,
    const __bf16* __restrict__ Bhi, const __bf16* __restrict__ Blo,
    const float* __restrict__ addsrc, const float* __restrict__ bias, float* __restrict__ C,
    int N, int K, int kslice, int nbx, int nby, int nwg) {
  constexpr int BM = FM * 32;
  constexpr int BN = FN * 32;
  constexpr int RGA = BM / 16;
  constexpr int RGB = BN / 16;
  constexpr int NITER = (2 * (RGA + RGB)) / 4;
  constexpr int ABYTES = BM * 64;
  constexpr int BBYTES = BN * 64;
  constexpr int BUFBYTES = 2 * ABYTES + 2 * BBYTES;
  __shared__ char lds[2 * BUFBYTES];

  int tid = threadIdx.x;
  int wave = tid >> 6, lane = tid & 63;
  int wm = wave >> 1, wn = wave & 1;
  int bx, by, kz;
  if (nbx > 0) {
    int orig = (blockIdx.x % 8) * (nwg / 8) + blockIdx.x / 8;
    bx = orig % nbx;
    int t = orig / nbx;
    if (nby > 0) {
      by = t % nby;
      kz = t / nby;
    } else {
      by = t;
      kz = 0;
    }
  } else {
    bx = blockIdx.x;
    by = blockIdx.y;
    kz = blockIdx.z;
  }
  int bm = by * BM;
  int bn = bx * BN;
  int kbeg = ATOMIC ? kz * kslice : 0;
  int kend = ATOMIC ? (kbeg + kslice) : K;
  int l2 = lane >> 2;
  int gch = (lane & 3) ^ ((lane >> 3) & 3);
  int lr = lane & 15, lg = lane >> 4;

  f32x4 acc[FM][FN] = {};

  auto stage = [&](char* buf, int k0) {
#pragma unroll
    for (int it = 0; it < NITER; ++it) {
      int rg = wave + it * 4;
      const __bf16* src;
      int row0, boff;
      if (rg < RGA) {
        src = Ahi;
        row0 = bm + rg * 16;
        boff = rg * 1024;
      } else if (rg < 2 * RGA) {
        src = Alo;
        row0 = bm + (rg - RGA) * 16;
        boff = ABYTES + (rg - RGA) * 1024;
      } else if (rg < 2 * RGA + RGB) {
        src = Bhi;
        row0 = bn + (rg - 2 * RGA) * 16;
        boff = 2 * ABYTES + (rg - 2 * RGA) * 1024;
      } else {
        src = Blo;
        row0 = bn + (rg - 2 * RGA - RGB) * 16;
        boff = 2 * ABYTES + BBYTES + (rg - 2 * RGA - RGB) * 1024;
      }
      gload16(src + (size_t)(row0 + l2) * K + k0 + gch * 8, buf + boff);
    }
  };

  stage(lds, kbeg);
  __syncthreads();

  char* curb = lds;
  char* nxtb = lds + BUFBYTES;
  for (int k0 = kbeg; k0 < kend; k0 += 32) {
    if (k0 + 32 < kend) stage(nxtb, k0 + 32);

    bf16x8 ahi[FM], alo[FM], bhi[FN], blo[FN];
#pragma unroll
    for (int m = 0; m < FM; ++m) {
      int r = wm * FM * 16 + m * 16 + lr;
      int off = r * 64 + ((lg ^ ((r >> 1) & 3)) * 16);
      ahi[m] = *(const bf16x8*)(curb + off);
      alo[m] = *(const bf16x8*)(curb + ABYTES + off);
    }
#pragma unroll
    for (int n = 0; n < FN; ++n) {
      int r = wn * FN * 16 + n * 16 + lr;
      int off = r * 64 + ((lg ^ ((r >> 1) & 3)) * 16);
      bhi[n] = *(const bf16x8*)(curb + 2 * ABYTES + off);
      blo[n] = *(const bf16x8*)(curb + 2 * ABYTES + BBYTES + off);
    }
#pragma unroll
    for (int m = 0; m < FM; ++m)
#pragma unroll
      for (int n = 0; n < FN; ++n) {
        acc[m][n] = __builtin_amdgcn_mfma_f32_16x16x32_bf16(ahi[m], bhi[n], acc[m][n], 0, 0, 0);
        acc[m][n] = __builtin_amdgcn_mfma_f32_16x16x32_bf16(ahi[m], blo[n], acc[m][n], 0, 0, 0);
        acc[m][n] = __builtin_amdgcn_mfma_f32_16x16x32_bf16(alo[m], bhi[n], acc[m][n], 0, 0, 0);
      }
    __syncthreads();
    char* t = curb;
    curb = nxtb;
    nxtb = t;
  }

#pragma unroll
  for (int m = 0; m < FM; ++m) {
#pragma unroll
    for (int n = 0; n < FN; ++n) {
      int gcol = bn + wn * FN * 16 + n * 16 + lr;
      if (gcol < N) {
#pragma unroll
        for (int r = 0; r < 4; ++r) {
          int grow = bm + wm * FM * 16 + m * 16 + lg * 4 + r;
          if (ATOMIC) {
            unsafeAtomicAdd(&C[(size_t)grow * N + gcol], acc[m][n][r]);
          } else {
            float v = acc[m][n][r];
            if (addsrc) v += addsrc[(size_t)grow * N + gcol];
            if (bias) v += bias[gcol];
            C[(size_t)grow * N + gcol] = v;
          }
        }
      }
    }
  }
}

// ---------------- conv+silu for shared B/C channels + dt softplus -> xBC, dts ----------------
__global__ __launch_bounds__(256) void convBC_kernel(const float* __restrict__ zx,
                                                     const float* __restrict__ cw,
                                                     const float* __restrict__ cb,
                                                     const float* __restrict__ dtb,
                                                     float* __restrict__ xBC,
                                                     float* __restrict__ dts) {
  int row = blockIdx.x;
  int c = threadIdx.x;  // 0..255
  int ch = DINNER + c;  // conv-channel index (B/C section)
  int l = row & (L_SEQ - 1);
  float acc = cb[ch];
#pragma unroll
  for (int k = 0; k < 4; ++k) {
    int ls = l - 3 + k;
    if (ls >= 0)
      acc = fmaf(cw[ch * 4 + k], zx[(size_t)(row - 3 + k) * DINPROJ + DINNER + ch], acc);
  }
  xBC[(size_t)row * BCDIM + c] = siluf(acc);
  if (c < NHEADS) {
    float raw = zx[(size_t)row * DINPROJ + DINNER + CONVDIM + c] + dtb[c];
    dts[(size_t)row * NHEADS + c] = softplusf(raw);
  }
}

// ---------------- Sraw = C . B^T per (batch, chunk) — head-independent, hoisted ----------------
__global__ __launch_bounds__(256) void sraw_kernel(const float* __restrict__ xBC,
                                                   float* __restrict__ Sraw) {
  __shared__ float Bs[CHUNK][132];
  __shared__ float Cs[CHUNK][132];
  int ci = blockIdx.x, b = blockIdx.y;
  int tid = threadIdx.x;
  int row0 = b * L_SEQ + ci * CHUNK;
#pragma unroll
  for (int i = 0; i < 4; ++i) {
    int vi = tid + i * 256;
    int t = vi >> 5;
    int n4 = (vi & 31) * 4;
    const float* r = xBC + (size_t)(row0 + t) * BCDIM;
    *(float4*)&Bs[t][n4] = *(const float4*)(r + n4);
    *(float4*)&Cs[t][n4] = *(const float4*)(r + DSTATE + n4);
  }
  __syncthreads();
  int t0 = (tid >> 4) * 2;
  int s0 = (tid & 15) * 2;
  float sacc[2][2] = {};
#pragma unroll
  for (int n = 0; n < DSTATE; n += 4) {
    float cr[2][4], br[2][4];
#pragma unroll
    for (int i = 0; i < 2; ++i) *(float4*)&cr[i][0] = *(const float4*)&Cs[t0 + i][n];
#pragma unroll
    for (int j = 0; j < 2; ++j) *(float4*)&br[j][0] = *(const float4*)&Bs[s0 + j][n];
#pragma unroll
    for (int i = 0; i < 2; ++i)
#pragma unroll
      for (int j = 0; j < 2; ++j)
#pragma unroll
        for (int k = 0; k < 4; ++k) sacc[i][j] = fmaf(cr[i][k], br[j][k], sacc[i][j]);
  }
  float* Sp = Sraw + ((size_t)(b * NCHUNK + ci) * CHUNK) * CHUNK;
#pragma unroll
  for (int i = 0; i < 2; ++i)
#pragma unroll
    for (int j = 0; j < 2; ++j) Sp[(t0 + i) * CHUNK + s0 + j] = sacc[i][j];
}

// ---------------- chunked SSD: X-conv + intra-chunk (VALU) + chunk state (MFMA) ----------
// Gt layout: [bh][ci][p][cs*8..], cs = (n/8) ^ (p&7)  (transposed + chunk-swizzled)
__global__ __launch_bounds__(256) void chunk_local_kernel(
    const float* __restrict__ zx, const float* __restrict__ xBC, const float* __restrict__ Sraw,
    const float* __restrict__ dts, const float* __restrict__ cw, const float* __restrict__ cb,
    const float* __restrict__ Alog, const float* __restrict__ Dp, float* __restrict__ y,
    __bf16* __restrict__ Gt, float* __restrict__ et, float* __restrict__ elast) {
  __shared__ __bf16 Bt[DSTATE][40];   // B^T [n][s] bf16
  __shared__ float Xs[CHUNK][68];     // X [s][p] fp32
  __shared__ __bf16 Xt[HEADDIM][40];  // (sW*X)^T [p][s] bf16
  __shared__ float Ss[CHUNK][36];
  __shared__ __bf16 Gl[HEADDIM][136];  // G staging [p][n]
  __shared__ float sP[CHUNK], sW[CHUNK], sDt[CHUNK];

  int ci = blockIdx.x, h = blockIdx.y, b = blockIdx.z;
  int bh = b * NHEADS + h;
  int tid = threadIdx.x;
  int wave = tid >> 6, lane = tid & 63;
  int row0 = b * L_SEQ + ci * CHUNK;

#pragma unroll
  for (int i = 0; i < 4; ++i) {
    int vi = tid + i * 256;  // 1024
    int s = vi >> 5;
    int n4 = (vi & 31) * 4;
    float4 v = *(const float4*)(xBC + (size_t)(row0 + s) * BCDIM + n4);
    Bt[n4 + 0][s] = (__bf16)v.x;
    Bt[n4 + 1][s] = (__bf16)v.y;
    Bt[n4 + 2][s] = (__bf16)v.z;
    Bt[n4 + 3][s] = (__bf16)v.w;
  }
#pragma unroll
  for (int i = 0; i < 2; ++i) {
    int vi = tid + i * 256;
    int t = vi >> 4;
    int p4 = (vi & 15) * 4;
    int cX = h * HEADDIM + p4;
    float oX[4];
#pragma unroll
    for (int q = 0; q < 4; ++q) oX[q] = cb[cX + q];
#pragma unroll
    for (int k = 0; k < 4; ++k) {
      if (ci > 0 || t + k >= 3) {
        float4 v = *(const float4*)(zx + (size_t)(row0 + t - 3 + k) * DINPROJ + DINNER + cX);
#pragma unroll
        for (int q = 0; q < 4; ++q) oX[q] = fmaf(cw[(cX + q) * 4 + k], ((const float*)&v)[q], oX[q]);
      }
    }
#pragma unroll
    for (int q = 0; q < 4; ++q) Xs[t][p4 + q] = siluf(oX[q]);
  }
  if (tid < 32) {
    int t = tid;
    float Ah = -expf(Alog[h]);
    float dtv = dts[(size_t)(row0 + t) * NHEADS + h];
    float P = dtv * Ah;
#pragma unroll
    for (int off = 1; off < 32; off <<= 1) {
      float u = __shfl_up(P, off, 32);
      if (t >= off) P += u;
    }
    float Plast = __shfl(P, 31, 32);
    float e = expf(P);
    sP[t] = P;
    sDt[t] = dtv;
    sW[t] = expf(Plast - P) * dtv;
    et[(size_t)(bh * NCHUNK + ci) * CHUNK + t] = e;
    if (t == 31) elast[bh * NCHUNK + ci] = e;
  }
  __syncthreads();

  int t0 = (tid >> 4) * 2;
  int s0 = (tid & 15) * 2;
  {
    const float* Sp = Sraw + ((size_t)(b * NCHUNK + ci) * CHUNK) * CHUNK;
#pragma unroll
    for (int i = 0; i < 2; ++i)
#pragma unroll
      for (int j = 0; j < 2; ++j) {
        int t = t0 + i, s = s0 + j;
        float sr = Sp[t * CHUNK + s];
        Ss[t][s] = (t >= s) ? sr * expf(sP[t] - sP[s]) * sDt[s] : 0.f;
      }
  }
#pragma unroll
  for (int i = 0; i < 8; ++i) {
    int vi = tid + i * 256;  // 2048
    int p = vi >> 5;
    int s = vi & 31;
    Xt[p][s] = (__bf16)(sW[s] * Xs[s][p]);
  }
  __syncthreads();

  {
    int p0 = (tid & 15) * 4;
    float acc[2][4] = {};
#pragma unroll
    for (int s = 0; s < CHUNK; s += 4) {
      float sr[2][4], xr[4][4];
#pragma unroll
      for (int i = 0; i < 2; ++i) *(float4*)&sr[i][0] = *(const float4*)&Ss[t0 + i][s];
#pragma unroll
      for (int u = 0; u < 4; ++u) *(float4*)&xr[u][0] = *(const float4*)&Xs[s + u][p0];
#pragma unroll
      for (int i = 0; i < 2; ++i)
#pragma unroll
        for (int j = 0; j < 4; ++j)
#pragma unroll
          for (int u = 0; u < 4; ++u) acc[i][j] = fmaf(sr[i][u], xr[u][j], acc[i][j]);
    }
    float Dh = Dp[h];
#pragma unroll
    for (int i = 0; i < 2; ++i) {
      int row = row0 + t0 + i;
      float4 o;
      o.x = acc[i][0] + Dh * Xs[t0 + i][p0 + 0];
      o.y = acc[i][1] + Dh * Xs[t0 + i][p0 + 1];
      o.z = acc[i][2] + Dh * Xs[t0 + i][p0 + 2];
      o.w = acc[i][3] + Dh * Xs[t0 + i][p0 + 3];
      *(float4*)(y + (size_t)row * DINNER + h * HEADDIM + p0) = o;
    }
  }

  {
    int lr = lane & 15, lg = lane >> 4;
    f32x4 gacc[2][4] = {};
#pragma unroll
    for (int nt = 0; nt < 2; ++nt) {
      bf16x8 af = *(const bf16x8*)&Bt[(wave * 2 + nt) * 16 + lr][lg * 8];
#pragma unroll
      for (int pt = 0; pt < 4; ++pt) {
        bf16x8 bfr = *(const bf16x8*)&Xt[pt * 16 + lr][lg * 8];
        gacc[nt][pt] = __builtin_amdgcn_mfma_f32_16x16x32_bf16(af, bfr, gacc[nt][pt], 0, 0, 0);
      }
    }
#pragma unroll
    for (int nt = 0; nt < 2; ++nt)
#pragma unroll
      for (int pt = 0; pt < 4; ++pt) {
        int p = pt * 16 + lr;
        int n0 = (wave * 2 + nt) * 16 + lg * 4;
        bf16x4 o;
#pragma unroll
        for (int r = 0; r < 4; ++r) o[r] = (__bf16)gacc[nt][pt][r];
        *(bf16x4*)&Gl[p][n0] = o;
      }
  }
  __syncthreads();
  {
    __bf16* Gp = Gt + ((size_t)bh * NCHUNK + ci) * (DSTATE * HEADDIM);
#pragma unroll
    for (int i = 0; i < 4; ++i) {
      int vi = tid + i * 256;  // 1024
      int p = vi >> 4;
      int c = vi & 15;
      bf16x8 v = *(const bf16x8*)&Gl[p][c * 8];
      int cs = c ^ (p & 7);
      *(bf16x8*)(Gp + (size_t)p * DSTATE + cs * 8) = v;
    }
  }
}

// ---------------- combine chunk states (bf16x8-wide, fp32 running state) -----------
__global__ __launch_bounds__(256) void combine_kernel(__bf16* __restrict__ G,
                                                      const float* __restrict__ elast) {
  int part = blockIdx.x;  // 0..3
  int bh = blockIdx.y;
  int gi = part * 256 + threadIdx.x;  // bf16x8 group index within 1024
  __bf16* base = G + (size_t)bh * NCHUNK * (DSTATE * HEADDIM);
  const float* el = elast + bh * NCHUNK;
  float hs[8] = {};
#pragma unroll
  for (int c = 0; c < NCHUNK - 1; ++c) {
    bf16x8 g = *(bf16x8*)(base + (size_t)c * (DSTATE * HEADDIM) + gi * 8);
    float e = el[c];
    bf16x8 o;
#pragma unroll
    for (int q = 0; q < 8; ++q) {
      hs[q] = fmaf(e, hs[q], (float)g[q]);
      o[q] = (__bf16)hs[q];
    }
    *(bf16x8*)(base + (size_t)c * (DSTATE * HEADDIM) + gi * 8) = o;
  }
}

// ---------------- inter-chunk contribution: MFMA bf16 (C 32x128 @ Ht^T 128x64) ---------------
__global__ __launch_bounds__(256) void apply_inter_kernel(const float* __restrict__ xBC,
                                                          const __bf16* __restrict__ Gt,
                                                          const float* __restrict__ et,
                                                          float* __restrict__ y) {
  __shared__ __bf16 CsB[CHUNK * DSTATE];   // [t][128] bf16, chunk-swizzled
  __shared__ __bf16 HsB[HEADDIM * DSTATE]; // [p][128] bf16, pre-swizzled global -> linear stage
  __shared__ float sE[CHUNK];
  int ci = blockIdx.x + 1;
  int h = blockIdx.y, b = blockIdx.z;
  int bh = b * NHEADS + h;
  int tid = threadIdx.x;
  int wave = tid >> 6, lane = tid & 63;
  int row0 = b * L_SEQ + ci * CHUNK;

  const __bf16* Hsrc = Gt + ((size_t)bh * NCHUNK + (ci - 1)) * (DSTATE * HEADDIM);
#pragma unroll
  for (int r = 0; r < 4; ++r) {
    gload16(Hsrc + (size_t)r * 2048 + wave * 512 + lane * 8,
            (char*)HsB + r * 4096 + wave * 1024);
  }
#pragma unroll
  for (int i = 0; i < 2; ++i) {
    int vi = tid + i * 256;
    int t = vi >> 4;
    int c = vi & 15;
    const float* src = xBC + (size_t)(row0 + t) * BCDIM + DSTATE + c * 8;
    float4 v0 = *(const float4*)src;
    float4 v1 = *(const float4*)(src + 4);
    bf16x8 o;
    o[0] = (__bf16)v0.x; o[1] = (__bf16)v0.y; o[2] = (__bf16)v0.z; o[3] = (__bf16)v0.w;
    o[4] = (__bf16)v1.x; o[5] = (__bf16)v1.y; o[6] = (__bf16)v1.z; o[7] = (__bf16)v1.w;
    int cs = c ^ (t & 7);
    *(bf16x8*)&CsB[t * DSTATE + cs * 8] = o;
  }
  if (tid < CHUNK) sE[tid] = et[(size_t)(bh * NCHUNK + ci) * CHUNK + tid];
  __syncthreads();

  int lr = lane & 15, lg = lane >> 4;
  int wm = wave >> 1;
  int wnb = (wave & 1) * 2;
  f32x4 acc[2] = {};
#pragma unroll
  for (int ks = 0; ks < 4; ++ks) {
    int ar = wm * 16 + lr;
    bf16x8 af = *(const bf16x8*)&CsB[ar * DSTATE + (((ks * 4 + lg) ^ (ar & 7)) * 8)];
#pragma unroll
    for (int nn = 0; nn < 2; ++nn) {
      int br = (wnb + nn) * 16 + lr;
      bf16x8 bfr = *(const bf16x8*)&HsB[br * DSTATE + (((ks * 4 + lg) ^ (br & 7)) * 8)];
      acc[nn] = __builtin_amdgcn_mfma_f32_16x16x32_bf16(af, bfr, acc[nn], 0, 0, 0);
    }
  }
#pragma unroll
  for (int nn = 0; nn < 2; ++nn) {
    int p = (wnb + nn) * 16 + lr;
#pragma unroll
    for (int r = 0; r < 4; ++r) {
      int t = wm * 16 + lg * 4 + r;
      float e = sE[t];
      float* yp = &y[(size_t)(row0 + t) * DINNER + h * HEADDIM + p];
      *yp = fmaf(e, acc[nn][r], *yp);
    }
  }
}

// ---------------- gate (silu(z)) + RMS norm -> bf16 hi/lo ----------------
__global__ __launch_bounds__(256) void gate_rms_kernel(const float* __restrict__ y,
                                                       const float* __restrict__ zx,
                                                       const float* __restrict__ rmsw,
                                                       __bf16* __restrict__ oh,
                                                       __bf16* __restrict__ ol) {
  __shared__ float sred[8];
  int row = blockIdx.x, tid = threadIdx.x;
  const float* z = zx + (size_t)row * DINPROJ;
  const float* yr = y + (size_t)row * DINNER;
  float v[6];
  float ss = 0.f;
#pragma unroll
  for (int j = 0; j < 6; ++j) {
    int d = tid + j * 256;
    float val = yr[d] * siluf(z[d]);
    v[j] = val;
    ss += val * val;
  }
  float total = block_reduce_sum(ss, sred);
  float r = 1.f / sqrtf(total * (1.f / DINNER) + 1e-5f);
#pragma unroll
  for (int j = 0; j < 6; ++j) {
    int d = tid + j * 256;
    float val = v[j] * r * rmsw[d];
    __bf16 h = (__bf16)val;
    oh[(size_t)row * DINNER + d] = h;
    ol[(size_t)row * DINNER + d] = (__bf16)(val - (float)h);
  }
}

extern "C" void kernel_launch(void* const* d_in, const int* in_sizes, int n_in,
                              void* d_out, int out_size, void* d_ws, size_t ws_size,
                              hipStream_t stream) {
  const int* tokens = (const int*)d_in[0];
  const float* emb = (const float*)d_in[1];
  const float* ln_w = (const float*)d_in[2];
  const float* ln_b = (const float*)d_in[3];
  const float* Win = (const float*)d_in[4];
  const float* conv_w = (const float*)d_in[5];
  const float* conv_b = (const float*)d_in[6];
  const float* dt_bias = (const float*)d_in[7];
  const float* A_log = (const float*)d_in[8];
  const float* Dp = (const float*)d_in[9];
  const float* rms_w = (const float*)d_in[10];
  const float* Wout = (const float*)d_in[11];
  const float* Wcls = (const float*)d_in[12];
  const float* bcls = (const float*)d_in[13];
  float* out = (float*)d_out;

  float* ws = (float*)d_ws;
  float* x = ws;                                // 1024*768
  float* zx = x + (size_t)ROWS * DMODEL;        // 1024*3352
  float* y = zx + (size_t)ROWS * DINPROJ;       // 1024*1536
  __bf16* Gt = (__bf16*)(y + (size_t)ROWS * DINNER);  // transposed+swizzled bf16
  float* et = (float*)(Gt + (size_t)B_SZ * NHEADS * NCHUNK * DSTATE * HEADDIM);
  float* elast = et + (size_t)B_SZ * NHEADS * NCHUNK * CHUNK;
  float* xBC = elast + B_SZ * NHEADS * NCHUNK;  // 1024*256
  float* Sraw = xBC + (size_t)ROWS * BCDIM;     // 2*16*32*32
  float* dts = Sraw + (size_t)B_SZ * NCHUNK * CHUNK * CHUNK;  // 1024*24
  __bf16* bp = (__bf16*)(dts + (size_t)ROWS * NHEADS);
  __bf16* nxh = bp;  bp += (size_t)ROWS * DMODEL;
  __bf16* nxl = bp;  bp += (size_t)ROWS * DMODEL;
  __bf16* yh = bp;   bp += (size_t)ROWS * DINNER;
  __bf16* yl = bp;   bp += (size_t)ROWS * DINNER;
  __bf16* xh = bp;   bp += (size_t)ROWS * DMODEL;
  __bf16* xl = bp;   bp += (size_t)ROWS * DMODEL;
  __bf16* wih0 = bp; bp += (size_t)NPAD_IN * DMODEL;
  __bf16* wil0 = bp; bp += (size_t)NPAD_IN * DMODEL;
  __bf16* wih1 = bp; bp += (size_t)NPAD_IN * DMODEL;
  __bf16* wil1 = bp; bp += (size_t)NPAD_IN * DMODEL;
  __bf16* woh0 = bp; bp += (size_t)DMODEL * DINNER;
  __bf16* wol0 = bp; bp += (size_t)DMODEL * DINNER;
  __bf16* woh1 = bp; bp += (size_t)DMODEL * DINNER;
  __bf16* wol1 = bp; bp += (size_t)DMODEL * DINNER;
  __bf16* wch = bp;  bp += (size_t)NPAD_CLS * DMODEL;
  __bf16* wcl = bp;

  constexpr int TIN = (NPAD_IN / 32) * (DMODEL / 32);
  constexpr int TOUT = (DMODEL / 32) * (DINNER / 32);
  constexpr int TCLS = (NPAD_CLS / 32) * (DMODEL / 32);
  decomp_all_kernel<<<2 * TIN + 2 * TOUT + TCLS + ROWS, 256, 0, stream>>>(
      Win, Wout, Wcls, tokens, emb, ln_w, ln_b, x, nxh, nxl, wih0, wil0, wih1, wil1, woh0, wol0,
      woh1, wol1, wch, wcl);

  for (int blk = 0; blk < 2; ++blk) {
    const float* cw_b = conv_w + (size_t)blk * CONVDIM * 4;
    const float* cb_b = conv_b + (size_t)blk * CONVDIM;
    const float* dtb_b = dt_bias + (size_t)blk * NHEADS;
    const float* Alog_b = A_log + (size_t)blk * NHEADS;
    const float* Dp_b = Dp + (size_t)blk * NHEADS;
    const float* rmsw_b = rms_w + (size_t)blk * DINNER;
    __bf16* wih = blk ? wih1 : wih0;
    __bf16* wil = blk ? wil1 : wil0;
    __bf16* woh = blk ? woh1 : woh0;
    __bf16* wol = blk ? wol1 : wol0;

    if (blk == 1) {
      ln_kernel<<<ROWS, 256, 0, stream>>>(x, ln_w + (size_t)blk * DMODEL,
                                          ln_b + (size_t)blk * DMODEL, nxh, nxl);
    }

    // in-proj: 128x64 tiles, 54*8 = 432 blocks, by-major XCD swizzle
    mfma_gemm_kernel<4, 2, false><<<(NPAD_IN / 64) * (ROWS / 128), 256, 0, stream>>>(
        nxh, nxl, wih, wil, nullptr, nullptr, zx, DINPROJ, DMODEL, 0, NPAD_IN / 64, 0,
        (NPAD_IN / 64) * (ROWS / 128));

    convBC_kernel<<<ROWS, BCDIM, 0, stream>>>(zx, cw_b, cb_b, dtb_b, xBC, dts);

    sraw_kernel<<<dim3(NCHUNK, B_SZ), 256, 0, stream>>>(xBC, Sraw);

    chunk_local_kernel<<<dim3(NCHUNK, NHEADS, B_SZ), 256, 0, stream>>>(
        zx, xBC, Sraw, dts, cw_b, cb_b, Alog_b, Dp_b, y, Gt, et, elast);

    combine_kernel<<<dim3(4, B_SZ * NHEADS), 256, 0, stream>>>(Gt, elast);

    apply_inter_kernel<<<dim3(NCHUNK - 1, NHEADS, B_SZ), 256, 0, stream>>>(xBC, Gt, et, y);

    gate_rms_kernel<<<ROWS, 256, 0, stream>>>(y, zx, rmsw_b, yh, yl);

    // out-proj: split-K=2 (kslice 768), 12*16*2 = 384 blocks (384 % 8 == 0)
    mfma_gemm_kernel<2, 2, true><<<(DMODEL / 64) * (ROWS / 64) * 2, 256, 0, stream>>>(
        yh, yl, woh, wol, nullptr, nullptr, x, DMODEL, DINNER, DINNER / 2, DMODEL / 64,
        ROWS / 64, (DMODEL / 64) * (ROWS / 64) * 2);
  }

  act_decomp_kernel<<<ROWS, 256, 0, stream>>>(x, xh, xl);
  mfma_gemm_kernel<2, 2, false><<<(NPAD_CLS / 64) * (ROWS / 64), 256, 0, stream>>>(
      xh, xl, wch, wcl, nullptr, bcls, out, 1000, DMODEL, 0, NPAD_CLS / 64, 0,
      (NPAD_CLS / 64) * (ROWS / 64));
}